// Round 14
// baseline (2598.639 us; speedup 1.0000x reference)
//
#include <hip/hip_runtime.h>

typedef unsigned short u16;
typedef __attribute__((ext_vector_type(8))) short bf16x8;
typedef __attribute__((ext_vector_type(4))) float f32x4;

#define DEV __device__ __forceinline__

DEV float b2f(u16 h){ return __uint_as_float(((unsigned)h) << 16); }
DEV u16 f2b(float f){ unsigned u = __float_as_uint(f); u += 0x7FFFu + ((u >> 16) & 1u); return (u16)(u >> 16); }

DEV void gload16(const u16* g, u16* l){
  __builtin_amdgcn_global_load_lds((const __attribute__((address_space(1))) unsigned*)g,
                                   (__attribute__((address_space(3))) unsigned*)l, 16, 0, 0);
}

// ---------------- weight transpose + convert:  W[K,N] f32 -> Wt[N,K] bf16 (x scale) ----------------
__global__ __launch_bounds__(256) void wtrans(const float* __restrict__ src, u16* __restrict__ dst,
                                              int K, int N, float scale){
  __shared__ float tile[32][33];
  int k0 = blockIdx.x * 32, n0 = blockIdx.y * 32;
  int tid = threadIdx.x;
#pragma unroll
  for (int i = 0; i < 4; i++){
    int idx = tid + i * 256;
    int r = idx >> 5, c = idx & 31;
    tile[r][c] = src[(size_t)(k0 + r) * N + n0 + c];
  }
  __syncthreads();
#pragma unroll
  for (int i = 0; i < 4; i++){
    int idx = tid + i * 256;
    int r = idx >> 5, c = idx & 31;
    dst[(size_t)(n0 + r) * K + k0 + c] = f2b(tile[c][r] * scale);
  }
}

// ---------------- f32 -> bf16 convert ----------------
__global__ __launch_bounds__(256) void cvt16(const float* __restrict__ src, u16* __restrict__ dst){
  size_t i = ((size_t)blockIdx.x * 256 + threadIdx.x) * 4;
  float4 f = *(const float4*)(src + i);
  ushort4 o = make_ushort4(f2b(f.x), f2b(f.y), f2b(f.z), f2b(f.w));
  *(ushort4*)(dst + i) = o;
}

// ---------------- bias concat (all layers): [6][3072] = bq|bk|bv ----------------
__global__ void catbias(const float* __restrict__ bq, const float* __restrict__ bk,
                        const float* __restrict__ bv, float* __restrict__ bcat){
  int i = blockIdx.x * 256 + threadIdx.x;
  if (i >= 6 * 3072) return;
  int l = i / 3072, j = i % 3072;
  float v = (j < 1024) ? bq[l * 1024 + j] : (j < 2048) ? bk[l * 1024 + j - 1024] : bv[l * 1024 + j - 2048];
  bcat[i] = v;
}

// ---------------- diagnostic / zero fill ----------------
__global__ void fillv(float* __restrict__ p, float v, int n){
  int i = blockIdx.x * 256 + threadIdx.x;
  if (i < n) p[i] = v;
}

// ---------------- 128^2 bf16 MFMA GEMM (gload_lds dbuf + counted vmcnt + XCD swizzle) ----------------
// EPI 2: relu bf16 [M,N] ; EPI 5: fused QKV ; EPI 6: bf16 [M,N]
DEV int swz(int r){ return (r & 3) ^ ((r >> 2) & 3); }

template<int EPI>
__global__ __launch_bounds__(256) void gemm_bt(const u16* __restrict__ A, const u16* __restrict__ Bt,
                                               const float* __restrict__ bias, void* __restrict__ outp,
                                               int M, int N, int K, int ldA, int ldB){
  __shared__ __align__(16) u16 As[2][4096];
  __shared__ __align__(16) u16 Bs[2][4096];
  const int tid = threadIdx.x;
  const int lane = tid & 63;
  const int w = tid >> 6;
  const int wm = w >> 1, wn = w & 1;
  int nx = gridDim.x;
  int nwg = nx * gridDim.y;
  int lin = blockIdx.y * nx + blockIdx.x;
  int cpx = nwg >> 3;
  int sw = (lin & 7) * cpx + (lin >> 3);
  const int m0 = (sw / nx) * 128;
  const int n0 = (sw % nx) * 128;

  int r0 = tid >> 2, c0 = tid & 3;
  int r1 = r0 + 64;
  int cs0 = c0 ^ swz(r0);
  int cs1 = c0 ^ swz(r1);
  const u16* ag0 = A + (size_t)(m0 + r0) * ldA + cs0 * 8;
  const u16* ag1 = A + (size_t)(m0 + r1) * ldA + cs1 * 8;
  const u16* bg0 = Bt + (size_t)(n0 + r0) * ldB + cs0 * 8;
  const u16* bg1 = Bt + (size_t)(n0 + r1) * ldB + cs1 * 8;

  f32x4 acc[4][4] = {};
  const int KT = K >> 5;

  gload16(ag0, &As[0][w * 512]);
  gload16(ag1, &As[0][2048 + w * 512]);
  gload16(bg0, &Bs[0][w * 512]);
  gload16(bg1, &Bs[0][2048 + w * 512]);

  for (int kt = 0; kt < KT; kt++){
    int cur = kt & 1;
    if (kt + 1 < KT){
      int ko = (kt + 1) << 5;
      gload16(ag0 + ko, &As[cur ^ 1][w * 512]);
      gload16(ag1 + ko, &As[cur ^ 1][2048 + w * 512]);
      gload16(bg0 + ko, &Bs[cur ^ 1][w * 512]);
      gload16(bg1 + ko, &Bs[cur ^ 1][2048 + w * 512]);
      asm volatile("s_waitcnt vmcnt(4)" ::: "memory");
    } else {
      asm volatile("s_waitcnt vmcnt(0)" ::: "memory");
    }
    __builtin_amdgcn_s_barrier();
    bf16x8 fa[4], fb[4];
#pragma unroll
    for (int m = 0; m < 4; m++){
      int row = wm * 64 + m * 16 + (lane & 15);
      int cc = (lane >> 4) ^ swz(row);
      fa[m] = *(const bf16x8*)(&As[cur][row * 32 + cc * 8]);
    }
#pragma unroll
    for (int n = 0; n < 4; n++){
      int row = wn * 64 + n * 16 + (lane & 15);
      int cc = (lane >> 4) ^ swz(row);
      fb[n] = *(const bf16x8*)(&Bs[cur][row * 32 + cc * 8]);
    }
#pragma unroll
    for (int m = 0; m < 4; m++)
#pragma unroll
      for (int n = 0; n < 4; n++)
        acc[m][n] = __builtin_amdgcn_mfma_f32_16x16x32_bf16(fa[m], fb[n], acc[m][n], 0, 0, 0);
    asm volatile("s_waitcnt lgkmcnt(0)" ::: "memory");
    __builtin_amdgcn_s_barrier();
  }

#pragma unroll
  for (int m = 0; m < 4; m++){
    int rowb = m0 + wm * 64 + m * 16 + ((lane >> 4) << 2);
#pragma unroll
    for (int n = 0; n < 4; n++){
      int col = n0 + wn * 64 + n * 16 + (lane & 15);
      float bv = bias[col];
      if (EPI == 5 && col >= 2048){
        int cv = col - 2048, hh = cv >> 6, dh = cv & 63;
        int bIdx = rowb >> 11, s4 = rowb & 2047;
        ushort4 pk = make_ushort4(f2b(acc[m][n][0] + bv), f2b(acc[m][n][1] + bv),
                                  f2b(acc[m][n][2] + bv), f2b(acc[m][n][3] + bv));
        *(ushort4*)&((u16*)outp + 16777216)[((size_t)(bIdx * 16 + hh) * 64 + dh) * 2048 + s4] = pk;
      } else {
#pragma unroll
        for (int r = 0; r < 4; r++){
          float v = acc[m][n][r] + bv;
          int rr = rowb + r;
          if (EPI == 5){
            u16* dst0 = (u16*)outp + (col < 1024 ? 0 : 8388608);
            int cv = col & 1023, hh = cv >> 6, dh = cv & 63;
            int bIdx = rr >> 11, s = rr & 2047;
            dst0[(((size_t)(bIdx * 16 + hh) * 2048 + s) << 6) + dh] = f2b(v);
          } else if (EPI == 2){
            ((u16*)outp)[(size_t)rr * N + col] = f2b(v > 0.f ? v : 0.f);
          } else {
            ((u16*)outp)[(size_t)rr * N + col] = f2b(v);
          }
        }
      }
    }
  }
}

// ---------------- 8-phase 256^2 GEMM (m201 template): BK=64, K-half subtiles, counted vmcnt ----------------
// EPI 2: relu bf16 ; EPI 6: bf16   (scalar epilogue)
template<int EPI>
__global__ __launch_bounds__(512, 1) void gemm8p(const u16* __restrict__ A, const u16* __restrict__ Bt,
                                                 const float* __restrict__ bias, void* __restrict__ outp,
                                                 int M, int N, int K, int ldA, int ldB){
  __shared__ __align__(16) u16 As[2][16384];
  __shared__ __align__(16) u16 Bs[2][16384];
  const int tid = threadIdx.x;
  const int lane = tid & 63;
  const int w = tid >> 6;
  const int wm = w >> 2, wn = w & 3;
  int nx = gridDim.x;
  int nwg = nx * gridDim.y;
  int lin = blockIdx.y * nx + blockIdx.x;
  int cpx = nwg >> 3;
  int sw = (lin & 7) * cpx + (lin >> 3);
  const int m0 = (sw / nx) * 256;
  const int n0 = (sw % nx) * 256;

  const int id1 = 512 + tid;
  const int r0 = tid >> 2, c20 = tid & 3;
  const int r1 = id1 >> 2, c21 = id1 & 3;
  const int cs0 = c20 ^ ((r0 >> 1) & 3);
  const int cs1 = c21 ^ ((r1 >> 1) & 3);
  const u16* Ag0 = A + (size_t)(m0 + r0) * ldA + cs0 * 8;
  const u16* Ag1 = A + (size_t)(m0 + r1) * ldA + cs1 * 8;
  const u16* Bg0 = Bt + (size_t)(n0 + r0) * ldB + cs0 * 8;
  const u16* Bg1 = Bt + (size_t)(n0 + r1) * ldB + cs1 * 8;

  f32x4 acc[8][4] = {};
  const int KT = K >> 6;

  auto stA = [&](int buf, int kt, int ks){
    int kc = kt * 64 + ks * 32;
    gload16(Ag0 + kc, &As[buf][ks * 8192 + w * 512]);
    gload16(Ag1 + kc, &As[buf][ks * 8192 + 4096 + w * 512]);
  };
  auto stB = [&](int buf, int kt, int ks){
    int kc = kt * 64 + ks * 32;
    gload16(Bg0 + kc, &Bs[buf][ks * 8192 + w * 512]);
    gload16(Bg1 + kc, &Bs[buf][ks * 8192 + 4096 + w * 512]);
  };

  stA(0, 0, 0); stB(0, 0, 0); stA(0, 0, 1); stB(0, 0, 1);

  for (int t = 0; t < KT; t++){
    int c = t & 1, nb = c ^ 1;
    bool pf = (t + 1 < KT);
    asm volatile("s_waitcnt vmcnt(4)" ::: "memory");
    __builtin_amdgcn_s_barrier();

#pragma unroll
    for (int ks = 0; ks < 2; ks++){
      if (ks == 1){
        if (pf) asm volatile("s_waitcnt vmcnt(4)" ::: "memory");
        else    asm volatile("s_waitcnt vmcnt(0)" ::: "memory");
        __builtin_amdgcn_s_barrier();
      }
      if (pf){ if (ks == 0) stA(nb, t + 1, 0); else stA(nb, t + 1, 1); }
      bf16x8 fa[8], fb[2];
#pragma unroll
      for (int m = 0; m < 8; m++){
        int row = wm * 128 + m * 16 + (lane & 15);
        int slot = (lane >> 4) ^ ((row >> 1) & 3);
        fa[m] = *(const bf16x8*)(&As[c][ks * 8192 + row * 32 + slot * 8]);
      }
#pragma unroll
      for (int nn = 0; nn < 2; nn++){
        int row = wn * 64 + nn * 16 + (lane & 15);
        int slot = (lane >> 4) ^ ((row >> 1) & 3);
        fb[nn] = *(const bf16x8*)(&Bs[c][ks * 8192 + row * 32 + slot * 8]);
      }
      __builtin_amdgcn_s_setprio(1);
#pragma unroll
      for (int m = 0; m < 8; m++)
#pragma unroll
        for (int nn = 0; nn < 2; nn++)
          acc[m][nn] = __builtin_amdgcn_mfma_f32_16x16x32_bf16(fa[m], fb[nn], acc[m][nn], 0, 0, 0);
      __builtin_amdgcn_s_setprio(0);
      if (pf){ if (ks == 0) stB(nb, t + 1, 0); else stB(nb, t + 1, 1); }
#pragma unroll
      for (int nn = 0; nn < 2; nn++){
        int row = wn * 64 + 32 + nn * 16 + (lane & 15);
        int slot = (lane >> 4) ^ ((row >> 1) & 3);
        fb[nn] = *(const bf16x8*)(&Bs[c][ks * 8192 + row * 32 + slot * 8]);
      }
      __builtin_amdgcn_s_setprio(1);
#pragma unroll
      for (int m = 0; m < 8; m++)
#pragma unroll
        for (int nn = 0; nn < 2; nn++)
          acc[m][2 + nn] = __builtin_amdgcn_mfma_f32_16x16x32_bf16(fa[m], fb[nn], acc[m][2 + nn], 0, 0, 0);
      __builtin_amdgcn_s_setprio(0);
    }
  }

#pragma unroll
  for (int m = 0; m < 8; m++){
    int rowb = m0 + wm * 128 + m * 16 + ((lane >> 4) << 2);
#pragma unroll
    for (int n = 0; n < 4; n++){
      int col = n0 + wn * 64 + n * 16 + (lane & 15);
      float bv = bias[col];
#pragma unroll
      for (int r = 0; r < 4; r++){
        float v = acc[m][n][r] + bv;
        int rr = rowb + r;
        if (EPI == 2) ((u16*)outp)[(size_t)rr * N + col] = f2b(v > 0.f ? v : 0.f);
        else          ((u16*)outp)[(size_t)rr * N + col] = f2b(v);
      }
    }
  }
}

// ---------------- 8-phase 256^2 split-K GEMM: 256 blocks = (4 n)x(32 m)x(2 kz), bf16 partials ----------------
// used for W2 (Khalf=2048) and Wo (Khalf=512)
__global__ __launch_bounds__(512, 1) void gemm8pk(const u16* __restrict__ A, const u16* __restrict__ Bt,
                                                  const float* __restrict__ bias0, const float* __restrict__ bias1,
                                                  u16* __restrict__ out0, u16* __restrict__ out1,
                                                  int M, int N, int Khalf, int ldA, int ldB){
  __shared__ __align__(16) u16 As[2][16384];
  __shared__ __align__(16) u16 Bs[2][16384];
  const int tid = threadIdx.x;
  const int lane = tid & 63;
  const int w = tid >> 6;
  const int wm = w >> 2, wn = w & 3;
  int lin = blockIdx.x;               // 256 blocks
  int cpx = gridDim.x >> 3;
  int sw = (lin & 7) * cpx + (lin >> 3);
  const int kz = sw & 1;
  const int t2 = sw >> 1;
  const int n0 = (t2 & 3) * 256;
  const int m0 = (t2 >> 2) * 256;
  const u16* Ab = A + kz * Khalf;
  const u16* Bb = Bt + kz * Khalf;
  u16* outp = kz ? out1 : out0;
  const float* bias = kz ? bias1 : bias0;

  const int id1 = 512 + tid;
  const int r0 = tid >> 2, c20 = tid & 3;
  const int r1 = id1 >> 2, c21 = id1 & 3;
  const int cs0 = c20 ^ ((r0 >> 1) & 3);
  const int cs1 = c21 ^ ((r1 >> 1) & 3);
  const u16* Ag0 = Ab + (size_t)(m0 + r0) * ldA + cs0 * 8;
  const u16* Ag1 = Ab + (size_t)(m0 + r1) * ldA + cs1 * 8;
  const u16* Bg0 = Bb + (size_t)(n0 + r0) * ldB + cs0 * 8;
  const u16* Bg1 = Bb + (size_t)(n0 + r1) * ldB + cs1 * 8;

  f32x4 acc[8][4] = {};
  const int KT = Khalf >> 6;

  auto stA = [&](int buf, int kt, int ks){
    int kc = kt * 64 + ks * 32;
    gload16(Ag0 + kc, &As[buf][ks * 8192 + w * 512]);
    gload16(Ag1 + kc, &As[buf][ks * 8192 + 4096 + w * 512]);
  };
  auto stB = [&](int buf, int kt, int ks){
    int kc = kt * 64 + ks * 32;
    gload16(Bg0 + kc, &Bs[buf][ks * 8192 + w * 512]);
    gload16(Bg1 + kc, &Bs[buf][ks * 8192 + 4096 + w * 512]);
  };

  stA(0, 0, 0); stB(0, 0, 0); stA(0, 0, 1); stB(0, 0, 1);

  for (int t = 0; t < KT; t++){
    int c = t & 1, nb = c ^ 1;
    bool pf = (t + 1 < KT);
    asm volatile("s_waitcnt vmcnt(4)" ::: "memory");
    __builtin_amdgcn_s_barrier();

#pragma unroll
    for (int ks = 0; ks < 2; ks++){
      if (ks == 1){
        if (pf) asm volatile("s_waitcnt vmcnt(4)" ::: "memory");
        else    asm volatile("s_waitcnt vmcnt(0)" ::: "memory");
        __builtin_amdgcn_s_barrier();
      }
      if (pf){ if (ks == 0) stA(nb, t + 1, 0); else stA(nb, t + 1, 1); }
      bf16x8 fa[8], fb[2];
#pragma unroll
      for (int m = 0; m < 8; m++){
        int row = wm * 128 + m * 16 + (lane & 15);
        int slot = (lane >> 4) ^ ((row >> 1) & 3);
        fa[m] = *(const bf16x8*)(&As[c][ks * 8192 + row * 32 + slot * 8]);
      }
#pragma unroll
      for (int nn = 0; nn < 2; nn++){
        int row = wn * 64 + nn * 16 + (lane & 15);
        int slot = (lane >> 4) ^ ((row >> 1) & 3);
        fb[nn] = *(const bf16x8*)(&Bs[c][ks * 8192 + row * 32 + slot * 8]);
      }
      __builtin_amdgcn_s_setprio(1);
#pragma unroll
      for (int m = 0; m < 8; m++)
#pragma unroll
        for (int nn = 0; nn < 2; nn++)
          acc[m][nn] = __builtin_amdgcn_mfma_f32_16x16x32_bf16(fa[m], fb[nn], acc[m][nn], 0, 0, 0);
      __builtin_amdgcn_s_setprio(0);
      if (pf){ if (ks == 0) stB(nb, t + 1, 0); else stB(nb, t + 1, 1); }
#pragma unroll
      for (int nn = 0; nn < 2; nn++){
        int row = wn * 64 + 32 + nn * 16 + (lane & 15);
        int slot = (lane >> 4) ^ ((row >> 1) & 3);
        fb[nn] = *(const bf16x8*)(&Bs[c][ks * 8192 + row * 32 + slot * 8]);
      }
      __builtin_amdgcn_s_setprio(1);
#pragma unroll
      for (int m = 0; m < 8; m++)
#pragma unroll
        for (int nn = 0; nn < 2; nn++)
          acc[m][2 + nn] = __builtin_amdgcn_mfma_f32_16x16x32_bf16(fa[m], fb[nn], acc[m][2 + nn], 0, 0, 0);
      __builtin_amdgcn_s_setprio(0);
    }
  }

#pragma unroll
  for (int m = 0; m < 8; m++){
    int rowb = m0 + wm * 128 + m * 16 + ((lane >> 4) << 2);
#pragma unroll
    for (int n = 0; n < 4; n++){
      int col = n0 + wn * 64 + n * 16 + (lane & 15);
      float bv = bias[col];
#pragma unroll
      for (int r = 0; r < 4; r++)
        outp[(size_t)(rowb + r) * N + col] = f2b(acc[m][n][r] + bv);
    }
  }
}

// ---------------- FAVOR phi v2 (MFMA) ----------------
__global__ __launch_bounds__(256) void phi2(const u16* __restrict__ qb, const u16* __restrict__ kb,
                                            const u16* __restrict__ omT,
                                            u16* __restrict__ Qp, u16* __restrict__ Kp){
  __shared__ __align__(16) u16 qs[128 * 64];
  __shared__ __align__(16) u16 wl[64 * 64];
  __shared__ __align__(16) u16 ph[128 * 128];
  __shared__ float part[2][128];
  __shared__ float nrm[128];
  int tid = threadIdx.x, w = tid >> 6, lane = tid & 63;
  int blk = blockIdx.x;
  const u16* src; u16* dst; int row0;
  if (blk < 1024){ src = qb; dst = Qp; row0 = blk * 128; }
  else           { src = kb; dst = Kp; row0 = (blk - 1024) * 128; }
  const u16* g = src + (size_t)row0 * 64;
#pragma unroll
  for (int i = 0; i < 4; i++){
    int id = tid * 4 + i;
    int r = id >> 3, kc = id & 7;
    *(bf16x8*)(qs + r * 64 + ((kc ^ (r & 7)) << 3)) = *(const bf16x8*)(g + r * 64 + kc * 8);
  }
#pragma unroll
  for (int i = 0; i < 2; i++){
    int id = tid * 2 + i;
    int m = id >> 3, kc = id & 7;
    *(bf16x8*)(wl + m * 64 + ((kc ^ (m & 7)) << 3)) = *(const bf16x8*)(omT + id * 8);
  }
  __syncthreads();
  {
    int r = tid & 127, half = tid >> 7;
    float s = 0.f;
#pragma unroll
    for (int j = 0; j < 4; j++){
      int kc = half * 4 + j;
      bf16x8 v = *(const bf16x8*)(qs + r * 64 + ((kc ^ (r & 7)) << 3));
#pragma unroll
      for (int e = 0; e < 8; e++){ float f = b2f((u16)v[e]); s += f * f; }
    }
    part[half][r] = s;
  }
  __syncthreads();
  if (tid < 128) nrm[tid] = 0.0625f * (part[0][tid] + part[1][tid]);
  __syncthreads();
  f32x4 acc[2][4] = {};
#pragma unroll
  for (int kt = 0; kt < 2; kt++){
    int kc = kt * 4 + (lane >> 4);
    bf16x8 fa[2], fb[4];
#pragma unroll
    for (int mt = 0; mt < 2; mt++){
      int r = w * 32 + mt * 16 + (lane & 15);
      fa[mt] = *(const bf16x8*)(qs + r * 64 + ((kc ^ (r & 7)) << 3));
    }
#pragma unroll
    for (int nt = 0; nt < 4; nt++){
      int m = nt * 16 + (lane & 15);
      fb[nt] = *(const bf16x8*)(wl + m * 64 + ((kc ^ (m & 7)) << 3));
    }
#pragma unroll
    for (int mt = 0; mt < 2; mt++)
#pragma unroll
      for (int nt = 0; nt < 4; nt++)
        acc[mt][nt] = __builtin_amdgcn_mfma_f32_16x16x32_bf16(fa[mt], fb[nt], acc[mt][nt], 0, 0, 0);
  }
  const float LNC = -2.4260151319598086f;   // ln(128^-0.5)
#pragma unroll
  for (int mt = 0; mt < 2; mt++)
#pragma unroll
    for (int nt = 0; nt < 4; nt++)
#pragma unroll
      for (int r4 = 0; r4 < 4; r4++){
        int r = w * 32 + mt * 16 + ((lane >> 4) << 2) + r4;
        int m = nt * 16 + (lane & 15);
        float u = acc[mt][nt][r4];
        float nr = nrm[r];
        ph[r * 128 + m]      = f2b(__expf(u - nr + LNC));
        ph[r * 128 + 64 + m] = f2b(__expf(-u - nr + LNC));
      }
  __syncthreads();
  u16* go = dst + (size_t)row0 * 128;
#pragma unroll
  for (int i = 0; i < 8; i++){
    int id = i * 256 + tid;
    *(bf16x8*)(go + id * 8) = *(const bf16x8*)(ph + id * 8);
  }
}

// ---------------- per-chunk kv^T[d][m], ksum [128m] ----------------
__global__ __launch_bounds__(256) void kvchunk(const u16* __restrict__ Kp, const u16* __restrict__ vt,
                                               float* __restrict__ kv, float* __restrict__ ksum){
  __shared__ __align__(16) u16 Ks[128 * 128];
  __shared__ __align__(16) u16 Vst[64 * 128];
  int blk = blockIdx.x; int bh = blk >> 4, c = blk & 15;
  int tid = threadIdx.x;
  size_t base = (size_t)bh * 2048 + c * 128;
  const u16* Kc = Kp + base * 128;
  const u16* vtc = vt + (size_t)bh * 64 * 2048 + c * 128;
  {
    int j = tid >> 1, half = tid & 1;
#pragma unroll
    for (int i = 0; i < 8; i++)
      *(bf16x8*)(Ks + j * 128 + half * 64 + i * 8) = *(const bf16x8*)(Kc + j * 128 + half * 64 + i * 8);
#pragma unroll
    for (int i = 0; i < 4; i++){
      int id = tid * 4 + i;
      int d = id >> 4, mc = id & 15;
      *(bf16x8*)(Vst + d * 128 + mc * 8) = *(const bf16x8*)(vtc + (size_t)d * 2048 + mc * 8);
    }
  }
  __syncthreads();
  int tm = tid & 15, td = tid >> 4;
  int mbase = tm * 8, dbase = td * 4;
  float acc[8][4] = {};
  float ks[8] = {};
  for (int i = 0; i < 128; i++){
    bf16x8 kk = *(const bf16x8*)(Ks + i * 128 + mbase);
    float kf[8];
#pragma unroll
    for (int e = 0; e < 8; e++) kf[e] = b2f((u16)kk[e]);
    float vf[4];
#pragma unroll
    for (int e = 0; e < 4; e++) vf[e] = b2f(Vst[(dbase + e) * 128 + i]);
#pragma unroll
    for (int a = 0; a < 8; a++){
      ks[a] += kf[a];
#pragma unroll
      for (int bb = 0; bb < 4; bb++) acc[a][bb] += kf[a] * vf[bb];
    }
  }
  float* kvout = kv + ((size_t)bh * 16 + c) * 8192;
#pragma unroll
  for (int a = 0; a < 8; a++)
#pragma unroll
    for (int bb = 0; bb < 4; bb++)
      kvout[(size_t)(dbase + bb) * 128 + mbase + a] = acc[a][bb];
  if (td == 0){
    float* kso = ksum + ((size_t)bh * 16 + c) * 128;
#pragma unroll
    for (int a = 0; a < 8; a++) kso[mbase + a] = ks[a];
  }
}

// ---------------- exclusive prefix over chunks (in place) ----------------
__global__ __launch_bounds__(256) void kvscan(float* __restrict__ kv, float* __restrict__ ksum){
  int bh = blockIdx.x;
  int p = blockIdx.y;
  int tid = threadIdx.x;
  if (p < 8){
    size_t base = (size_t)bh * 16 * 8192;
    int idx0 = p * 1024 + tid;
    for (int rep = 0; rep < 4; rep++){
      int idx = idx0 + rep * 256;
      float run = 0.f;
#pragma unroll
      for (int c = 0; c < 16; c++){
        size_t off = base + (size_t)c * 8192 + idx;
        float v = kv[off]; kv[off] = run; run += v;
      }
    }
  } else if (tid < 128){
    size_t base = (size_t)bh * 16 * 128;
    float run = 0.f;
#pragma unroll
    for (int c = 0; c < 16; c++){
      size_t off = base + c * 128 + tid;
      float v = ksum[off]; ksum[off] = run; run += v;
    }
  }
}

// ---------------- MFMA fused attention ----------------
__global__ __launch_bounds__(512) void attn_fused(const u16* __restrict__ Qp, const u16* __restrict__ Kp,
                                                  const u16* __restrict__ vt, const float* __restrict__ kvp,
                                                  const float* __restrict__ ksum, u16* __restrict__ aout){
  __shared__ __align__(16) u16 sm[53248];
  int blk = blockIdx.x, bh = blk >> 4, c = blk & 15;
  int b = bh >> 4, h = bh & 15;
  int tid = threadIdx.x, w = tid >> 6, lane = tid & 63;
  size_t base = (size_t)bh * 2048 + c * 128;
  const u16* Qc = Qp + base * 128;
  const u16* Kc = Kp + base * 128;
  const u16* vtc = vt + (size_t)bh * 64 * 2048 + c * 128;
  const float* kvc = kvp + ((size_t)bh * 16 + c) * 8192;
  const float* ksc = ksum + ((size_t)bh * 16 + c) * 128;
  u16* Qs = sm;
  u16* Ks = sm + 16384;
  u16* B2 = sm + 32768;

#pragma unroll
  for (int i = 0; i < 4; i++){
    int id = tid * 4 + i;
    int r = id >> 4, kc = id & 15;
    int swo = (kc ^ (r & 15)) << 3;
    *(bf16x8*)(Qs + r * 128 + swo) = *(const bf16x8*)(Qc + (size_t)r * 128 + kc * 8);
    *(bf16x8*)(Ks + r * 128 + swo) = *(const bf16x8*)(Kc + (size_t)r * 128 + kc * 8);
  }
#pragma unroll
  for (int i = 0; i < 2; i++){
    int id = tid * 2 + i;
    int d = id >> 4, kc = id & 15;
    *(bf16x8*)(B2 + d * 256 + ((kc ^ (d & 31)) << 3)) = *(const bf16x8*)(vtc + (size_t)d * 2048 + kc * 8);
  }
#pragma unroll
  for (int i = 0; i < 2; i++){
    int id = tid * 2 + i;
    int d = id >> 4, mc = id & 15;
    const float* s8 = kvc + d * 128 + mc * 8;
    float4 f0 = *(const float4*)(s8);
    float4 f1 = *(const float4*)(s8 + 4);
    bf16x8 pk;
    pk[0] = (short)f2b(f0.x); pk[1] = (short)f2b(f0.y); pk[2] = (short)f2b(f0.z); pk[3] = (short)f2b(f0.w);
    pk[4] = (short)f2b(f1.x); pk[5] = (short)f2b(f1.y); pk[6] = (short)f2b(f1.z); pk[7] = (short)f2b(f1.w);
    int kc = 16 + mc;
    *(bf16x8*)(B2 + d * 256 + ((kc ^ (d & 31)) << 3)) = pk;
  }
  {
    int row = 64 + (tid >> 5), kc = tid & 31;
    bf16x8 pk = {};
    if (row == 64){
      if (kc < 16){
#pragma unroll
        for (int e = 0; e < 8; e++) pk[e] = (short)0x3F80;
      } else {
        const float* s8 = ksc + (kc - 16) * 8;
        float4 f0 = *(const float4*)(s8);
        float4 f1 = *(const float4*)(s8 + 4);
        pk[0] = (short)f2b(f0.x); pk[1] = (short)f2b(f0.y); pk[2] = (short)f2b(f0.z); pk[3] = (short)f2b(f0.w);
        pk[4] = (short)f2b(f1.x); pk[5] = (short)f2b(f1.y); pk[6] = (short)f2b(f1.z); pk[7] = (short)f2b(f1.w);
      }
    }
    *(bf16x8*)(B2 + row * 256 + ((kc ^ (row & 31)) << 3)) = pk;
  }
  __syncthreads();

  int wm = w >> 2, wn = w & 3;
  f32x4 acc1[4][2] = {};
#pragma unroll
  for (int kk = 0; kk < 4; kk++){
    int kc = kk * 4 + (lane >> 4);
    bf16x8 fa[4], fb[2];
#pragma unroll
    for (int m = 0; m < 4; m++){
      int row = wm * 64 + m * 16 + (lane & 15);
      fa[m] = *(const bf16x8*)(Qs + row * 128 + ((kc ^ (row & 15)) << 3));
    }
#pragma unroll
    for (int n = 0; n < 2; n++){
      int row = wn * 32 + n * 16 + (lane & 15);
      fb[n] = *(const bf16x8*)(Ks + row * 128 + ((kc ^ (row & 15)) << 3));
    }
#pragma unroll
    for (int m = 0; m < 4; m++)
#pragma unroll
      for (int n = 0; n < 2; n++)
        acc1[m][n] = __builtin_amdgcn_mfma_f32_16x16x32_bf16(fa[m], fb[n], acc1[m][n], 0, 0, 0);
  }
  __syncthreads();

#pragma unroll
  for (int m = 0; m < 4; m++)
#pragma unroll
    for (int n = 0; n < 2; n++)
#pragma unroll
      for (int r = 0; r < 4; r++){
        int i = wm * 64 + m * 16 + ((lane >> 4) << 2) + r;
        int j = wn * 32 + n * 16 + (lane & 15);
        float v = (j <= i) ? acc1[m][n][r] : 0.f;
        Ks[i * 128 + (((j >> 3) ^ (i & 15)) << 3) + (j & 7)] = f2b(v);
      }
  __syncthreads();

  f32x4 acc2[5] = {};
#pragma unroll
  for (int kk = 0; kk < 8; kk++){
    int kc = kk * 4 + (lane >> 4);
    int rowA = w * 16 + (lane & 15);
    bf16x8 fa2;
    if (kk < 4) fa2 = *(const bf16x8*)(Ks + rowA * 128 + ((kc ^ (rowA & 15)) << 3));
    else        fa2 = *(const bf16x8*)(Qs + rowA * 128 + (((kc - 16) ^ (rowA & 15)) << 3));
#pragma unroll
    for (int n = 0; n < 5; n++){
      int d = n * 16 + (lane & 15);
      bf16x8 fb2 = *(const bf16x8*)(B2 + d * 256 + ((kc ^ (d & 31)) << 3));
      acc2[n] = __builtin_amdgcn_mfma_f32_16x16x32_bf16(fa2, fb2, acc2[n], 0, 0, 0);
    }
  }

  float dd[4];
#pragma unroll
  for (int r = 0; r < 4; r++) dd[r] = __shfl(acc2[4][r], lane & 48) + 1e-6f;
  size_t obase = ((size_t)b * 2048 + c * 128) * 1024 + (size_t)h * 64;
#pragma unroll
  for (int n = 0; n < 4; n++)
#pragma unroll
    for (int r = 0; r < 4; r++){
      int i = w * 16 + ((lane >> 4) << 2) + r;
      int d = n * 16 + (lane & 15);
      aout[obase + (size_t)i * 1024 + d] = f2b(acc2[n][r] / dd[r]);
    }
}

// ---------------- residual + TWO bf16 partials + LayerNorm (P1 may alias outb) ----------------
__global__ __launch_bounds__(256) void ln3_kernel(const float* __restrict__ X1, const u16* __restrict__ P0,
                                                  const u16* P1, const float* __restrict__ g,
                                                  const float* __restrict__ bb,
                                                  float* __restrict__ outf, u16* outb){
  __shared__ float red[2][4];
  int row = blockIdx.x, tid = threadIdx.x, w = tid >> 6, lane = tid & 63;
  size_t ro = (size_t)row * 1024 + tid * 4;
  float4 a = *(const float4*)(X1 + ro);
  ushort4 p0 = *(const ushort4*)(P0 + ro);
  ushort4 p1 = *(const ushort4*)(P1 + ro);
  float x0 = a.x + b2f(p0.x) + b2f(p1.x);
  float x1 = a.y + b2f(p0.y) + b2f(p1.y);
  float x2 = a.z + b2f(p0.z) + b2f(p1.z);
  float x3 = a.w + b2f(p0.w) + b2f(p1.w);
  float s1 = x0 + x1 + x2 + x3;
  float s2 = x0 * x0 + x1 * x1 + x2 * x2 + x3 * x3;
#pragma unroll
  for (int off = 32; off; off >>= 1){ s1 += __shfl_xor(s1, off); s2 += __shfl_xor(s2, off); }
  if (lane == 0){ red[0][w] = s1; red[1][w] = s2; }
  __syncthreads();
  float t1 = red[0][0] + red[0][1] + red[0][2] + red[0][3];
  float t2 = red[1][0] + red[1][1] + red[1][2] + red[1][3];
  float mu = t1 * (1.f / 1024.f);
  float var = t2 * (1.f / 1024.f) - mu * mu;
  float rs = rsqrtf(var + 1e-5f);
  float4 gv = *(const float4*)(g + tid * 4);
  float4 bv = *(const float4*)(bb + tid * 4);
  float o0 = (x0 - mu) * rs * gv.x + bv.x;
  float o1 = (x1 - mu) * rs * gv.y + bv.y;
  float o2 = (x2 - mu) * rs * gv.z + bv.z;
  float o3 = (x3 - mu) * rs * gv.w + bv.w;
  *(float4*)(outf + ro) = make_float4(o0, o1, o2, o3);
  *(ushort4*)(outb + ro) = make_ushort4(f2b(o0), f2b(o1), f2b(o2), f2b(o3));
}

// ---------------- host ----------------
extern "C" void kernel_launch(void* const* d_in, const int* in_sizes, int n_in,
                              void* d_out, int out_size, void* d_ws, size_t ws_size,
                              hipStream_t stream){
  (void)in_sizes; (void)n_in;
  const float* x   = (const float*)d_in[0];
  const float* Wq  = (const float*)d_in[1];
  const float* bq  = (const float*)d_in[2];
  const float* Wk  = (const float*)d_in[3];
  const float* bk  = (const float*)d_in[4];
  const float* Wv  = (const float*)d_in[5];
  const float* bv  = (const float*)d_in[6];
  const float* Wo  = (const float*)d_in[7];
  const float* bo  = (const float*)d_in[8];
  const float* om  = (const float*)d_in[9];
  const float* g1  = (const float*)d_in[10];
  const float* be1 = (const float*)d_in[11];
  const float* W1  = (const float*)d_in[12];
  const float* bf1 = (const float*)d_in[13];
  const float* W2  = (const float*)d_in[14];
  const float* bf2 = (const float*)d_in[15];
  const float* g2  = (const float*)d_in[16];
  const float* be2 = (const float*)d_in[17];

  char* ws = (char*)d_ws;
  size_t off = 0;
  auto alloc = [&](size_t bytes) -> void* {
    void* p = ws + off; off += (bytes + 255) & ~(size_t)255; return p;
  };
  u16* Wcat = (u16*)alloc(3072ull * 1024 * 2);
  u16* Wot  = (u16*)alloc(1024ull * 1024 * 2);
  u16* W1t  = (u16*)alloc(4096ull * 1024 * 2);
  u16* W2t  = (u16*)alloc(1024ull * 4096 * 2);
  u16* omT  = (u16*)alloc(64ull * 64 * 2);
  float* bcat = (float*)alloc(6ull * 3072 * 4);
  float* zbuf = (float*)alloc(1024 * 4);
  u16* Xb  = (u16*)alloc(8192ull * 1024 * 2);
  u16* qb  = (u16*)alloc(131072ull * 64 * 2);   // contiguous qb|kb|vt|Qp for ybuf alias
  u16* kb  = (u16*)alloc(131072ull * 64 * 2);
  u16* vt  = (u16*)alloc(131072ull * 64 * 2);
  u16* Qp  = (u16*)alloc(131072ull * 128 * 2);
  u16* Kp  = (u16*)alloc(131072ull * 128 * 2);
  float* ksum = (float*)alloc(64ull * 16 * 128 * 4);

  if (off > ws_size){
    fillv<<<(out_size + 255) / 256, 256, 0, stream>>>((float*)d_out, (float)(ws_size >> 20), out_size);
    return;
  }

  float* kvbuf  = (float*)qb;            // kv^T f32 32MB over qb+kb (dead after phi2)
  u16*  ybuf   = qb;                    // FFN intermediate bf16 [8192][4096] over qb..Qp[0:16MB]
  u16*  wooutb = Qp;                    // Wo partial kz=0 bf16 (Qp dead after attn)
  u16*  wop1   = Qp + 8388608;          // Wo partial kz=1 (dead before W2 writes here)
  u16*  w2outb = Qp + 8388608;          // W2 partial kz=0 bf16 (same region, later lifetime)
  // W2 partial kz=1 lives in Xb (h1-bf16 dead after W1; ln3 reads it then rewrites Xb)
  float* h1     = (float*)Kp;            // residual-1 LN out f32 (Kp dead after attn)
  float* resid  = (float*)d_out;         // persistent f32 activation stream

  cvt16<<<8192, 256, 0, stream>>>(x, Xb);
  catbias<<<72, 256, 0, stream>>>(bq, bk, bv, bcat);
  fillv<<<4, 256, 0, stream>>>(zbuf, 0.f, 1024);

  const float* Xsrc = x;
  for (int l = 0; l < 6; l++){
    size_t o1k = (size_t)l * 1024 * 1024;
    size_t o4k = (size_t)l * 4096 * 1024;
    wtrans<<<dim3(32, 32), 256, 0, stream>>>(Wq + o1k, Wcat, 1024, 1024, 1.f);
    wtrans<<<dim3(32, 32), 256, 0, stream>>>(Wk + o1k, Wcat + 1048576, 1024, 1024, 1.f);
    wtrans<<<dim3(32, 32), 256, 0, stream>>>(Wv + o1k, Wcat + 2097152, 1024, 1024, 1.f);
    wtrans<<<dim3(32, 32), 256, 0, stream>>>(Wo + o1k, Wot, 1024, 1024, 1.f);
    wtrans<<<dim3(32, 128), 256, 0, stream>>>(W1 + o4k, W1t, 1024, 4096, 1.f);
    wtrans<<<dim3(128, 32), 256, 0, stream>>>(W2 + o4k, W2t, 4096, 1024, 1.f);
    wtrans<<<dim3(2, 2), 256, 0, stream>>>(om + (size_t)l * 4096, omT, 64, 64, 0.35355339059327373f);

    gemm_bt<5><<<dim3(24, 64), 256, 0, stream>>>(Xb, Wcat, bcat + l * 3072, qb, 8192, 3072, 1024, 1024, 1024);
    phi2<<<2048, 256, 0, stream>>>(qb, kb, omT, Qp, Kp);
    kvchunk<<<1024, 256, 0, stream>>>(Kp, vt, kvbuf, ksum);
    kvscan<<<dim3(64, 9), 256, 0, stream>>>(kvbuf, ksum);
    attn_fused<<<1024, 512, 0, stream>>>(Qp, Kp, vt, kvbuf, ksum, Xb);
    // Wo split-K=2 on the fat-phase template: kz=0 -> wooutb (+bias), kz=1 -> wop1 (zero bias)
    gemm8pk<<<dim3(256), 512, 0, stream>>>(Xb, Wot, bo + l * 1024, zbuf, wooutb, wop1,
                                           8192, 1024, 512, 1024, 1024);
    ln3_kernel<<<8192, 256, 0, stream>>>(Xsrc, wooutb, wop1, g1 + l * 1024, be1 + l * 1024, h1, Xb);
    gemm8p<2><<<dim3(16, 32), 512, 0, stream>>>(Xb, W1t, bf1 + l * 4096, ybuf, 8192, 4096, 1024, 1024, 1024);
    gemm8pk<<<dim3(256), 512, 0, stream>>>(ybuf, W2t, bf2 + l * 1024, zbuf, w2outb, Xb,
                                           8192, 1024, 2048, 4096, 4096);
    ln3_kernel<<<8192, 256, 0, stream>>>(h1, w2outb, Xb, g2 + l * 1024, be2 + l * 1024, resid, Xb);
    Xsrc = resid;
  }
}

// Round 15
// 2508.400 us; speedup vs baseline: 1.0360x; 1.0360x over previous
//
#include <hip/hip_runtime.h>

typedef unsigned short u16;
typedef __attribute__((ext_vector_type(8))) short bf16x8;
typedef __attribute__((ext_vector_type(4))) float f32x4;

#define DEV __device__ __forceinline__

DEV float b2f(u16 h){ return __uint_as_float(((unsigned)h) << 16); }
DEV u16 f2b(float f){ unsigned u = __float_as_uint(f); u += 0x7FFFu + ((u >> 16) & 1u); return (u16)(u >> 16); }

DEV void gload16(const u16* g, u16* l){
  __builtin_amdgcn_global_load_lds((const __attribute__((address_space(1))) unsigned*)g,
                                   (__attribute__((address_space(3))) unsigned*)l, 16, 0, 0);
}

// ---------------- merged per-layer weight transpose: 7 tensors in one launch ----------------
// ranges: [0,4096) Wq/Wk/Wv/Wo (1024x1024) ; [4096,8192) W1 (K1024,N4096) ;
//         [8192,12288) W2 (K4096,N1024) ; [12288,12292) omega (64x64, scaled)
__global__ __launch_bounds__(256) void wtrans7(const float* __restrict__ Wq, const float* __restrict__ Wk,
                                               const float* __restrict__ Wv, const float* __restrict__ Wo,
                                               const float* __restrict__ W1, const float* __restrict__ W2,
                                               const float* __restrict__ om,
                                               u16* __restrict__ Wcat, u16* __restrict__ Wot,
                                               u16* __restrict__ W1t, u16* __restrict__ W2t,
                                               u16* __restrict__ omT){
  __shared__ float tile[32][33];
  int id = blockIdx.x;
  const float* src; u16* dst; int K, N, kb, nb; float scale = 1.f;
  if (id < 4096){
    int wsel = id >> 10, loc = id & 1023;
    kb = loc >> 5; nb = loc & 31; K = 1024; N = 1024;
    src = (wsel == 0) ? Wq : (wsel == 1) ? Wk : (wsel == 2) ? Wv : Wo;
    dst = (wsel < 3) ? Wcat + (size_t)wsel * 1048576 : Wot;
  } else if (id < 8192){
    int loc = id - 4096;
    kb = loc & 31; nb = loc >> 5; K = 1024; N = 4096;
    src = W1; dst = W1t;
  } else if (id < 12288){
    int loc = id - 8192;
    kb = loc & 127; nb = loc >> 7; K = 4096; N = 1024;
    src = W2; dst = W2t;
  } else {
    int loc = id - 12288;
    kb = loc & 1; nb = loc >> 1; K = 64; N = 64;
    src = om; dst = omT; scale = 0.35355339059327373f;
  }
  int k0 = kb * 32, n0 = nb * 32;
  int tid = threadIdx.x;
#pragma unroll
  for (int i = 0; i < 4; i++){
    int idx = tid + i * 256;
    int r = idx >> 5, c = idx & 31;
    tile[r][c] = src[(size_t)(k0 + r) * N + n0 + c];
  }
  __syncthreads();
#pragma unroll
  for (int i = 0; i < 4; i++){
    int idx = tid + i * 256;
    int r = idx >> 5, c = idx & 31;
    dst[(size_t)(n0 + r) * K + k0 + c] = f2b(tile[c][r] * scale);
  }
}

// ---------------- f32 -> bf16 convert ----------------
__global__ __launch_bounds__(256) void cvt16(const float* __restrict__ src, u16* __restrict__ dst){
  size_t i = ((size_t)blockIdx.x * 256 + threadIdx.x) * 4;
  float4 f = *(const float4*)(src + i);
  ushort4 o = make_ushort4(f2b(f.x), f2b(f.y), f2b(f.z), f2b(f.w));
  *(ushort4*)(dst + i) = o;
}

// ---------------- bias concat (all layers): [6][3072] = bq|bk|bv ----------------
__global__ void catbias(const float* __restrict__ bq, const float* __restrict__ bk,
                        const float* __restrict__ bv, float* __restrict__ bcat){
  int i = blockIdx.x * 256 + threadIdx.x;
  if (i >= 6 * 3072) return;
  int l = i / 3072, j = i % 3072;
  float v = (j < 1024) ? bq[l * 1024 + j] : (j < 2048) ? bk[l * 1024 + j - 1024] : bv[l * 1024 + j - 2048];
  bcat[i] = v;
}

// ---------------- diagnostic / zero fill ----------------
__global__ void fillv(float* __restrict__ p, float v, int n){
  int i = blockIdx.x * 256 + threadIdx.x;
  if (i < n) p[i] = v;
}

// ---------------- 128^2 bf16 MFMA GEMM (gload_lds dbuf + counted vmcnt + XCD swizzle) ----------------
// EPI 2: relu bf16 [M,N] ; EPI 5: fused QKV ; EPI 6: bf16 [M,N]
DEV int swz(int r){ return (r & 3) ^ ((r >> 2) & 3); }

template<int EPI>
__global__ __launch_bounds__(256) void gemm_bt(const u16* __restrict__ A, const u16* __restrict__ Bt,
                                               const float* __restrict__ bias, void* __restrict__ outp,
                                               int M, int N, int K, int ldA, int ldB){
  __shared__ __align__(16) u16 As[2][4096];
  __shared__ __align__(16) u16 Bs[2][4096];
  const int tid = threadIdx.x;
  const int lane = tid & 63;
  const int w = tid >> 6;
  const int wm = w >> 1, wn = w & 1;
  int nx = gridDim.x;
  int nwg = nx * gridDim.y;
  int lin = blockIdx.y * nx + blockIdx.x;
  int cpx = nwg >> 3;
  int sw = (lin & 7) * cpx + (lin >> 3);
  const int m0 = (sw / nx) * 128;
  const int n0 = (sw % nx) * 128;

  int r0 = tid >> 2, c0 = tid & 3;
  int r1 = r0 + 64;
  int cs0 = c0 ^ swz(r0);
  int cs1 = c0 ^ swz(r1);
  const u16* ag0 = A + (size_t)(m0 + r0) * ldA + cs0 * 8;
  const u16* ag1 = A + (size_t)(m0 + r1) * ldA + cs1 * 8;
  const u16* bg0 = Bt + (size_t)(n0 + r0) * ldB + cs0 * 8;
  const u16* bg1 = Bt + (size_t)(n0 + r1) * ldB + cs1 * 8;

  f32x4 acc[4][4] = {};
  const int KT = K >> 5;

  gload16(ag0, &As[0][w * 512]);
  gload16(ag1, &As[0][2048 + w * 512]);
  gload16(bg0, &Bs[0][w * 512]);
  gload16(bg1, &Bs[0][2048 + w * 512]);

  for (int kt = 0; kt < KT; kt++){
    int cur = kt & 1;
    if (kt + 1 < KT){
      int ko = (kt + 1) << 5;
      gload16(ag0 + ko, &As[cur ^ 1][w * 512]);
      gload16(ag1 + ko, &As[cur ^ 1][2048 + w * 512]);
      gload16(bg0 + ko, &Bs[cur ^ 1][w * 512]);
      gload16(bg1 + ko, &Bs[cur ^ 1][2048 + w * 512]);
      asm volatile("s_waitcnt vmcnt(4)" ::: "memory");
    } else {
      asm volatile("s_waitcnt vmcnt(0)" ::: "memory");
    }
    __builtin_amdgcn_s_barrier();
    bf16x8 fa[4], fb[4];
#pragma unroll
    for (int m = 0; m < 4; m++){
      int row = wm * 64 + m * 16 + (lane & 15);
      int cc = (lane >> 4) ^ swz(row);
      fa[m] = *(const bf16x8*)(&As[cur][row * 32 + cc * 8]);
    }
#pragma unroll
    for (int n = 0; n < 4; n++){
      int row = wn * 64 + n * 16 + (lane & 15);
      int cc = (lane >> 4) ^ swz(row);
      fb[n] = *(const bf16x8*)(&Bs[cur][row * 32 + cc * 8]);
    }
#pragma unroll
    for (int m = 0; m < 4; m++)
#pragma unroll
      for (int n = 0; n < 4; n++)
        acc[m][n] = __builtin_amdgcn_mfma_f32_16x16x32_bf16(fa[m], fb[n], acc[m][n], 0, 0, 0);
    asm volatile("s_waitcnt lgkmcnt(0)" ::: "memory");
    __builtin_amdgcn_s_barrier();
  }

#pragma unroll
  for (int m = 0; m < 4; m++){
    int rowb = m0 + wm * 64 + m * 16 + ((lane >> 4) << 2);
#pragma unroll
    for (int n = 0; n < 4; n++){
      int col = n0 + wn * 64 + n * 16 + (lane & 15);
      float bv = bias[col];
      if (EPI == 5 && col >= 2048){
        int cv = col - 2048, hh = cv >> 6, dh = cv & 63;
        int bIdx = rowb >> 11, s4 = rowb & 2047;
        ushort4 pk = make_ushort4(f2b(acc[m][n][0] + bv), f2b(acc[m][n][1] + bv),
                                  f2b(acc[m][n][2] + bv), f2b(acc[m][n][3] + bv));
        *(ushort4*)&((u16*)outp + 16777216)[((size_t)(bIdx * 16 + hh) * 64 + dh) * 2048 + s4] = pk;
      } else {
#pragma unroll
        for (int r = 0; r < 4; r++){
          float v = acc[m][n][r] + bv;
          int rr = rowb + r;
          if (EPI == 5){
            u16* dst0 = (u16*)outp + (col < 1024 ? 0 : 8388608);
            int cv = col & 1023, hh = cv >> 6, dh = cv & 63;
            int bIdx = rr >> 11, s = rr & 2047;
            dst0[(((size_t)(bIdx * 16 + hh) * 2048 + s) << 6) + dh] = f2b(v);
          } else if (EPI == 2){
            ((u16*)outp)[(size_t)rr * N + col] = f2b(v > 0.f ? v : 0.f);
          } else {
            ((u16*)outp)[(size_t)rr * N + col] = f2b(v);
          }
        }
      }
    }
  }
}

// ---------------- 8-phase 256^2 GEMM (m201 template): BK=64, K-half subtiles, counted vmcnt ----------------
// EPI 2: relu bf16 ; EPI 6: bf16   (scalar epilogue)
template<int EPI>
__global__ __launch_bounds__(512, 1) void gemm8p(const u16* __restrict__ A, const u16* __restrict__ Bt,
                                                 const float* __restrict__ bias, void* __restrict__ outp,
                                                 int M, int N, int K, int ldA, int ldB){
  __shared__ __align__(16) u16 As[2][16384];
  __shared__ __align__(16) u16 Bs[2][16384];
  const int tid = threadIdx.x;
  const int lane = tid & 63;
  const int w = tid >> 6;
  const int wm = w >> 2, wn = w & 3;
  int nx = gridDim.x;
  int nwg = nx * gridDim.y;
  int lin = blockIdx.y * nx + blockIdx.x;
  int cpx = nwg >> 3;
  int sw = (lin & 7) * cpx + (lin >> 3);
  const int m0 = (sw / nx) * 256;
  const int n0 = (sw % nx) * 256;

  const int id1 = 512 + tid;
  const int r0 = tid >> 2, c20 = tid & 3;
  const int r1 = id1 >> 2, c21 = id1 & 3;
  const int cs0 = c20 ^ ((r0 >> 1) & 3);
  const int cs1 = c21 ^ ((r1 >> 1) & 3);
  const u16* Ag0 = A + (size_t)(m0 + r0) * ldA + cs0 * 8;
  const u16* Ag1 = A + (size_t)(m0 + r1) * ldA + cs1 * 8;
  const u16* Bg0 = Bt + (size_t)(n0 + r0) * ldB + cs0 * 8;
  const u16* Bg1 = Bt + (size_t)(n0 + r1) * ldB + cs1 * 8;

  f32x4 acc[8][4] = {};
  const int KT = K >> 6;

  auto stA = [&](int buf, int kt, int ks){
    int kc = kt * 64 + ks * 32;
    gload16(Ag0 + kc, &As[buf][ks * 8192 + w * 512]);
    gload16(Ag1 + kc, &As[buf][ks * 8192 + 4096 + w * 512]);
  };
  auto stB = [&](int buf, int kt, int ks){
    int kc = kt * 64 + ks * 32;
    gload16(Bg0 + kc, &Bs[buf][ks * 8192 + w * 512]);
    gload16(Bg1 + kc, &Bs[buf][ks * 8192 + 4096 + w * 512]);
  };

  stA(0, 0, 0); stB(0, 0, 0); stA(0, 0, 1); stB(0, 0, 1);

  for (int t = 0; t < KT; t++){
    int c = t & 1, nb = c ^ 1;
    bool pf = (t + 1 < KT);
    asm volatile("s_waitcnt vmcnt(4)" ::: "memory");
    __builtin_amdgcn_s_barrier();

#pragma unroll
    for (int ks = 0; ks < 2; ks++){
      if (ks == 1){
        if (pf) asm volatile("s_waitcnt vmcnt(4)" ::: "memory");
        else    asm volatile("s_waitcnt vmcnt(0)" ::: "memory");
        __builtin_amdgcn_s_barrier();
      }
      if (pf){ if (ks == 0) stA(nb, t + 1, 0); else stA(nb, t + 1, 1); }
      bf16x8 fa[8], fb[2];
#pragma unroll
      for (int m = 0; m < 8; m++){
        int row = wm * 128 + m * 16 + (lane & 15);
        int slot = (lane >> 4) ^ ((row >> 1) & 3);
        fa[m] = *(const bf16x8*)(&As[c][ks * 8192 + row * 32 + slot * 8]);
      }
#pragma unroll
      for (int nn = 0; nn < 2; nn++){
        int row = wn * 64 + nn * 16 + (lane & 15);
        int slot = (lane >> 4) ^ ((row >> 1) & 3);
        fb[nn] = *(const bf16x8*)(&Bs[c][ks * 8192 + row * 32 + slot * 8]);
      }
      __builtin_amdgcn_s_setprio(1);
#pragma unroll
      for (int m = 0; m < 8; m++)
#pragma unroll
        for (int nn = 0; nn < 2; nn++)
          acc[m][nn] = __builtin_amdgcn_mfma_f32_16x16x32_bf16(fa[m], fb[nn], acc[m][nn], 0, 0, 0);
      __builtin_amdgcn_s_setprio(0);
      if (pf){ if (ks == 0) stB(nb, t + 1, 0); else stB(nb, t + 1, 1); }
#pragma unroll
      for (int nn = 0; nn < 2; nn++){
        int row = wn * 64 + 32 + nn * 16 + (lane & 15);
        int slot = (lane >> 4) ^ ((row >> 1) & 3);
        fb[nn] = *(const bf16x8*)(&Bs[c][ks * 8192 + row * 32 + slot * 8]);
      }
      __builtin_amdgcn_s_setprio(1);
#pragma unroll
      for (int m = 0; m < 8; m++)
#pragma unroll
        for (int nn = 0; nn < 2; nn++)
          acc[m][2 + nn] = __builtin_amdgcn_mfma_f32_16x16x32_bf16(fa[m], fb[nn], acc[m][2 + nn], 0, 0, 0);
      __builtin_amdgcn_s_setprio(0);
    }
  }

#pragma unroll
  for (int m = 0; m < 8; m++){
    int rowb = m0 + wm * 128 + m * 16 + ((lane >> 4) << 2);
#pragma unroll
    for (int n = 0; n < 4; n++){
      int col = n0 + wn * 64 + n * 16 + (lane & 15);
      float bv = bias[col];
#pragma unroll
      for (int r = 0; r < 4; r++){
        float v = acc[m][n][r] + bv;
        int rr = rowb + r;
        if (EPI == 2) ((u16*)outp)[(size_t)rr * N + col] = f2b(v > 0.f ? v : 0.f);
        else          ((u16*)outp)[(size_t)rr * N + col] = f2b(v);
      }
    }
  }
}

// ---------------- 8-phase 256^2 split-K GEMM: 256 blocks = (4 n)x(32 m)x(2 kz), bf16 partials ----------------
__global__ __launch_bounds__(512, 1) void gemm8pk(const u16* __restrict__ A, const u16* __restrict__ Bt,
                                                  const float* __restrict__ bias0, const float* __restrict__ bias1,
                                                  u16* __restrict__ out0, u16* __restrict__ out1,
                                                  int M, int N, int Khalf, int ldA, int ldB){
  __shared__ __align__(16) u16 As[2][16384];
  __shared__ __align__(16) u16 Bs[2][16384];
  const int tid = threadIdx.x;
  const int lane = tid & 63;
  const int w = tid >> 6;
  const int wm = w >> 2, wn = w & 3;
  int lin = blockIdx.x;               // 256 blocks
  int cpx = gridDim.x >> 3;
  int sw = (lin & 7) * cpx + (lin >> 3);
  const int kz = sw & 1;
  const int t2 = sw >> 1;
  const int n0 = (t2 & 3) * 256;
  const int m0 = (t2 >> 2) * 256;
  const u16* Ab = A + kz * Khalf;
  const u16* Bb = Bt + kz * Khalf;
  u16* outp = kz ? out1 : out0;
  const float* bias = kz ? bias1 : bias0;

  const int id1 = 512 + tid;
  const int r0 = tid >> 2, c20 = tid & 3;
  const int r1 = id1 >> 2, c21 = id1 & 3;
  const int cs0 = c20 ^ ((r0 >> 1) & 3);
  const int cs1 = c21 ^ ((r1 >> 1) & 3);
  const u16* Ag0 = Ab + (size_t)(m0 + r0) * ldA + cs0 * 8;
  const u16* Ag1 = Ab + (size_t)(m0 + r1) * ldA + cs1 * 8;
  const u16* Bg0 = Bb + (size_t)(n0 + r0) * ldB + cs0 * 8;
  const u16* Bg1 = Bb + (size_t)(n0 + r1) * ldB + cs1 * 8;

  f32x4 acc[8][4] = {};
  const int KT = Khalf >> 6;

  auto stA = [&](int buf, int kt, int ks){
    int kc = kt * 64 + ks * 32;
    gload16(Ag0 + kc, &As[buf][ks * 8192 + w * 512]);
    gload16(Ag1 + kc, &As[buf][ks * 8192 + 4096 + w * 512]);
  };
  auto stB = [&](int buf, int kt, int ks){
    int kc = kt * 64 + ks * 32;
    gload16(Bg0 + kc, &Bs[buf][ks * 8192 + w * 512]);
    gload16(Bg1 + kc, &Bs[buf][ks * 8192 + 4096 + w * 512]);
  };

  stA(0, 0, 0); stB(0, 0, 0); stA(0, 0, 1); stB(0, 0, 1);

  for (int t = 0; t < KT; t++){
    int c = t & 1, nb = c ^ 1;
    bool pf = (t + 1 < KT);
    asm volatile("s_waitcnt vmcnt(4)" ::: "memory");
    __builtin_amdgcn_s_barrier();

#pragma unroll
    for (int ks = 0; ks < 2; ks++){
      if (ks == 1){
        if (pf) asm volatile("s_waitcnt vmcnt(4)" ::: "memory");
        else    asm volatile("s_waitcnt vmcnt(0)" ::: "memory");
        __builtin_amdgcn_s_barrier();
      }
      if (pf){ if (ks == 0) stA(nb, t + 1, 0); else stA(nb, t + 1, 1); }
      bf16x8 fa[8], fb[2];
#pragma unroll
      for (int m = 0; m < 8; m++){
        int row = wm * 128 + m * 16 + (lane & 15);
        int slot = (lane >> 4) ^ ((row >> 1) & 3);
        fa[m] = *(const bf16x8*)(&As[c][ks * 8192 + row * 32 + slot * 8]);
      }
#pragma unroll
      for (int nn = 0; nn < 2; nn++){
        int row = wn * 64 + nn * 16 + (lane & 15);
        int slot = (lane >> 4) ^ ((row >> 1) & 3);
        fb[nn] = *(const bf16x8*)(&Bs[c][ks * 8192 + row * 32 + slot * 8]);
      }
      __builtin_amdgcn_s_setprio(1);
#pragma unroll
      for (int m = 0; m < 8; m++)
#pragma unroll
        for (int nn = 0; nn < 2; nn++)
          acc[m][nn] = __builtin_amdgcn_mfma_f32_16x16x32_bf16(fa[m], fb[nn], acc[m][nn], 0, 0, 0);
      __builtin_amdgcn_s_setprio(0);
      if (pf){ if (ks == 0) stB(nb, t + 1, 0); else stB(nb, t + 1, 1); }
#pragma unroll
      for (int nn = 0; nn < 2; nn++){
        int row = wn * 64 + 32 + nn * 16 + (lane & 15);
        int slot = (lane >> 4) ^ ((row >> 1) & 3);
        fb[nn] = *(const bf16x8*)(&Bs[c][ks * 8192 + row * 32 + slot * 8]);
      }
      __builtin_amdgcn_s_setprio(1);
#pragma unroll
      for (int m = 0; m < 8; m++)
#pragma unroll
        for (int nn = 0; nn < 2; nn++)
          acc[m][2 + nn] = __builtin_amdgcn_mfma_f32_16x16x32_bf16(fa[m], fb[nn], acc[m][2 + nn], 0, 0, 0);
      __builtin_amdgcn_s_setprio(0);
    }
  }

#pragma unroll
  for (int m = 0; m < 8; m++){
    int rowb = m0 + wm * 128 + m * 16 + ((lane >> 4) << 2);
#pragma unroll
    for (int n = 0; n < 4; n++){
      int col = n0 + wn * 64 + n * 16 + (lane & 15);
      float bv = bias[col];
#pragma unroll
      for (int r = 0; r < 4; r++)
        outp[(size_t)(rowb + r) * N + col] = f2b(acc[m][n][r] + bv);
    }
  }
}

// ---------------- FAVOR phi v2 (MFMA) ----------------
__global__ __launch_bounds__(256) void phi2(const u16* __restrict__ qb, const u16* __restrict__ kb,
                                            const u16* __restrict__ omT,
                                            u16* __restrict__ Qp, u16* __restrict__ Kp){
  __shared__ __align__(16) u16 qs[128 * 64];
  __shared__ __align__(16) u16 wl[64 * 64];
  __shared__ __align__(16) u16 ph[128 * 128];
  __shared__ float part[2][128];
  __shared__ float nrm[128];
  int tid = threadIdx.x, w = tid >> 6, lane = tid & 63;
  int blk = blockIdx.x;
  const u16* src; u16* dst; int row0;
  if (blk < 1024){ src = qb; dst = Qp; row0 = blk * 128; }
  else           { src = kb; dst = Kp; row0 = (blk - 1024) * 128; }
  const u16* g = src + (size_t)row0 * 64;
#pragma unroll
  for (int i = 0; i < 4; i++){
    int id = tid * 4 + i;
    int r = id >> 3, kc = id & 7;
    *(bf16x8*)(qs + r * 64 + ((kc ^ (r & 7)) << 3)) = *(const bf16x8*)(g + r * 64 + kc * 8);
  }
#pragma unroll
  for (int i = 0; i < 2; i++){
    int id = tid * 2 + i;
    int m = id >> 3, kc = id & 7;
    *(bf16x8*)(wl + m * 64 + ((kc ^ (m & 7)) << 3)) = *(const bf16x8*)(omT + id * 8);
  }
  __syncthreads();
  {
    int r = tid & 127, half = tid >> 7;
    float s = 0.f;
#pragma unroll
    for (int j = 0; j < 4; j++){
      int kc = half * 4 + j;
      bf16x8 v = *(const bf16x8*)(qs + r * 64 + ((kc ^ (r & 7)) << 3));
#pragma unroll
      for (int e = 0; e < 8; e++){ float f = b2f((u16)v[e]); s += f * f; }
    }
    part[half][r] = s;
  }
  __syncthreads();
  if (tid < 128) nrm[tid] = 0.0625f * (part[0][tid] + part[1][tid]);
  __syncthreads();
  f32x4 acc[2][4] = {};
#pragma unroll
  for (int kt = 0; kt < 2; kt++){
    int kc = kt * 4 + (lane >> 4);
    bf16x8 fa[2], fb[4];
#pragma unroll
    for (int mt = 0; mt < 2; mt++){
      int r = w * 32 + mt * 16 + (lane & 15);
      fa[mt] = *(const bf16x8*)(qs + r * 64 + ((kc ^ (r & 7)) << 3));
    }
#pragma unroll
    for (int nt = 0; nt < 4; nt++){
      int m = nt * 16 + (lane & 15);
      fb[nt] = *(const bf16x8*)(wl + m * 64 + ((kc ^ (m & 7)) << 3));
    }
#pragma unroll
    for (int mt = 0; mt < 2; mt++)
#pragma unroll
      for (int nt = 0; nt < 4; nt++)
        acc[mt][nt] = __builtin_amdgcn_mfma_f32_16x16x32_bf16(fa[mt], fb[nt], acc[mt][nt], 0, 0, 0);
  }
  const float LNC = -2.4260151319598086f;   // ln(128^-0.5)
#pragma unroll
  for (int mt = 0; mt < 2; mt++)
#pragma unroll
    for (int nt = 0; nt < 4; nt++)
#pragma unroll
      for (int r4 = 0; r4 < 4; r4++){
        int r = w * 32 + mt * 16 + ((lane >> 4) << 2) + r4;
        int m = nt * 16 + (lane & 15);
        float u = acc[mt][nt][r4];
        float nr = nrm[r];
        ph[r * 128 + m]      = f2b(__expf(u - nr + LNC));
        ph[r * 128 + 64 + m] = f2b(__expf(-u - nr + LNC));
      }
  __syncthreads();
  u16* go = dst + (size_t)row0 * 128;
#pragma unroll
  for (int i = 0; i < 8; i++){
    int id = i * 256 + tid;
    *(bf16x8*)(go + id * 8) = *(const bf16x8*)(ph + id * 8);
  }
}

// ---------------- per-chunk kv^T[d][m], ksum [128m] ----------------
__global__ __launch_bounds__(256) void kvchunk(const u16* __restrict__ Kp, const u16* __restrict__ vt,
                                               float* __restrict__ kv, float* __restrict__ ksum){
  __shared__ __align__(16) u16 Ks[128 * 128];
  __shared__ __align__(16) u16 Vst[64 * 128];
  int blk = blockIdx.x; int bh = blk >> 4, c = blk & 15;
  int tid = threadIdx.x;
  size_t base = (size_t)bh * 2048 + c * 128;
  const u16* Kc = Kp + base * 128;
  const u16* vtc = vt + (size_t)bh * 64 * 2048 + c * 128;
  {
    int j = tid >> 1, half = tid & 1;
#pragma unroll
    for (int i = 0; i < 8; i++)
      *(bf16x8*)(Ks + j * 128 + half * 64 + i * 8) = *(const bf16x8*)(Kc + j * 128 + half * 64 + i * 8);
#pragma unroll
    for (int i = 0; i < 4; i++){
      int id = tid * 4 + i;
      int d = id >> 4, mc = id & 15;
      *(bf16x8*)(Vst + d * 128 + mc * 8) = *(const bf16x8*)(vtc + (size_t)d * 2048 + mc * 8);
    }
  }
  __syncthreads();
  int tm = tid & 15, td = tid >> 4;
  int mbase = tm * 8, dbase = td * 4;
  float acc[8][4] = {};
  float ks[8] = {};
  for (int i = 0; i < 128; i++){
    bf16x8 kk = *(const bf16x8*)(Ks + i * 128 + mbase);
    float kf[8];
#pragma unroll
    for (int e = 0; e < 8; e++) kf[e] = b2f((u16)kk[e]);
    float vf[4];
#pragma unroll
    for (int e = 0; e < 4; e++) vf[e] = b2f(Vst[(dbase + e) * 128 + i]);
#pragma unroll
    for (int a = 0; a < 8; a++){
      ks[a] += kf[a];
#pragma unroll
      for (int bb = 0; bb < 4; bb++) acc[a][bb] += kf[a] * vf[bb];
    }
  }
  float* kvout = kv + ((size_t)bh * 16 + c) * 8192;
#pragma unroll
  for (int a = 0; a < 8; a++)
#pragma unroll
    for (int bb = 0; bb < 4; bb++)
      kvout[(size_t)(dbase + bb) * 128 + mbase + a] = acc[a][bb];
  if (td == 0){
    float* kso = ksum + ((size_t)bh * 16 + c) * 128;
#pragma unroll
    for (int a = 0; a < 8; a++) kso[mbase + a] = ks[a];
  }
}

// ---------------- exclusive prefix over chunks (in place) ----------------
__global__ __launch_bounds__(256) void kvscan(float* __restrict__ kv, float* __restrict__ ksum){
  int bh = blockIdx.x;
  int p = blockIdx.y;
  int tid = threadIdx.x;
  if (p < 8){
    size_t base = (size_t)bh * 16 * 8192;
    int idx0 = p * 1024 + tid;
    for (int rep = 0; rep < 4; rep++){
      int idx = idx0 + rep * 256;
      float run = 0.f;
#pragma unroll
      for (int c = 0; c < 16; c++){
        size_t off = base + (size_t)c * 8192 + idx;
        float v = kv[off]; kv[off] = run; run += v;
      }
    }
  } else if (tid < 128){
    size_t base = (size_t)bh * 16 * 128;
    float run = 0.f;
#pragma unroll
    for (int c = 0; c < 16; c++){
      size_t off = base + c * 128 + tid;
      float v = ksum[off]; ksum[off] = run; run += v;
    }
  }
}

// ---------------- MFMA fused attention ----------------
__global__ __launch_bounds__(512) void attn_fused(const u16* __restrict__ Qp, const u16* __restrict__ Kp,
                                                  const u16* __restrict__ vt, const float* __restrict__ kvp,
                                                  const float* __restrict__ ksum, u16* __restrict__ aout){
  __shared__ __align__(16) u16 sm[53248];
  int blk = blockIdx.x, bh = blk >> 4, c = blk & 15;
  int b = bh >> 4, h = bh & 15;
  int tid = threadIdx.x, w = tid >> 6, lane = tid & 63;
  size_t base = (size_t)bh * 2048 + c * 128;
  const u16* Qc = Qp + base * 128;
  const u16* Kc = Kp + base * 128;
  const u16* vtc = vt + (size_t)bh * 64 * 2048 + c * 128;
  const float* kvc = kvp + ((size_t)bh * 16 + c) * 8192;
  const float* ksc = ksum + ((size_t)bh * 16 + c) * 128;
  u16* Qs = sm;
  u16* Ks = sm + 16384;
  u16* B2 = sm + 32768;

#pragma unroll
  for (int i = 0; i < 4; i++){
    int id = tid * 4 + i;
    int r = id >> 4, kc = id & 15;
    int swo = (kc ^ (r & 15)) << 3;
    *(bf16x8*)(Qs + r * 128 + swo) = *(const bf16x8*)(Qc + (size_t)r * 128 + kc * 8);
    *(bf16x8*)(Ks + r * 128 + swo) = *(const bf16x8*)(Kc + (size_t)r * 128 + kc * 8);
  }
#pragma unroll
  for (int i = 0; i < 2; i++){
    int id = tid * 2 + i;
    int d = id >> 4, kc = id & 15;
    *(bf16x8*)(B2 + d * 256 + ((kc ^ (d & 31)) << 3)) = *(const bf16x8*)(vtc + (size_t)d * 2048 + kc * 8);
  }
#pragma unroll
  for (int i = 0; i < 2; i++){
    int id = tid * 2 + i;
    int d = id >> 4, mc = id & 15;
    const float* s8 = kvc + d * 128 + mc * 8;
    float4 f0 = *(const float4*)(s8);
    float4 f1 = *(const float4*)(s8 + 4);
    bf16x8 pk;
    pk[0] = (short)f2b(f0.x); pk[1] = (short)f2b(f0.y); pk[2] = (short)f2b(f0.z); pk[3] = (short)f2b(f0.w);
    pk[4] = (short)f2b(f1.x); pk[5] = (short)f2b(f1.y); pk[6] = (short)f2b(f1.z); pk[7] = (short)f2b(f1.w);
    int kc = 16 + mc;
    *(bf16x8*)(B2 + d * 256 + ((kc ^ (d & 31)) << 3)) = pk;
  }
  {
    int row = 64 + (tid >> 5), kc = tid & 31;
    bf16x8 pk = {};
    if (row == 64){
      if (kc < 16){
#pragma unroll
        for (int e = 0; e < 8; e++) pk[e] = (short)0x3F80;
      } else {
        const float* s8 = ksc + (kc - 16) * 8;
        float4 f0 = *(const float4*)(s8);
        float4 f1 = *(const float4*)(s8 + 4);
        pk[0] = (short)f2b(f0.x); pk[1] = (short)f2b(f0.y); pk[2] = (short)f2b(f0.z); pk[3] = (short)f2b(f0.w);
        pk[4] = (short)f2b(f1.x); pk[5] = (short)f2b(f1.y); pk[6] = (short)f2b(f1.z); pk[7] = (short)f2b(f1.w);
      }
    }
    *(bf16x8*)(B2 + row * 256 + ((kc ^ (row & 31)) << 3)) = pk;
  }
  __syncthreads();

  int wm = w >> 2, wn = w & 3;
  f32x4 acc1[4][2] = {};
#pragma unroll
  for (int kk = 0; kk < 4; kk++){
    int kc = kk * 4 + (lane >> 4);
    bf16x8 fa[4], fb[2];
#pragma unroll
    for (int m = 0; m < 4; m++){
      int row = wm * 64 + m * 16 + (lane & 15);
      fa[m] = *(const bf16x8*)(Qs + row * 128 + ((kc ^ (row & 15)) << 3));
    }
#pragma unroll
    for (int n = 0; n < 2; n++){
      int row = wn * 32 + n * 16 + (lane & 15);
      fb[n] = *(const bf16x8*)(Ks + row * 128 + ((kc ^ (row & 15)) << 3));
    }
#pragma unroll
    for (int m = 0; m < 4; m++)
#pragma unroll
      for (int n = 0; n < 2; n++)
        acc1[m][n] = __builtin_amdgcn_mfma_f32_16x16x32_bf16(fa[m], fb[n], acc1[m][n], 0, 0, 0);
  }
  __syncthreads();

#pragma unroll
  for (int m = 0; m < 4; m++)
#pragma unroll
    for (int n = 0; n < 2; n++)
#pragma unroll
      for (int r = 0; r < 4; r++){
        int i = wm * 64 + m * 16 + ((lane >> 4) << 2) + r;
        int j = wn * 32 + n * 16 + (lane & 15);
        float v = (j <= i) ? acc1[m][n][r] : 0.f;
        Ks[i * 128 + (((j >> 3) ^ (i & 15)) << 3) + (j & 7)] = f2b(v);
      }
  __syncthreads();

  f32x4 acc2[5] = {};
#pragma unroll
  for (int kk = 0; kk < 8; kk++){
    int kc = kk * 4 + (lane >> 4);
    int rowA = w * 16 + (lane & 15);
    bf16x8 fa2;
    if (kk < 4) fa2 = *(const bf16x8*)(Ks + rowA * 128 + ((kc ^ (rowA & 15)) << 3));
    else        fa2 = *(const bf16x8*)(Qs + rowA * 128 + (((kc - 16) ^ (rowA & 15)) << 3));
#pragma unroll
    for (int n = 0; n < 5; n++){
      int d = n * 16 + (lane & 15);
      bf16x8 fb2 = *(const bf16x8*)(B2 + d * 256 + ((kc ^ (d & 31)) << 3));
      acc2[n] = __builtin_amdgcn_mfma_f32_16x16x32_bf16(fa2, fb2, acc2[n], 0, 0, 0);
    }
  }

  float dd[4];
#pragma unroll
  for (int r = 0; r < 4; r++) dd[r] = __shfl(acc2[4][r], lane & 48) + 1e-6f;
  size_t obase = ((size_t)b * 2048 + c * 128) * 1024 + (size_t)h * 64;
#pragma unroll
  for (int n = 0; n < 4; n++)
#pragma unroll
    for (int r = 0; r < 4; r++){
      int i = w * 16 + ((lane >> 4) << 2) + r;
      int d = n * 16 + (lane & 15);
      aout[obase + (size_t)i * 1024 + d] = f2b(acc2[n][r] / dd[r]);
    }
}

// ---------------- fused residual-add + LayerNorm (X2 bf16), writes f32 + bf16 ----------------
__global__ __launch_bounds__(256) void ln_kernel(const float* __restrict__ X1, const u16* __restrict__ X2b,
                                                 const float* __restrict__ g, const float* __restrict__ bb,
                                                 float* __restrict__ outf, u16* __restrict__ outb){
  __shared__ float red[2][4];
  int row = blockIdx.x, tid = threadIdx.x, w = tid >> 6, lane = tid & 63;
  size_t ro = (size_t)row * 1024 + tid * 4;
  float4 a = *(const float4*)(X1 + ro);
  ushort4 bp = *(const ushort4*)(X2b + ro);
  float x0 = a.x + b2f(bp.x), x1 = a.y + b2f(bp.y), x2 = a.z + b2f(bp.z), x3 = a.w + b2f(bp.w);
  float s1 = x0 + x1 + x2 + x3;
  float s2 = x0 * x0 + x1 * x1 + x2 * x2 + x3 * x3;
#pragma unroll
  for (int off = 32; off; off >>= 1){ s1 += __shfl_xor(s1, off); s2 += __shfl_xor(s2, off); }
  if (lane == 0){ red[0][w] = s1; red[1][w] = s2; }
  __syncthreads();
  float t1 = red[0][0] + red[0][1] + red[0][2] + red[0][3];
  float t2 = red[1][0] + red[1][1] + red[1][2] + red[1][3];
  float mu = t1 * (1.f / 1024.f);
  float var = t2 * (1.f / 1024.f) - mu * mu;
  float rs = rsqrtf(var + 1e-5f);
  float4 gv = *(const float4*)(g + tid * 4);
  float4 bv = *(const float4*)(bb + tid * 4);
  float o0 = (x0 - mu) * rs * gv.x + bv.x;
  float o1 = (x1 - mu) * rs * gv.y + bv.y;
  float o2 = (x2 - mu) * rs * gv.z + bv.z;
  float o3 = (x3 - mu) * rs * gv.w + bv.w;
  *(float4*)(outf + ro) = make_float4(o0, o1, o2, o3);
  *(ushort4*)(outb + ro) = make_ushort4(f2b(o0), f2b(o1), f2b(o2), f2b(o3));
}

// ---------------- residual + TWO bf16 partials + LayerNorm (P1 may alias outb) ----------------
__global__ __launch_bounds__(256) void ln3_kernel(const float* __restrict__ X1, const u16* __restrict__ P0,
                                                  const u16* P1, const float* __restrict__ g,
                                                  const float* __restrict__ bb,
                                                  float* __restrict__ outf, u16* outb){
  __shared__ float red[2][4];
  int row = blockIdx.x, tid = threadIdx.x, w = tid >> 6, lane = tid & 63;
  size_t ro = (size_t)row * 1024 + tid * 4;
  float4 a = *(const float4*)(X1 + ro);
  ushort4 p0 = *(const ushort4*)(P0 + ro);
  ushort4 p1 = *(const ushort4*)(P1 + ro);
  float x0 = a.x + b2f(p0.x) + b2f(p1.x);
  float x1 = a.y + b2f(p0.y) + b2f(p1.y);
  float x2 = a.z + b2f(p0.z) + b2f(p1.z);
  float x3 = a.w + b2f(p0.w) + b2f(p1.w);
  float s1 = x0 + x1 + x2 + x3;
  float s2 = x0 * x0 + x1 * x1 + x2 * x2 + x3 * x3;
#pragma unroll
  for (int off = 32; off; off >>= 1){ s1 += __shfl_xor(s1, off); s2 += __shfl_xor(s2, off); }
  if (lane == 0){ red[0][w] = s1; red[1][w] = s2; }
  __syncthreads();
  float t1 = red[0][0] + red[0][1] + red[0][2] + red[0][3];
  float t2 = red[1][0] + red[1][1] + red[1][2] + red[1][3];
  float mu = t1 * (1.f / 1024.f);
  float var = t2 * (1.f / 1024.f) - mu * mu;
  float rs = rsqrtf(var + 1e-5f);
  float4 gv = *(const float4*)(g + tid * 4);
  float4 bv = *(const float4*)(bb + tid * 4);
  float o0 = (x0 - mu) * rs * gv.x + bv.x;
  float o1 = (x1 - mu) * rs * gv.y + bv.y;
  float o2 = (x2 - mu) * rs * gv.z + bv.z;
  float o3 = (x3 - mu) * rs * gv.w + bv.w;
  *(float4*)(outf + ro) = make_float4(o0, o1, o2, o3);
  *(ushort4*)(outb + ro) = make_ushort4(f2b(o0), f2b(o1), f2b(o2), f2b(o3));
}

// ---------------- host ----------------
extern "C" void kernel_launch(void* const* d_in, const int* in_sizes, int n_in,
                              void* d_out, int out_size, void* d_ws, size_t ws_size,
                              hipStream_t stream){
  (void)in_sizes; (void)n_in;
  const float* x   = (const float*)d_in[0];
  const float* Wq  = (const float*)d_in[1];
  const float* bq  = (const float*)d_in[2];
  const float* Wk  = (const float*)d_in[3];
  const float* bk  = (const float*)d_in[4];
  const float* Wv  = (const float*)d_in[5];
  const float* bv  = (const float*)d_in[6];
  const float* Wo  = (const float*)d_in[7];
  const float* bo  = (const float*)d_in[8];
  const float* om  = (const float*)d_in[9];
  const float* g1  = (const float*)d_in[10];
  const float* be1 = (const float*)d_in[11];
  const float* W1  = (const float*)d_in[12];
  const float* bf1 = (const float*)d_in[13];
  const float* W2  = (const float*)d_in[14];
  const float* bf2 = (const float*)d_in[15];
  const float* g2  = (const float*)d_in[16];
  const float* be2 = (const float*)d_in[17];

  char* ws = (char*)d_ws;
  size_t off = 0;
  auto alloc = [&](size_t bytes) -> void* {
    void* p = ws + off; off += (bytes + 255) & ~(size_t)255; return p;
  };
  u16* Wcat = (u16*)alloc(3072ull * 1024 * 2);
  u16* Wot  = (u16*)alloc(1024ull * 1024 * 2);
  u16* W1t  = (u16*)alloc(4096ull * 1024 * 2);
  u16* W2t  = (u16*)alloc(1024ull * 4096 * 2);
  u16* omT  = (u16*)alloc(64ull * 64 * 2);
  float* bcat = (float*)alloc(6ull * 3072 * 4);
  float* zbuf = (float*)alloc(1024 * 4);
  u16* Xb  = (u16*)alloc(8192ull * 1024 * 2);
  u16* qb  = (u16*)alloc(131072ull * 64 * 2);   // contiguous qb|kb|vt|Qp for ybuf alias
  u16* kb  = (u16*)alloc(131072ull * 64 * 2);
  u16* vt  = (u16*)alloc(131072ull * 64 * 2);
  u16* Qp  = (u16*)alloc(131072ull * 128 * 2);
  u16* Kp  = (u16*)alloc(131072ull * 128 * 2);
  float* ksum = (float*)alloc(64ull * 16 * 128 * 4);

  if (off > ws_size){
    fillv<<<(out_size + 255) / 256, 256, 0, stream>>>((float*)d_out, (float)(ws_size >> 20), out_size);
    return;
  }

  float* kvbuf  = (float*)qb;            // kv^T f32 32MB over qb+kb (dead after phi2)
  u16*  ybuf   = qb;                    // FFN intermediate bf16 [8192][4096] over qb..Qp[0:16MB]
  u16*  wooutb = Qp;                    // Wo out bf16 16MB (Qp dead after attn)
  u16*  w2outb = Qp + 8388608;          // W2 partial kz=0, bf16 16MB
  // W2 partial kz=1 lives in Xb (h1-bf16 dead after W1; ln3 reads it then rewrites Xb)
  float* h1     = (float*)Kp;            // residual-1 LN out f32 32MB (Kp dead after attn)
  float* resid  = (float*)d_out;         // persistent f32 activation stream

  cvt16<<<8192, 256, 0, stream>>>(x, Xb);
  catbias<<<72, 256, 0, stream>>>(bq, bk, bv, bcat);
  fillv<<<4, 256, 0, stream>>>(zbuf, 0.f, 1024);

  const float* Xsrc = x;
  for (int l = 0; l < 6; l++){
    size_t o1k = (size_t)l * 1024 * 1024;
    size_t o4k = (size_t)l * 4096 * 1024;
    wtrans7<<<12292, 256, 0, stream>>>(Wq + o1k, Wk + o1k, Wv + o1k, Wo + o1k,
                                       W1 + o4k, W2 + o4k, om + (size_t)l * 4096,
                                       Wcat, Wot, W1t, W2t, omT);

    gemm_bt<5><<<dim3(24, 64), 256, 0, stream>>>(Xb, Wcat, bcat + l * 3072, qb, 8192, 3072, 1024, 1024, 1024);
    phi2<<<2048, 256, 0, stream>>>(qb, kb, omT, Qp, Kp);
    kvchunk<<<1024, 256, 0, stream>>>(Kp, vt, kvbuf, ksum);
    kvscan<<<dim3(64, 9), 256, 0, stream>>>(kvbuf, ksum);
    attn_fused<<<1024, 512, 0, stream>>>(Qp, Kp, vt, kvbuf, ksum, Xb);
    gemm_bt<6><<<dim3(8, 64), 256, 0, stream>>>(Xb, Wot, bo + l * 1024, wooutb, 8192, 1024, 1024, 1024, 1024);
    ln_kernel<<<8192, 256, 0, stream>>>(Xsrc, wooutb, g1 + l * 1024, be1 + l * 1024, h1, Xb);
    gemm8p<2><<<dim3(16, 32), 512, 0, stream>>>(Xb, W1t, bf1 + l * 4096, ybuf, 8192, 4096, 1024, 1024, 1024);
    gemm8pk<<<dim3(256), 512, 0, stream>>>(ybuf, W2t, bf2 + l * 1024, zbuf, w2outb, Xb,
                                           8192, 1024, 2048, 4096, 4096);
    ln3_kernel<<<8192, 256, 0, stream>>>(h1, w2outb, Xb, g2 + l * 1024, be2 + l * 1024, resid, Xb);
    Xsrc = resid;
  }
}

// Round 16
// 2464.188 us; speedup vs baseline: 1.0546x; 1.0179x over previous
//
#include <hip/hip_runtime.h>

typedef unsigned short u16;
typedef __attribute__((ext_vector_type(8))) short bf16x8;
typedef __attribute__((ext_vector_type(4))) float f32x4;

#define DEV __device__ __forceinline__

DEV float b2f(u16 h){ return __uint_as_float(((unsigned)h) << 16); }
DEV u16 f2b(float f){ unsigned u = __float_as_uint(f); u += 0x7FFFu + ((u >> 16) & 1u); return (u16)(u >> 16); }

DEV void gload16(const u16* g, u16* l){
  __builtin_amdgcn_global_load_lds((const __attribute__((address_space(1))) unsigned*)g,
                                   (__attribute__((address_space(3))) unsigned*)l, 16, 0, 0);
}

// ---------------- merged per-layer weight transpose: 7 tensors in one launch ----------------
__global__ __launch_bounds__(256) void wtrans7(const float* __restrict__ Wq, const float* __restrict__ Wk,
                                               const float* __restrict__ Wv, const float* __restrict__ Wo,
                                               const float* __restrict__ W1, const float* __restrict__ W2,
                                               const float* __restrict__ om,
                                               u16* __restrict__ Wcat, u16* __restrict__ Wot,
                                               u16* __restrict__ W1t, u16* __restrict__ W2t,
                                               u16* __restrict__ omT){
  __shared__ float tile[32][33];
  int id = blockIdx.x;
  const float* src; u16* dst; int K, N, kb, nb; float scale = 1.f;
  if (id < 4096){
    int wsel = id >> 10, loc = id & 1023;
    kb = loc >> 5; nb = loc & 31; K = 1024; N = 1024;
    src = (wsel == 0) ? Wq : (wsel == 1) ? Wk : (wsel == 2) ? Wv : Wo;
    dst = (wsel < 3) ? Wcat + (size_t)wsel * 1048576 : Wot;
  } else if (id < 8192){
    int loc = id - 4096;
    kb = loc & 31; nb = loc >> 5; K = 1024; N = 4096;
    src = W1; dst = W1t;
  } else if (id < 12288){
    int loc = id - 8192;
    kb = loc & 127; nb = loc >> 7; K = 4096; N = 1024;
    src = W2; dst = W2t;
  } else {
    int loc = id - 12288;
    kb = loc & 1; nb = loc >> 1; K = 64; N = 64;
    src = om; dst = omT; scale = 0.35355339059327373f;
  }
  int k0 = kb * 32, n0 = nb * 32;
  int tid = threadIdx.x;
#pragma unroll
  for (int i = 0; i < 4; i++){
    int idx = tid + i * 256;
    int r = idx >> 5, c = idx & 31;
    tile[r][c] = src[(size_t)(k0 + r) * N + n0 + c];
  }
  __syncthreads();
#pragma unroll
  for (int i = 0; i < 4; i++){
    int idx = tid + i * 256;
    int r = idx >> 5, c = idx & 31;
    dst[(size_t)(n0 + r) * K + k0 + c] = f2b(tile[c][r] * scale);
  }
}

// ---------------- f32 -> bf16 convert ----------------
__global__ __launch_bounds__(256) void cvt16(const float* __restrict__ src, u16* __restrict__ dst){
  size_t i = ((size_t)blockIdx.x * 256 + threadIdx.x) * 4;
  float4 f = *(const float4*)(src + i);
  ushort4 o = make_ushort4(f2b(f.x), f2b(f.y), f2b(f.z), f2b(f.w));
  *(ushort4*)(dst + i) = o;
}

// ---------------- bias concat (all layers): [6][3072] = bq|bk|bv ----------------
__global__ void catbias(const float* __restrict__ bq, const float* __restrict__ bk,
                        const float* __restrict__ bv, float* __restrict__ bcat){
  int i = blockIdx.x * 256 + threadIdx.x;
  if (i >= 6 * 3072) return;
  int l = i / 3072, j = i % 3072;
  float v = (j < 1024) ? bq[l * 1024 + j] : (j < 2048) ? bk[l * 1024 + j - 1024] : bv[l * 1024 + j - 2048];
  bcat[i] = v;
}

// ---------------- diagnostic / zero fill ----------------
__global__ void fillv(float* __restrict__ p, float v, int n){
  int i = blockIdx.x * 256 + threadIdx.x;
  if (i < n) p[i] = v;
}

// ---------------- 128^2 bf16 MFMA GEMM (gload_lds dbuf + counted vmcnt + XCD swizzle) ----------------
// EPI 2: relu bf16 [M,N] ; EPI 5: fused QKV ; EPI 6: bf16 [M,N]
DEV int swz(int r){ return (r & 3) ^ ((r >> 2) & 3); }

template<int EPI>
__global__ __launch_bounds__(256) void gemm_bt(const u16* __restrict__ A, const u16* __restrict__ Bt,
                                               const float* __restrict__ bias, void* __restrict__ outp,
                                               int M, int N, int K, int ldA, int ldB){
  __shared__ __align__(16) u16 As[2][4096];
  __shared__ __align__(16) u16 Bs[2][4096];
  const int tid = threadIdx.x;
  const int lane = tid & 63;
  const int w = tid >> 6;
  const int wm = w >> 1, wn = w & 1;
  int nx = gridDim.x;
  int nwg = nx * gridDim.y;
  int lin = blockIdx.y * nx + blockIdx.x;
  int cpx = nwg >> 3;
  int sw = (lin & 7) * cpx + (lin >> 3);
  const int m0 = (sw / nx) * 128;
  const int n0 = (sw % nx) * 128;

  int r0 = tid >> 2, c0 = tid & 3;
  int r1 = r0 + 64;
  int cs0 = c0 ^ swz(r0);
  int cs1 = c0 ^ swz(r1);
  const u16* ag0 = A + (size_t)(m0 + r0) * ldA + cs0 * 8;
  const u16* ag1 = A + (size_t)(m0 + r1) * ldA + cs1 * 8;
  const u16* bg0 = Bt + (size_t)(n0 + r0) * ldB + cs0 * 8;
  const u16* bg1 = Bt + (size_t)(n0 + r1) * ldB + cs1 * 8;

  f32x4 acc[4][4] = {};
  const int KT = K >> 5;

  gload16(ag0, &As[0][w * 512]);
  gload16(ag1, &As[0][2048 + w * 512]);
  gload16(bg0, &Bs[0][w * 512]);
  gload16(bg1, &Bs[0][2048 + w * 512]);

  for (int kt = 0; kt < KT; kt++){
    int cur = kt & 1;
    if (kt + 1 < KT){
      int ko = (kt + 1) << 5;
      gload16(ag0 + ko, &As[cur ^ 1][w * 512]);
      gload16(ag1 + ko, &As[cur ^ 1][2048 + w * 512]);
      gload16(bg0 + ko, &Bs[cur ^ 1][w * 512]);
      gload16(bg1 + ko, &Bs[cur ^ 1][2048 + w * 512]);
      asm volatile("s_waitcnt vmcnt(4)" ::: "memory");
    } else {
      asm volatile("s_waitcnt vmcnt(0)" ::: "memory");
    }
    __builtin_amdgcn_s_barrier();
    bf16x8 fa[4], fb[4];
#pragma unroll
    for (int m = 0; m < 4; m++){
      int row = wm * 64 + m * 16 + (lane & 15);
      int cc = (lane >> 4) ^ swz(row);
      fa[m] = *(const bf16x8*)(&As[cur][row * 32 + cc * 8]);
    }
#pragma unroll
    for (int n = 0; n < 4; n++){
      int row = wn * 64 + n * 16 + (lane & 15);
      int cc = (lane >> 4) ^ swz(row);
      fb[n] = *(const bf16x8*)(&Bs[cur][row * 32 + cc * 8]);
    }
#pragma unroll
    for (int m = 0; m < 4; m++)
#pragma unroll
      for (int n = 0; n < 4; n++)
        acc[m][n] = __builtin_amdgcn_mfma_f32_16x16x32_bf16(fa[m], fb[n], acc[m][n], 0, 0, 0);
    asm volatile("s_waitcnt lgkmcnt(0)" ::: "memory");
    __builtin_amdgcn_s_barrier();
  }

#pragma unroll
  for (int m = 0; m < 4; m++){
    int rowb = m0 + wm * 64 + m * 16 + ((lane >> 4) << 2);
#pragma unroll
    for (int n = 0; n < 4; n++){
      int col = n0 + wn * 64 + n * 16 + (lane & 15);
      float bv = bias[col];
      if (EPI == 5 && col >= 2048){
        int cv = col - 2048, hh = cv >> 6, dh = cv & 63;
        int bIdx = rowb >> 11, s4 = rowb & 2047;
        ushort4 pk = make_ushort4(f2b(acc[m][n][0] + bv), f2b(acc[m][n][1] + bv),
                                  f2b(acc[m][n][2] + bv), f2b(acc[m][n][3] + bv));
        *(ushort4*)&((u16*)outp + 16777216)[((size_t)(bIdx * 16 + hh) * 64 + dh) * 2048 + s4] = pk;
      } else {
#pragma unroll
        for (int r = 0; r < 4; r++){
          float v = acc[m][n][r] + bv;
          int rr = rowb + r;
          if (EPI == 5){
            u16* dst0 = (u16*)outp + (col < 1024 ? 0 : 8388608);
            int cv = col & 1023, hh = cv >> 6, dh = cv & 63;
            int bIdx = rr >> 11, s = rr & 2047;
            dst0[(((size_t)(bIdx * 16 + hh) * 2048 + s) << 6) + dh] = f2b(v);
          } else if (EPI == 2){
            ((u16*)outp)[(size_t)rr * N + col] = f2b(v > 0.f ? v : 0.f);
          } else {
            ((u16*)outp)[(size_t)rr * N + col] = f2b(v);
          }
        }
      }
    }
  }
}

// ---------------- 8-phase 256^2 GEMM (m201 template): BK=64, K-half subtiles, counted vmcnt ----------------
// EPI 2: relu bf16 ; EPI 6: bf16   (scalar epilogue)
template<int EPI>
__global__ __launch_bounds__(512, 1) void gemm8p(const u16* __restrict__ A, const u16* __restrict__ Bt,
                                                 const float* __restrict__ bias, void* __restrict__ outp,
                                                 int M, int N, int K, int ldA, int ldB){
  __shared__ __align__(16) u16 As[2][16384];
  __shared__ __align__(16) u16 Bs[2][16384];
  const int tid = threadIdx.x;
  const int lane = tid & 63;
  const int w = tid >> 6;
  const int wm = w >> 2, wn = w & 3;
  int nx = gridDim.x;
  int nwg = nx * gridDim.y;
  int lin = blockIdx.y * nx + blockIdx.x;
  int cpx = nwg >> 3;
  int sw = (lin & 7) * cpx + (lin >> 3);
  const int m0 = (sw / nx) * 256;
  const int n0 = (sw % nx) * 256;

  const int id1 = 512 + tid;
  const int r0 = tid >> 2, c20 = tid & 3;
  const int r1 = id1 >> 2, c21 = id1 & 3;
  const int cs0 = c20 ^ ((r0 >> 1) & 3);
  const int cs1 = c21 ^ ((r1 >> 1) & 3);
  const u16* Ag0 = A + (size_t)(m0 + r0) * ldA + cs0 * 8;
  const u16* Ag1 = A + (size_t)(m0 + r1) * ldA + cs1 * 8;
  const u16* Bg0 = Bt + (size_t)(n0 + r0) * ldB + cs0 * 8;
  const u16* Bg1 = Bt + (size_t)(n0 + r1) * ldB + cs1 * 8;

  f32x4 acc[8][4] = {};
  const int KT = K >> 6;

  auto stA = [&](int buf, int kt, int ks){
    int kc = kt * 64 + ks * 32;
    gload16(Ag0 + kc, &As[buf][ks * 8192 + w * 512]);
    gload16(Ag1 + kc, &As[buf][ks * 8192 + 4096 + w * 512]);
  };
  auto stB = [&](int buf, int kt, int ks){
    int kc = kt * 64 + ks * 32;
    gload16(Bg0 + kc, &Bs[buf][ks * 8192 + w * 512]);
    gload16(Bg1 + kc, &Bs[buf][ks * 8192 + 4096 + w * 512]);
  };

  stA(0, 0, 0); stB(0, 0, 0); stA(0, 0, 1); stB(0, 0, 1);

  for (int t = 0; t < KT; t++){
    int c = t & 1, nb = c ^ 1;
    bool pf = (t + 1 < KT);
    asm volatile("s_waitcnt vmcnt(4)" ::: "memory");
    __builtin_amdgcn_s_barrier();

#pragma unroll
    for (int ks = 0; ks < 2; ks++){
      if (ks == 1){
        if (pf) asm volatile("s_waitcnt vmcnt(4)" ::: "memory");
        else    asm volatile("s_waitcnt vmcnt(0)" ::: "memory");
        __builtin_amdgcn_s_barrier();
      }
      if (pf){ if (ks == 0) stA(nb, t + 1, 0); else stA(nb, t + 1, 1); }
      bf16x8 fa[8], fb[2];
#pragma unroll
      for (int m = 0; m < 8; m++){
        int row = wm * 128 + m * 16 + (lane & 15);
        int slot = (lane >> 4) ^ ((row >> 1) & 3);
        fa[m] = *(const bf16x8*)(&As[c][ks * 8192 + row * 32 + slot * 8]);
      }
#pragma unroll
      for (int nn = 0; nn < 2; nn++){
        int row = wn * 64 + nn * 16 + (lane & 15);
        int slot = (lane >> 4) ^ ((row >> 1) & 3);
        fb[nn] = *(const bf16x8*)(&Bs[c][ks * 8192 + row * 32 + slot * 8]);
      }
      __builtin_amdgcn_s_setprio(1);
#pragma unroll
      for (int m = 0; m < 8; m++)
#pragma unroll
        for (int nn = 0; nn < 2; nn++)
          acc[m][nn] = __builtin_amdgcn_mfma_f32_16x16x32_bf16(fa[m], fb[nn], acc[m][nn], 0, 0, 0);
      __builtin_amdgcn_s_setprio(0);
      if (pf){ if (ks == 0) stB(nb, t + 1, 0); else stB(nb, t + 1, 1); }
#pragma unroll
      for (int nn = 0; nn < 2; nn++){
        int row = wn * 64 + 32 + nn * 16 + (lane & 15);
        int slot = (lane >> 4) ^ ((row >> 1) & 3);
        fb[nn] = *(const bf16x8*)(&Bs[c][ks * 8192 + row * 32 + slot * 8]);
      }
      __builtin_amdgcn_s_setprio(1);
#pragma unroll
      for (int m = 0; m < 8; m++)
#pragma unroll
        for (int nn = 0; nn < 2; nn++)
          acc[m][2 + nn] = __builtin_amdgcn_mfma_f32_16x16x32_bf16(fa[m], fb[nn], acc[m][2 + nn], 0, 0, 0);
      __builtin_amdgcn_s_setprio(0);
    }
  }

#pragma unroll
  for (int m = 0; m < 8; m++){
    int rowb = m0 + wm * 128 + m * 16 + ((lane >> 4) << 2);
#pragma unroll
    for (int n = 0; n < 4; n++){
      int col = n0 + wn * 64 + n * 16 + (lane & 15);
      float bv = bias[col];
#pragma unroll
      for (int r = 0; r < 4; r++){
        float v = acc[m][n][r] + bv;
        int rr = rowb + r;
        if (EPI == 2) ((u16*)outp)[(size_t)rr * N + col] = f2b(v > 0.f ? v : 0.f);
        else          ((u16*)outp)[(size_t)rr * N + col] = f2b(v);
      }
    }
  }
}

// ---------------- 8-phase 256^2 split-K GEMM: 256 blocks = (4 n)x(32 m)x(2 kz), bf16 partials ----------------
__global__ __launch_bounds__(512, 1) void gemm8pk(const u16* __restrict__ A, const u16* __restrict__ Bt,
                                                  const float* __restrict__ bias0, const float* __restrict__ bias1,
                                                  u16* __restrict__ out0, u16* __restrict__ out1,
                                                  int M, int N, int Khalf, int ldA, int ldB){
  __shared__ __align__(16) u16 As[2][16384];
  __shared__ __align__(16) u16 Bs[2][16384];
  const int tid = threadIdx.x;
  const int lane = tid & 63;
  const int w = tid >> 6;
  const int wm = w >> 2, wn = w & 3;
  int lin = blockIdx.x;               // 256 blocks
  int cpx = gridDim.x >> 3;
  int sw = (lin & 7) * cpx + (lin >> 3);
  const int kz = sw & 1;
  const int t2 = sw >> 1;
  const int n0 = (t2 & 3) * 256;
  const int m0 = (t2 >> 2) * 256;
  const u16* Ab = A + kz * Khalf;
  const u16* Bb = Bt + kz * Khalf;
  u16* outp = kz ? out1 : out0;
  const float* bias = kz ? bias1 : bias0;

  const int id1 = 512 + tid;
  const int r0 = tid >> 2, c20 = tid & 3;
  const int r1 = id1 >> 2, c21 = id1 & 3;
  const int cs0 = c20 ^ ((r0 >> 1) & 3);
  const int cs1 = c21 ^ ((r1 >> 1) & 3);
  const u16* Ag0 = Ab + (size_t)(m0 + r0) * ldA + cs0 * 8;
  const u16* Ag1 = Ab + (size_t)(m0 + r1) * ldA + cs1 * 8;
  const u16* Bg0 = Bb + (size_t)(n0 + r0) * ldB + cs0 * 8;
  const u16* Bg1 = Bb + (size_t)(n0 + r1) * ldB + cs1 * 8;

  f32x4 acc[8][4] = {};
  const int KT = Khalf >> 6;

  auto stA = [&](int buf, int kt, int ks){
    int kc = kt * 64 + ks * 32;
    gload16(Ag0 + kc, &As[buf][ks * 8192 + w * 512]);
    gload16(Ag1 + kc, &As[buf][ks * 8192 + 4096 + w * 512]);
  };
  auto stB = [&](int buf, int kt, int ks){
    int kc = kt * 64 + ks * 32;
    gload16(Bg0 + kc, &Bs[buf][ks * 8192 + w * 512]);
    gload16(Bg1 + kc, &Bs[buf][ks * 8192 + 4096 + w * 512]);
  };

  stA(0, 0, 0); stB(0, 0, 0); stA(0, 0, 1); stB(0, 0, 1);

  for (int t = 0; t < KT; t++){
    int c = t & 1, nb = c ^ 1;
    bool pf = (t + 1 < KT);
    asm volatile("s_waitcnt vmcnt(4)" ::: "memory");
    __builtin_amdgcn_s_barrier();

#pragma unroll
    for (int ks = 0; ks < 2; ks++){
      if (ks == 1){
        if (pf) asm volatile("s_waitcnt vmcnt(4)" ::: "memory");
        else    asm volatile("s_waitcnt vmcnt(0)" ::: "memory");
        __builtin_amdgcn_s_barrier();
      }
      if (pf){ if (ks == 0) stA(nb, t + 1, 0); else stA(nb, t + 1, 1); }
      bf16x8 fa[8], fb[2];
#pragma unroll
      for (int m = 0; m < 8; m++){
        int row = wm * 128 + m * 16 + (lane & 15);
        int slot = (lane >> 4) ^ ((row >> 1) & 3);
        fa[m] = *(const bf16x8*)(&As[c][ks * 8192 + row * 32 + slot * 8]);
      }
#pragma unroll
      for (int nn = 0; nn < 2; nn++){
        int row = wn * 64 + nn * 16 + (lane & 15);
        int slot = (lane >> 4) ^ ((row >> 1) & 3);
        fb[nn] = *(const bf16x8*)(&Bs[c][ks * 8192 + row * 32 + slot * 8]);
      }
      __builtin_amdgcn_s_setprio(1);
#pragma unroll
      for (int m = 0; m < 8; m++)
#pragma unroll
        for (int nn = 0; nn < 2; nn++)
          acc[m][nn] = __builtin_amdgcn_mfma_f32_16x16x32_bf16(fa[m], fb[nn], acc[m][nn], 0, 0, 0);
      __builtin_amdgcn_s_setprio(0);
      if (pf){ if (ks == 0) stB(nb, t + 1, 0); else stB(nb, t + 1, 1); }
#pragma unroll
      for (int nn = 0; nn < 2; nn++){
        int row = wn * 64 + 32 + nn * 16 + (lane & 15);
        int slot = (lane >> 4) ^ ((row >> 1) & 3);
        fb[nn] = *(const bf16x8*)(&Bs[c][ks * 8192 + row * 32 + slot * 8]);
      }
      __builtin_amdgcn_s_setprio(1);
#pragma unroll
      for (int m = 0; m < 8; m++)
#pragma unroll
        for (int nn = 0; nn < 2; nn++)
          acc[m][2 + nn] = __builtin_amdgcn_mfma_f32_16x16x32_bf16(fa[m], fb[nn], acc[m][2 + nn], 0, 0, 0);
      __builtin_amdgcn_s_setprio(0);
    }
  }

#pragma unroll
  for (int m = 0; m < 8; m++){
    int rowb = m0 + wm * 128 + m * 16 + ((lane >> 4) << 2);
#pragma unroll
    for (int n = 0; n < 4; n++){
      int col = n0 + wn * 64 + n * 16 + (lane & 15);
      float bv = bias[col];
#pragma unroll
      for (int r = 0; r < 4; r++)
        outp[(size_t)(rowb + r) * N + col] = f2b(acc[m][n][r] + bv);
    }
  }
}

// ---------------- FAVOR phi v2 (MFMA) ----------------
__global__ __launch_bounds__(256) void phi2(const u16* __restrict__ qb, const u16* __restrict__ kb,
                                            const u16* __restrict__ omT,
                                            u16* __restrict__ Qp, u16* __restrict__ Kp){
  __shared__ __align__(16) u16 qs[128 * 64];
  __shared__ __align__(16) u16 wl[64 * 64];
  __shared__ __align__(16) u16 ph[128 * 128];
  __shared__ float part[2][128];
  __shared__ float nrm[128];
  int tid = threadIdx.x, w = tid >> 6, lane = tid & 63;
  int blk = blockIdx.x;
  const u16* src; u16* dst; int row0;
  if (blk < 1024){ src = qb; dst = Qp; row0 = blk * 128; }
  else           { src = kb; dst = Kp; row0 = (blk - 1024) * 128; }
  const u16* g = src + (size_t)row0 * 64;
#pragma unroll
  for (int i = 0; i < 4; i++){
    int id = tid * 4 + i;
    int r = id >> 3, kc = id & 7;
    *(bf16x8*)(qs + r * 64 + ((kc ^ (r & 7)) << 3)) = *(const bf16x8*)(g + r * 64 + kc * 8);
  }
#pragma unroll
  for (int i = 0; i < 2; i++){
    int id = tid * 2 + i;
    int m = id >> 3, kc = id & 7;
    *(bf16x8*)(wl + m * 64 + ((kc ^ (m & 7)) << 3)) = *(const bf16x8*)(omT + id * 8);
  }
  __syncthreads();
  {
    int r = tid & 127, half = tid >> 7;
    float s = 0.f;
#pragma unroll
    for (int j = 0; j < 4; j++){
      int kc = half * 4 + j;
      bf16x8 v = *(const bf16x8*)(qs + r * 64 + ((kc ^ (r & 7)) << 3));
#pragma unroll
      for (int e = 0; e < 8; e++){ float f = b2f((u16)v[e]); s += f * f; }
    }
    part[half][r] = s;
  }
  __syncthreads();
  if (tid < 128) nrm[tid] = 0.0625f * (part[0][tid] + part[1][tid]);
  __syncthreads();
  f32x4 acc[2][4] = {};
#pragma unroll
  for (int kt = 0; kt < 2; kt++){
    int kc = kt * 4 + (lane >> 4);
    bf16x8 fa[2], fb[4];
#pragma unroll
    for (int mt = 0; mt < 2; mt++){
      int r = w * 32 + mt * 16 + (lane & 15);
      fa[mt] = *(const bf16x8*)(qs + r * 64 + ((kc ^ (r & 7)) << 3));
    }
#pragma unroll
    for (int nt = 0; nt < 4; nt++){
      int m = nt * 16 + (lane & 15);
      fb[nt] = *(const bf16x8*)(wl + m * 64 + ((kc ^ (m & 7)) << 3));
    }
#pragma unroll
    for (int mt = 0; mt < 2; mt++)
#pragma unroll
      for (int nt = 0; nt < 4; nt++)
        acc[mt][nt] = __builtin_amdgcn_mfma_f32_16x16x32_bf16(fa[mt], fb[nt], acc[mt][nt], 0, 0, 0);
  }
  const float LNC = -2.4260151319598086f;   // ln(128^-0.5)
#pragma unroll
  for (int mt = 0; mt < 2; mt++)
#pragma unroll
    for (int nt = 0; nt < 4; nt++)
#pragma unroll
      for (int r4 = 0; r4 < 4; r4++){
        int r = w * 32 + mt * 16 + ((lane >> 4) << 2) + r4;
        int m = nt * 16 + (lane & 15);
        float u = acc[mt][nt][r4];
        float nr = nrm[r];
        ph[r * 128 + m]      = f2b(__expf(u - nr + LNC));
        ph[r * 128 + 64 + m] = f2b(__expf(-u - nr + LNC));
      }
  __syncthreads();
  u16* go = dst + (size_t)row0 * 128;
#pragma unroll
  for (int i = 0; i < 8; i++){
    int id = i * 256 + tid;
    *(bf16x8*)(go + id * 8) = *(const bf16x8*)(ph + id * 8);
  }
}

// ---------------- per-chunk kv^T[d][m], ksum [128m] ----------------
__global__ __launch_bounds__(256) void kvchunk(const u16* __restrict__ Kp, const u16* __restrict__ vt,
                                               float* __restrict__ kv, float* __restrict__ ksum){
  __shared__ __align__(16) u16 Ks[128 * 128];
  __shared__ __align__(16) u16 Vst[64 * 128];
  int blk = blockIdx.x; int bh = blk >> 4, c = blk & 15;
  int tid = threadIdx.x;
  size_t base = (size_t)bh * 2048 + c * 128;
  const u16* Kc = Kp + base * 128;
  const u16* vtc = vt + (size_t)bh * 64 * 2048 + c * 128;
  {
    int j = tid >> 1, half = tid & 1;
#pragma unroll
    for (int i = 0; i < 8; i++)
      *(bf16x8*)(Ks + j * 128 + half * 64 + i * 8) = *(const bf16x8*)(Kc + j * 128 + half * 64 + i * 8);
#pragma unroll
    for (int i = 0; i < 4; i++){
      int id = tid * 4 + i;
      int d = id >> 4, mc = id & 15;
      *(bf16x8*)(Vst + d * 128 + mc * 8) = *(const bf16x8*)(vtc + (size_t)d * 2048 + mc * 8);
    }
  }
  __syncthreads();
  int tm = tid & 15, td = tid >> 4;
  int mbase = tm * 8, dbase = td * 4;
  float acc[8][4] = {};
  float ks[8] = {};
  for (int i = 0; i < 128; i++){
    bf16x8 kk = *(const bf16x8*)(Ks + i * 128 + mbase);
    float kf[8];
#pragma unroll
    for (int e = 0; e < 8; e++) kf[e] = b2f((u16)kk[e]);
    float vf[4];
#pragma unroll
    for (int e = 0; e < 4; e++) vf[e] = b2f(Vst[(dbase + e) * 128 + i]);
#pragma unroll
    for (int a = 0; a < 8; a++){
      ks[a] += kf[a];
#pragma unroll
      for (int bb = 0; bb < 4; bb++) acc[a][bb] += kf[a] * vf[bb];
    }
  }
  float* kvout = kv + ((size_t)bh * 16 + c) * 8192;
#pragma unroll
  for (int a = 0; a < 8; a++)
#pragma unroll
    for (int bb = 0; bb < 4; bb++)
      kvout[(size_t)(dbase + bb) * 128 + mbase + a] = acc[a][bb];
  if (td == 0){
    float* kso = ksum + ((size_t)bh * 16 + c) * 128;
#pragma unroll
    for (int a = 0; a < 8; a++) kso[mbase + a] = ks[a];
  }
}

// ---------------- exclusive prefix over chunks (in place) ----------------
__global__ __launch_bounds__(256) void kvscan(float* __restrict__ kv, float* __restrict__ ksum){
  int bh = blockIdx.x;
  int p = blockIdx.y;
  int tid = threadIdx.x;
  if (p < 8){
    size_t base = (size_t)bh * 16 * 8192;
    int idx0 = p * 1024 + tid;
    for (int rep = 0; rep < 4; rep++){
      int idx = idx0 + rep * 256;
      float run = 0.f;
#pragma unroll
      for (int c = 0; c < 16; c++){
        size_t off = base + (size_t)c * 8192 + idx;
        float v = kv[off]; kv[off] = run; run += v;
      }
    }
  } else if (tid < 128){
    size_t base = (size_t)bh * 16 * 128;
    float run = 0.f;
#pragma unroll
    for (int c = 0; c < 16; c++){
      size_t off = base + c * 128 + tid;
      float v = ksum[off]; ksum[off] = run; run += v;
    }
  }
}

// ---------------- MFMA fused attention ----------------
__global__ __launch_bounds__(512) void attn_fused(const u16* __restrict__ Qp, const u16* __restrict__ Kp,
                                                  const u16* __restrict__ vt, const float* __restrict__ kvp,
                                                  const float* __restrict__ ksum, u16* __restrict__ aout){
  __shared__ __align__(16) u16 sm[53248];
  int blk = blockIdx.x, bh = blk >> 4, c = blk & 15;
  int b = bh >> 4, h = bh & 15;
  int tid = threadIdx.x, w = tid >> 6, lane = tid & 63;
  size_t base = (size_t)bh * 2048 + c * 128;
  const u16* Qc = Qp + base * 128;
  const u16* Kc = Kp + base * 128;
  const u16* vtc = vt + (size_t)bh * 64 * 2048 + c * 128;
  const float* kvc = kvp + ((size_t)bh * 16 + c) * 8192;
  const float* ksc = ksum + ((size_t)bh * 16 + c) * 128;
  u16* Qs = sm;
  u16* Ks = sm + 16384;
  u16* B2 = sm + 32768;

#pragma unroll
  for (int i = 0; i < 4; i++){
    int id = tid * 4 + i;
    int r = id >> 4, kc = id & 15;
    int swo = (kc ^ (r & 15)) << 3;
    *(bf16x8*)(Qs + r * 128 + swo) = *(const bf16x8*)(Qc + (size_t)r * 128 + kc * 8);
    *(bf16x8*)(Ks + r * 128 + swo) = *(const bf16x8*)(Kc + (size_t)r * 128 + kc * 8);
  }
#pragma unroll
  for (int i = 0; i < 2; i++){
    int id = tid * 2 + i;
    int d = id >> 4, kc = id & 15;
    *(bf16x8*)(B2 + d * 256 + ((kc ^ (d & 31)) << 3)) = *(const bf16x8*)(vtc + (size_t)d * 2048 + kc * 8);
  }
#pragma unroll
  for (int i = 0; i < 2; i++){
    int id = tid * 2 + i;
    int d = id >> 4, mc = id & 15;
    const float* s8 = kvc + d * 128 + mc * 8;
    float4 f0 = *(const float4*)(s8);
    float4 f1 = *(const float4*)(s8 + 4);
    bf16x8 pk;
    pk[0] = (short)f2b(f0.x); pk[1] = (short)f2b(f0.y); pk[2] = (short)f2b(f0.z); pk[3] = (short)f2b(f0.w);
    pk[4] = (short)f2b(f1.x); pk[5] = (short)f2b(f1.y); pk[6] = (short)f2b(f1.z); pk[7] = (short)f2b(f1.w);
    int kc = 16 + mc;
    *(bf16x8*)(B2 + d * 256 + ((kc ^ (d & 31)) << 3)) = pk;
  }
  {
    int row = 64 + (tid >> 5), kc = tid & 31;
    bf16x8 pk = {};
    if (row == 64){
      if (kc < 16){
#pragma unroll
        for (int e = 0; e < 8; e++) pk[e] = (short)0x3F80;
      } else {
        const float* s8 = ksc + (kc - 16) * 8;
        float4 f0 = *(const float4*)(s8);
        float4 f1 = *(const float4*)(s8 + 4);
        pk[0] = (short)f2b(f0.x); pk[1] = (short)f2b(f0.y); pk[2] = (short)f2b(f0.z); pk[3] = (short)f2b(f0.w);
        pk[4] = (short)f2b(f1.x); pk[5] = (short)f2b(f1.y); pk[6] = (short)f2b(f1.z); pk[7] = (short)f2b(f1.w);
      }
    }
    *(bf16x8*)(B2 + row * 256 + ((kc ^ (row & 31)) << 3)) = pk;
  }
  __syncthreads();

  int wm = w >> 2, wn = w & 3;
  f32x4 acc1[4][2] = {};
#pragma unroll
  for (int kk = 0; kk < 4; kk++){
    int kc = kk * 4 + (lane >> 4);
    bf16x8 fa[4], fb[2];
#pragma unroll
    for (int m = 0; m < 4; m++){
      int row = wm * 64 + m * 16 + (lane & 15);
      fa[m] = *(const bf16x8*)(Qs + row * 128 + ((kc ^ (row & 15)) << 3));
    }
#pragma unroll
    for (int n = 0; n < 2; n++){
      int row = wn * 32 + n * 16 + (lane & 15);
      fb[n] = *(const bf16x8*)(Ks + row * 128 + ((kc ^ (row & 15)) << 3));
    }
#pragma unroll
    for (int m = 0; m < 4; m++)
#pragma unroll
      for (int n = 0; n < 2; n++)
        acc1[m][n] = __builtin_amdgcn_mfma_f32_16x16x32_bf16(fa[m], fb[n], acc1[m][n], 0, 0, 0);
  }
  __syncthreads();

#pragma unroll
  for (int m = 0; m < 4; m++)
#pragma unroll
    for (int n = 0; n < 2; n++)
#pragma unroll
      for (int r = 0; r < 4; r++){
        int i = wm * 64 + m * 16 + ((lane >> 4) << 2) + r;
        int j = wn * 32 + n * 16 + (lane & 15);
        float v = (j <= i) ? acc1[m][n][r] : 0.f;
        Ks[i * 128 + (((j >> 3) ^ (i & 15)) << 3) + (j & 7)] = f2b(v);
      }
  __syncthreads();

  f32x4 acc2[5] = {};
#pragma unroll
  for (int kk = 0; kk < 8; kk++){
    int kc = kk * 4 + (lane >> 4);
    int rowA = w * 16 + (lane & 15);
    bf16x8 fa2;
    if (kk < 4) fa2 = *(const bf16x8*)(Ks + rowA * 128 + ((kc ^ (rowA & 15)) << 3));
    else        fa2 = *(const bf16x8*)(Qs + rowA * 128 + (((kc - 16) ^ (rowA & 15)) << 3));
#pragma unroll
    for (int n = 0; n < 5; n++){
      int d = n * 16 + (lane & 15);
      bf16x8 fb2 = *(const bf16x8*)(B2 + d * 256 + ((kc ^ (d & 31)) << 3));
      acc2[n] = __builtin_amdgcn_mfma_f32_16x16x32_bf16(fa2, fb2, acc2[n], 0, 0, 0);
    }
  }

  float dd[4];
#pragma unroll
  for (int r = 0; r < 4; r++) dd[r] = __shfl(acc2[4][r], lane & 48) + 1e-6f;
  size_t obase = ((size_t)b * 2048 + c * 128) * 1024 + (size_t)h * 64;
#pragma unroll
  for (int n = 0; n < 4; n++)
#pragma unroll
    for (int r = 0; r < 4; r++){
      int i = w * 16 + ((lane >> 4) << 2) + r;
      int d = n * 16 + (lane & 15);
      aout[obase + (size_t)i * 1024 + d] = f2b(acc2[n][r] / dd[r]);
    }
}

// ---------------- universal residual-add + LayerNorm ----------------
// X1: f32 (X1f) or bf16 (X1b), one non-null. P0 bf16; P1 optional bf16.
// outputs: outf f32 (optional), outb/outb2 bf16 (optional). All block-uniform branches.
__global__ __launch_bounds__(256) void lnr(const float* X1f, const u16* X1b,
                                           const u16* P0, const u16* P1,
                                           const float* __restrict__ g, const float* __restrict__ bb,
                                           float* outf, u16* outb, u16* outb2){
  __shared__ float red[2][4];
  int row = blockIdx.x, tid = threadIdx.x, w = tid >> 6, lane = tid & 63;
  size_t ro = (size_t)row * 1024 + tid * 4;
  float x0, x1, x2, x3;
  if (X1f){
    float4 a = *(const float4*)(X1f + ro);
    x0 = a.x; x1 = a.y; x2 = a.z; x3 = a.w;
  } else {
    ushort4 a = *(const ushort4*)(X1b + ro);
    x0 = b2f(a.x); x1 = b2f(a.y); x2 = b2f(a.z); x3 = b2f(a.w);
  }
  {
    ushort4 p0 = *(const ushort4*)(P0 + ro);
    x0 += b2f(p0.x); x1 += b2f(p0.y); x2 += b2f(p0.z); x3 += b2f(p0.w);
  }
  if (P1){
    ushort4 p1 = *(const ushort4*)(P1 + ro);
    x0 += b2f(p1.x); x1 += b2f(p1.y); x2 += b2f(p1.z); x3 += b2f(p1.w);
  }
  float s1 = x0 + x1 + x2 + x3;
  float s2 = x0 * x0 + x1 * x1 + x2 * x2 + x3 * x3;
#pragma unroll
  for (int off = 32; off; off >>= 1){ s1 += __shfl_xor(s1, off); s2 += __shfl_xor(s2, off); }
  if (lane == 0){ red[0][w] = s1; red[1][w] = s2; }
  __syncthreads();
  float t1 = red[0][0] + red[0][1] + red[0][2] + red[0][3];
  float t2 = red[1][0] + red[1][1] + red[1][2] + red[1][3];
  float mu = t1 * (1.f / 1024.f);
  float var = t2 * (1.f / 1024.f) - mu * mu;
  float rs = rsqrtf(var + 1e-5f);
  float4 gv = *(const float4*)(g + tid * 4);
  float4 bv = *(const float4*)(bb + tid * 4);
  float o0 = (x0 - mu) * rs * gv.x + bv.x;
  float o1 = (x1 - mu) * rs * gv.y + bv.y;
  float o2 = (x2 - mu) * rs * gv.z + bv.z;
  float o3 = (x3 - mu) * rs * gv.w + bv.w;
  if (outf) *(float4*)(outf + ro) = make_float4(o0, o1, o2, o3);
  ushort4 ob = make_ushort4(f2b(o0), f2b(o1), f2b(o2), f2b(o3));
  if (outb)  *(ushort4*)(outb + ro)  = ob;
  if (outb2) *(ushort4*)(outb2 + ro) = ob;
}

// ---------------- host ----------------
extern "C" void kernel_launch(void* const* d_in, const int* in_sizes, int n_in,
                              void* d_out, int out_size, void* d_ws, size_t ws_size,
                              hipStream_t stream){
  (void)in_sizes; (void)n_in;
  const float* x   = (const float*)d_in[0];
  const float* Wq  = (const float*)d_in[1];
  const float* bq  = (const float*)d_in[2];
  const float* Wk  = (const float*)d_in[3];
  const float* bk  = (const float*)d_in[4];
  const float* Wv  = (const float*)d_in[5];
  const float* bv  = (const float*)d_in[6];
  const float* Wo  = (const float*)d_in[7];
  const float* bo  = (const float*)d_in[8];
  const float* om  = (const float*)d_in[9];
  const float* g1  = (const float*)d_in[10];
  const float* be1 = (const float*)d_in[11];
  const float* W1  = (const float*)d_in[12];
  const float* bf1 = (const float*)d_in[13];
  const float* W2  = (const float*)d_in[14];
  const float* bf2 = (const float*)d_in[15];
  const float* g2  = (const float*)d_in[16];
  const float* be2 = (const float*)d_in[17];

  char* ws = (char*)d_ws;
  size_t off = 0;
  auto alloc = [&](size_t bytes) -> void* {
    void* p = ws + off; off += (bytes + 255) & ~(size_t)255; return p;
  };
  u16* Wcat = (u16*)alloc(3072ull * 1024 * 2);
  u16* Wot  = (u16*)alloc(1024ull * 1024 * 2);
  u16* W1t  = (u16*)alloc(4096ull * 1024 * 2);
  u16* W2t  = (u16*)alloc(1024ull * 4096 * 2);
  u16* omT  = (u16*)alloc(64ull * 64 * 2);
  float* bcat = (float*)alloc(6ull * 3072 * 4);
  float* zbuf = (float*)alloc(1024 * 4);
  u16* Xb  = (u16*)alloc(8192ull * 1024 * 2);
  u16* qb  = (u16*)alloc(131072ull * 64 * 2);   // contiguous qb|kb|vt|Qp for ybuf alias
  u16* kb  = (u16*)alloc(131072ull * 64 * 2);
  u16* vt  = (u16*)alloc(131072ull * 64 * 2);
  u16* Qp  = (u16*)alloc(131072ull * 128 * 2);
  u16* Kp  = (u16*)alloc(131072ull * 128 * 2);
  float* ksum = (float*)alloc(64ull * 16 * 128 * 4);

  if (off > ws_size){
    fillv<<<(out_size + 255) / 256, 256, 0, stream>>>((float*)d_out, (float)(ws_size >> 20), out_size);
    return;
  }

  float* kvbuf  = (float*)qb;            // kv^T f32 32MB over qb+kb (dead after phi2)
  u16*  ybuf   = qb;                    // FFN intermediate bf16 [8192][4096] over qb..Qp[0:16MB]
  u16*  wooutb = Qp;                    // Wo out bf16 16MB (Qp dead after attn)
  u16*  w2outb = Qp + 8388608;          // W2 partial kz=0, bf16 16MB (after ybuf span)
  u16*  w2p1   = Kp + 8388608;          // W2 partial kz=1, bf16 16MB (Kp[16:32], dead after attn)
  u16*  residb = (u16*)d_out;           // bf16 residual stream in d_out[0:16MB]; final layer writes f32

  cvt16<<<8192, 256, 0, stream>>>(x, Xb);
  catbias<<<72, 256, 0, stream>>>(bq, bk, bv, bcat);
  fillv<<<4, 256, 0, stream>>>(zbuf, 0.f, 1024);

  for (int l = 0; l < 6; l++){
    size_t o1k = (size_t)l * 1024 * 1024;
    size_t o4k = (size_t)l * 4096 * 1024;
    wtrans7<<<12292, 256, 0, stream>>>(Wq + o1k, Wk + o1k, Wv + o1k, Wo + o1k,
                                       W1 + o4k, W2 + o4k, om + (size_t)l * 4096,
                                       Wcat, Wot, W1t, W2t, omT);

    gemm_bt<5><<<dim3(24, 64), 256, 0, stream>>>(Xb, Wcat, bcat + l * 3072, qb, 8192, 3072, 1024, 1024, 1024);
    phi2<<<2048, 256, 0, stream>>>(qb, kb, omT, Qp, Kp);
    kvchunk<<<1024, 256, 0, stream>>>(Kp, vt, kvbuf, ksum);
    kvscan<<<dim3(64, 9), 256, 0, stream>>>(kvbuf, ksum);
    attn_fused<<<1024, 512, 0, stream>>>(Qp, Kp, vt, kvbuf, ksum, Xb);
    gemm_bt<6><<<dim3(8, 64), 256, 0, stream>>>(Xb, Wot, bo + l * 1024, wooutb, 8192, 1024, 1024, 1024, 1024);
    // ln1: X1 = x (l==0, f32) or residb (bf16); out = Xb only (h1 lives in Xb)
    lnr<<<8192, 256, 0, stream>>>(l == 0 ? x : nullptr, l == 0 ? nullptr : residb,
                                  wooutb, nullptr, g1 + l * 1024, be1 + l * 1024,
                                  nullptr, Xb, nullptr);
    gemm8p<2><<<dim3(16, 32), 512, 0, stream>>>(Xb, W1t, bf1 + l * 4096, ybuf, 8192, 4096, 1024, 1024, 1024);
    gemm8pk<<<dim3(256), 512, 0, stream>>>(ybuf, W2t, bf2 + l * 1024, zbuf, w2outb, w2p1,
                                           8192, 1024, 2048, 4096, 4096);
    // ln2: X1 = Xb (h1 bf16, survives: W2 partials no longer touch Xb)
    if (l == 5)
      lnr<<<8192, 256, 0, stream>>>(nullptr, Xb, w2outb, w2p1, g2 + l * 1024, be2 + l * 1024,
                                    (float*)d_out, nullptr, nullptr);
    else
      lnr<<<8192, 256, 0, stream>>>(nullptr, Xb, w2outb, w2p1, g2 + l * 1024, be2 + l * 1024,
                                    nullptr, Xb, residb);
  }
}

// Round 17
// 2411.308 us; speedup vs baseline: 1.0777x; 1.0219x over previous
//
#include <hip/hip_runtime.h>

typedef unsigned short u16;
typedef __attribute__((ext_vector_type(8))) short bf16x8;
typedef __attribute__((ext_vector_type(4))) float f32x4;

#define DEV __device__ __forceinline__

DEV float b2f(u16 h){ return __uint_as_float(((unsigned)h) << 16); }
DEV u16 f2b(float f){ unsigned u = __float_as_uint(f); u += 0x7FFFu + ((u >> 16) & 1u); return (u16)(u >> 16); }

DEV void gload16(const u16* g, u16* l){
  __builtin_amdgcn_global_load_lds((const __attribute__((address_space(1))) unsigned*)g,
                                   (__attribute__((address_space(3))) unsigned*)l, 16, 0, 0);
}

// ---------------- merged per-layer weight transpose: 7 tensors in one launch ----------------
__global__ __launch_bounds__(256) void wtrans7(const float* __restrict__ Wq, const float* __restrict__ Wk,
                                               const float* __restrict__ Wv, const float* __restrict__ Wo,
                                               const float* __restrict__ W1, const float* __restrict__ W2,
                                               const float* __restrict__ om,
                                               u16* __restrict__ Wcat, u16* __restrict__ Wot,
                                               u16* __restrict__ W1t, u16* __restrict__ W2t,
                                               u16* __restrict__ omT){
  __shared__ float tile[32][33];
  int id = blockIdx.x;
  const float* src; u16* dst; int K, N, kb, nb; float scale = 1.f;
  if (id < 4096){
    int wsel = id >> 10, loc = id & 1023;
    kb = loc >> 5; nb = loc & 31; K = 1024; N = 1024;
    src = (wsel == 0) ? Wq : (wsel == 1) ? Wk : (wsel == 2) ? Wv : Wo;
    dst = (wsel < 3) ? Wcat + (size_t)wsel * 1048576 : Wot;
  } else if (id < 8192){
    int loc = id - 4096;
    kb = loc & 31; nb = loc >> 5; K = 1024; N = 4096;
    src = W1; dst = W1t;
  } else if (id < 12288){
    int loc = id - 8192;
    kb = loc & 127; nb = loc >> 7; K = 4096; N = 1024;
    src = W2; dst = W2t;
  } else {
    int loc = id - 12288;
    kb = loc & 1; nb = loc >> 1; K = 64; N = 64;
    src = om; dst = omT; scale = 0.35355339059327373f;
  }
  int k0 = kb * 32, n0 = nb * 32;
  int tid = threadIdx.x;
#pragma unroll
  for (int i = 0; i < 4; i++){
    int idx = tid + i * 256;
    int r = idx >> 5, c = idx & 31;
    tile[r][c] = src[(size_t)(k0 + r) * N + n0 + c];
  }
  __syncthreads();
#pragma unroll
  for (int i = 0; i < 4; i++){
    int idx = tid + i * 256;
    int r = idx >> 5, c = idx & 31;
    dst[(size_t)(n0 + r) * K + k0 + c] = f2b(tile[c][r] * scale);
  }
}

// ---------------- f32 -> bf16 convert ----------------
__global__ __launch_bounds__(256) void cvt16(const float* __restrict__ src, u16* __restrict__ dst){
  size_t i = ((size_t)blockIdx.x * 256 + threadIdx.x) * 4;
  float4 f = *(const float4*)(src + i);
  ushort4 o = make_ushort4(f2b(f.x), f2b(f.y), f2b(f.z), f2b(f.w));
  *(ushort4*)(dst + i) = o;
}

// ---------------- bias concat (all layers): [6][3072] = bq|bk|bv ----------------
__global__ void catbias(const float* __restrict__ bq, const float* __restrict__ bk,
                        const float* __restrict__ bv, float* __restrict__ bcat){
  int i = blockIdx.x * 256 + threadIdx.x;
  if (i >= 6 * 3072) return;
  int l = i / 3072, j = i % 3072;
  float v = (j < 1024) ? bq[l * 1024 + j] : (j < 2048) ? bk[l * 1024 + j - 1024] : bv[l * 1024 + j - 2048];
  bcat[i] = v;
}

// ---------------- diagnostic / zero fill ----------------
__global__ void fillv(float* __restrict__ p, float v, int n){
  int i = blockIdx.x * 256 + threadIdx.x;
  if (i < n) p[i] = v;
}

// ---------------- 128^2 bf16 MFMA GEMM (gload_lds dbuf + counted vmcnt + XCD swizzle) ----------------
// EPI 2: relu bf16 [M,N] ; EPI 5: fused QKV ; EPI 6: bf16 [M,N]
DEV int swz(int r){ return (r & 3) ^ ((r >> 2) & 3); }

template<int EPI>
__global__ __launch_bounds__(256) void gemm_bt(const u16* __restrict__ A, const u16* __restrict__ Bt,
                                               const float* __restrict__ bias, void* __restrict__ outp,
                                               int M, int N, int K, int ldA, int ldB){
  __shared__ __align__(16) u16 As[2][4096];
  __shared__ __align__(16) u16 Bs[2][4096];
  const int tid = threadIdx.x;
  const int lane = tid & 63;
  const int w = tid >> 6;
  const int wm = w >> 1, wn = w & 1;
  int nx = gridDim.x;
  int nwg = nx * gridDim.y;
  int lin = blockIdx.y * nx + blockIdx.x;
  int cpx = nwg >> 3;
  int sw = (lin & 7) * cpx + (lin >> 3);
  const int m0 = (sw / nx) * 128;
  const int n0 = (sw % nx) * 128;

  int r0 = tid >> 2, c0 = tid & 3;
  int r1 = r0 + 64;
  int cs0 = c0 ^ swz(r0);
  int cs1 = c0 ^ swz(r1);
  const u16* ag0 = A + (size_t)(m0 + r0) * ldA + cs0 * 8;
  const u16* ag1 = A + (size_t)(m0 + r1) * ldA + cs1 * 8;
  const u16* bg0 = Bt + (size_t)(n0 + r0) * ldB + cs0 * 8;
  const u16* bg1 = Bt + (size_t)(n0 + r1) * ldB + cs1 * 8;

  f32x4 acc[4][4] = {};
  const int KT = K >> 5;

  gload16(ag0, &As[0][w * 512]);
  gload16(ag1, &As[0][2048 + w * 512]);
  gload16(bg0, &Bs[0][w * 512]);
  gload16(bg1, &Bs[0][2048 + w * 512]);

  for (int kt = 0; kt < KT; kt++){
    int cur = kt & 1;
    if (kt + 1 < KT){
      int ko = (kt + 1) << 5;
      gload16(ag0 + ko, &As[cur ^ 1][w * 512]);
      gload16(ag1 + ko, &As[cur ^ 1][2048 + w * 512]);
      gload16(bg0 + ko, &Bs[cur ^ 1][w * 512]);
      gload16(bg1 + ko, &Bs[cur ^ 1][2048 + w * 512]);
      asm volatile("s_waitcnt vmcnt(4)" ::: "memory");
    } else {
      asm volatile("s_waitcnt vmcnt(0)" ::: "memory");
    }
    __builtin_amdgcn_s_barrier();
    bf16x8 fa[4], fb[4];
#pragma unroll
    for (int m = 0; m < 4; m++){
      int row = wm * 64 + m * 16 + (lane & 15);
      int cc = (lane >> 4) ^ swz(row);
      fa[m] = *(const bf16x8*)(&As[cur][row * 32 + cc * 8]);
    }
#pragma unroll
    for (int n = 0; n < 4; n++){
      int row = wn * 64 + n * 16 + (lane & 15);
      int cc = (lane >> 4) ^ swz(row);
      fb[n] = *(const bf16x8*)(&Bs[cur][row * 32 + cc * 8]);
    }
#pragma unroll
    for (int m = 0; m < 4; m++)
#pragma unroll
      for (int n = 0; n < 4; n++)
        acc[m][n] = __builtin_amdgcn_mfma_f32_16x16x32_bf16(fa[m], fb[n], acc[m][n], 0, 0, 0);
    asm volatile("s_waitcnt lgkmcnt(0)" ::: "memory");
    __builtin_amdgcn_s_barrier();
  }

#pragma unroll
  for (int m = 0; m < 4; m++){
    int rowb = m0 + wm * 64 + m * 16 + ((lane >> 4) << 2);
#pragma unroll
    for (int n = 0; n < 4; n++){
      int col = n0 + wn * 64 + n * 16 + (lane & 15);
      float bv = bias[col];
      if (EPI == 5 && col >= 2048){
        int cv = col - 2048, hh = cv >> 6, dh = cv & 63;
        int bIdx = rowb >> 11, s4 = rowb & 2047;
        ushort4 pk = make_ushort4(f2b(acc[m][n][0] + bv), f2b(acc[m][n][1] + bv),
                                  f2b(acc[m][n][2] + bv), f2b(acc[m][n][3] + bv));
        *(ushort4*)&((u16*)outp + 16777216)[((size_t)(bIdx * 16 + hh) * 64 + dh) * 2048 + s4] = pk;
      } else {
#pragma unroll
        for (int r = 0; r < 4; r++){
          float v = acc[m][n][r] + bv;
          int rr = rowb + r;
          if (EPI == 5){
            u16* dst0 = (u16*)outp + (col < 1024 ? 0 : 8388608);
            int cv = col & 1023, hh = cv >> 6, dh = cv & 63;
            int bIdx = rr >> 11, s = rr & 2047;
            dst0[(((size_t)(bIdx * 16 + hh) * 2048 + s) << 6) + dh] = f2b(v);
          } else if (EPI == 2){
            ((u16*)outp)[(size_t)rr * N + col] = f2b(v > 0.f ? v : 0.f);
          } else {
            ((u16*)outp)[(size_t)rr * N + col] = f2b(v);
          }
        }
      }
    }
  }
}

// ---------------- 8-phase 256^2 GEMM (m201 template): BK=64, K-half subtiles, counted vmcnt ----------------
// EPI 2: relu bf16 ; EPI 6: bf16   (scalar epilogue)
template<int EPI>
__global__ __launch_bounds__(512, 1) void gemm8p(const u16* __restrict__ A, const u16* __restrict__ Bt,
                                                 const float* __restrict__ bias, void* __restrict__ outp,
                                                 int M, int N, int K, int ldA, int ldB){
  __shared__ __align__(16) u16 As[2][16384];
  __shared__ __align__(16) u16 Bs[2][16384];
  const int tid = threadIdx.x;
  const int lane = tid & 63;
  const int w = tid >> 6;
  const int wm = w >> 2, wn = w & 3;
  int nx = gridDim.x;
  int nwg = nx * gridDim.y;
  int lin = blockIdx.y * nx + blockIdx.x;
  int cpx = nwg >> 3;
  int sw = (lin & 7) * cpx + (lin >> 3);
  const int m0 = (sw / nx) * 256;
  const int n0 = (sw % nx) * 256;

  const int id1 = 512 + tid;
  const int r0 = tid >> 2, c20 = tid & 3;
  const int r1 = id1 >> 2, c21 = id1 & 3;
  const int cs0 = c20 ^ ((r0 >> 1) & 3);
  const int cs1 = c21 ^ ((r1 >> 1) & 3);
  const u16* Ag0 = A + (size_t)(m0 + r0) * ldA + cs0 * 8;
  const u16* Ag1 = A + (size_t)(m0 + r1) * ldA + cs1 * 8;
  const u16* Bg0 = Bt + (size_t)(n0 + r0) * ldB + cs0 * 8;
  const u16* Bg1 = Bt + (size_t)(n0 + r1) * ldB + cs1 * 8;

  f32x4 acc[8][4] = {};
  const int KT = K >> 6;

  auto stA = [&](int buf, int kt, int ks){
    int kc = kt * 64 + ks * 32;
    gload16(Ag0 + kc, &As[buf][ks * 8192 + w * 512]);
    gload16(Ag1 + kc, &As[buf][ks * 8192 + 4096 + w * 512]);
  };
  auto stB = [&](int buf, int kt, int ks){
    int kc = kt * 64 + ks * 32;
    gload16(Bg0 + kc, &Bs[buf][ks * 8192 + w * 512]);
    gload16(Bg1 + kc, &Bs[buf][ks * 8192 + 4096 + w * 512]);
  };

  stA(0, 0, 0); stB(0, 0, 0); stA(0, 0, 1); stB(0, 0, 1);

  for (int t = 0; t < KT; t++){
    int c = t & 1, nb = c ^ 1;
    bool pf = (t + 1 < KT);
    asm volatile("s_waitcnt vmcnt(4)" ::: "memory");
    __builtin_amdgcn_s_barrier();

#pragma unroll
    for (int ks = 0; ks < 2; ks++){
      if (ks == 1){
        if (pf) asm volatile("s_waitcnt vmcnt(4)" ::: "memory");
        else    asm volatile("s_waitcnt vmcnt(0)" ::: "memory");
        __builtin_amdgcn_s_barrier();
      }
      if (pf){ if (ks == 0) stA(nb, t + 1, 0); else stA(nb, t + 1, 1); }
      bf16x8 fa[8], fb[2];
#pragma unroll
      for (int m = 0; m < 8; m++){
        int row = wm * 128 + m * 16 + (lane & 15);
        int slot = (lane >> 4) ^ ((row >> 1) & 3);
        fa[m] = *(const bf16x8*)(&As[c][ks * 8192 + row * 32 + slot * 8]);
      }
#pragma unroll
      for (int nn = 0; nn < 2; nn++){
        int row = wn * 64 + nn * 16 + (lane & 15);
        int slot = (lane >> 4) ^ ((row >> 1) & 3);
        fb[nn] = *(const bf16x8*)(&Bs[c][ks * 8192 + row * 32 + slot * 8]);
      }
      __builtin_amdgcn_s_setprio(1);
#pragma unroll
      for (int m = 0; m < 8; m++)
#pragma unroll
        for (int nn = 0; nn < 2; nn++)
          acc[m][nn] = __builtin_amdgcn_mfma_f32_16x16x32_bf16(fa[m], fb[nn], acc[m][nn], 0, 0, 0);
      __builtin_amdgcn_s_setprio(0);
      if (pf){ if (ks == 0) stB(nb, t + 1, 0); else stB(nb, t + 1, 1); }
#pragma unroll
      for (int nn = 0; nn < 2; nn++){
        int row = wn * 64 + 32 + nn * 16 + (lane & 15);
        int slot = (lane >> 4) ^ ((row >> 1) & 3);
        fb[nn] = *(const bf16x8*)(&Bs[c][ks * 8192 + row * 32 + slot * 8]);
      }
      __builtin_amdgcn_s_setprio(1);
#pragma unroll
      for (int m = 0; m < 8; m++)
#pragma unroll
        for (int nn = 0; nn < 2; nn++)
          acc[m][2 + nn] = __builtin_amdgcn_mfma_f32_16x16x32_bf16(fa[m], fb[nn], acc[m][2 + nn], 0, 0, 0);
      __builtin_amdgcn_s_setprio(0);
    }
  }

#pragma unroll
  for (int m = 0; m < 8; m++){
    int rowb = m0 + wm * 128 + m * 16 + ((lane >> 4) << 2);
#pragma unroll
    for (int n = 0; n < 4; n++){
      int col = n0 + wn * 64 + n * 16 + (lane & 15);
      float bv = bias[col];
#pragma unroll
      for (int r = 0; r < 4; r++){
        float v = acc[m][n][r] + bv;
        int rr = rowb + r;
        if (EPI == 2) ((u16*)outp)[(size_t)rr * N + col] = f2b(v > 0.f ? v : 0.f);
        else          ((u16*)outp)[(size_t)rr * N + col] = f2b(v);
      }
    }
  }
}

// ---------------- 8-phase 256^2 split-K GEMM: 256 blocks = (4 n)x(32 m)x(2 kz), bf16 partials ----------------
__global__ __launch_bounds__(512, 1) void gemm8pk(const u16* __restrict__ A, const u16* __restrict__ Bt,
                                                  const float* __restrict__ bias0, const float* __restrict__ bias1,
                                                  u16* __restrict__ out0, u16* __restrict__ out1,
                                                  int M, int N, int Khalf, int ldA, int ldB){
  __shared__ __align__(16) u16 As[2][16384];
  __shared__ __align__(16) u16 Bs[2][16384];
  const int tid = threadIdx.x;
  const int lane = tid & 63;
  const int w = tid >> 6;
  const int wm = w >> 2, wn = w & 3;
  int lin = blockIdx.x;               // 256 blocks
  int cpx = gridDim.x >> 3;
  int sw = (lin & 7) * cpx + (lin >> 3);
  const int kz = sw & 1;
  const int t2 = sw >> 1;
  const int n0 = (t2 & 3) * 256;
  const int m0 = (t2 >> 2) * 256;
  const u16* Ab = A + kz * Khalf;
  const u16* Bb = Bt + kz * Khalf;
  u16* outp = kz ? out1 : out0;
  const float* bias = kz ? bias1 : bias0;

  const int id1 = 512 + tid;
  const int r0 = tid >> 2, c20 = tid & 3;
  const int r1 = id1 >> 2, c21 = id1 & 3;
  const int cs0 = c20 ^ ((r0 >> 1) & 3);
  const int cs1 = c21 ^ ((r1 >> 1) & 3);
  const u16* Ag0 = Ab + (size_t)(m0 + r0) * ldA + cs0 * 8;
  const u16* Ag1 = Ab + (size_t)(m0 + r1) * ldA + cs1 * 8;
  const u16* Bg0 = Bb + (size_t)(n0 + r0) * ldB + cs0 * 8;
  const u16* Bg1 = Bb + (size_t)(n0 + r1) * ldB + cs1 * 8;

  f32x4 acc[8][4] = {};
  const int KT = Khalf >> 6;

  auto stA = [&](int buf, int kt, int ks){
    int kc = kt * 64 + ks * 32;
    gload16(Ag0 + kc, &As[buf][ks * 8192 + w * 512]);
    gload16(Ag1 + kc, &As[buf][ks * 8192 + 4096 + w * 512]);
  };
  auto stB = [&](int buf, int kt, int ks){
    int kc = kt * 64 + ks * 32;
    gload16(Bg0 + kc, &Bs[buf][ks * 8192 + w * 512]);
    gload16(Bg1 + kc, &Bs[buf][ks * 8192 + 4096 + w * 512]);
  };

  stA(0, 0, 0); stB(0, 0, 0); stA(0, 0, 1); stB(0, 0, 1);

  for (int t = 0; t < KT; t++){
    int c = t & 1, nb = c ^ 1;
    bool pf = (t + 1 < KT);
    asm volatile("s_waitcnt vmcnt(4)" ::: "memory");
    __builtin_amdgcn_s_barrier();

#pragma unroll
    for (int ks = 0; ks < 2; ks++){
      if (ks == 1){
        if (pf) asm volatile("s_waitcnt vmcnt(4)" ::: "memory");
        else    asm volatile("s_waitcnt vmcnt(0)" ::: "memory");
        __builtin_amdgcn_s_barrier();
      }
      if (pf){ if (ks == 0) stA(nb, t + 1, 0); else stA(nb, t + 1, 1); }
      bf16x8 fa[8], fb[2];
#pragma unroll
      for (int m = 0; m < 8; m++){
        int row = wm * 128 + m * 16 + (lane & 15);
        int slot = (lane >> 4) ^ ((row >> 1) & 3);
        fa[m] = *(const bf16x8*)(&As[c][ks * 8192 + row * 32 + slot * 8]);
      }
#pragma unroll
      for (int nn = 0; nn < 2; nn++){
        int row = wn * 64 + nn * 16 + (lane & 15);
        int slot = (lane >> 4) ^ ((row >> 1) & 3);
        fb[nn] = *(const bf16x8*)(&Bs[c][ks * 8192 + row * 32 + slot * 8]);
      }
      __builtin_amdgcn_s_setprio(1);
#pragma unroll
      for (int m = 0; m < 8; m++)
#pragma unroll
        for (int nn = 0; nn < 2; nn++)
          acc[m][nn] = __builtin_amdgcn_mfma_f32_16x16x32_bf16(fa[m], fb[nn], acc[m][nn], 0, 0, 0);
      __builtin_amdgcn_s_setprio(0);
      if (pf){ if (ks == 0) stB(nb, t + 1, 0); else stB(nb, t + 1, 1); }
#pragma unroll
      for (int nn = 0; nn < 2; nn++){
        int row = wn * 64 + 32 + nn * 16 + (lane & 15);
        int slot = (lane >> 4) ^ ((row >> 1) & 3);
        fb[nn] = *(const bf16x8*)(&Bs[c][ks * 8192 + row * 32 + slot * 8]);
      }
      __builtin_amdgcn_s_setprio(1);
#pragma unroll
      for (int m = 0; m < 8; m++)
#pragma unroll
        for (int nn = 0; nn < 2; nn++)
          acc[m][2 + nn] = __builtin_amdgcn_mfma_f32_16x16x32_bf16(fa[m], fb[nn], acc[m][2 + nn], 0, 0, 0);
      __builtin_amdgcn_s_setprio(0);
    }
  }

#pragma unroll
  for (int m = 0; m < 8; m++){
    int rowb = m0 + wm * 128 + m * 16 + ((lane >> 4) << 2);
#pragma unroll
    for (int n = 0; n < 4; n++){
      int col = n0 + wn * 64 + n * 16 + (lane & 15);
      float bv = bias[col];
#pragma unroll
      for (int r = 0; r < 4; r++)
        outp[(size_t)(rowb + r) * N + col] = f2b(acc[m][n][r] + bv);
    }
  }
}

// ---------------- FAVOR phi v2 (MFMA) ----------------
__global__ __launch_bounds__(256) void phi2(const u16* __restrict__ qb, const u16* __restrict__ kb,
                                            const u16* __restrict__ omT,
                                            u16* __restrict__ Qp, u16* __restrict__ Kp){
  __shared__ __align__(16) u16 qs[128 * 64];
  __shared__ __align__(16) u16 wl[64 * 64];
  __shared__ __align__(16) u16 ph[128 * 128];
  __shared__ float part[2][128];
  __shared__ float nrm[128];
  int tid = threadIdx.x, w = tid >> 6, lane = tid & 63;
  int blk = blockIdx.x;
  const u16* src; u16* dst; int row0;
  if (blk < 1024){ src = qb; dst = Qp; row0 = blk * 128; }
  else           { src = kb; dst = Kp; row0 = (blk - 1024) * 128; }
  const u16* g = src + (size_t)row0 * 64;
#pragma unroll
  for (int i = 0; i < 4; i++){
    int id = tid * 4 + i;
    int r = id >> 3, kc = id & 7;
    *(bf16x8*)(qs + r * 64 + ((kc ^ (r & 7)) << 3)) = *(const bf16x8*)(g + r * 64 + kc * 8);
  }
#pragma unroll
  for (int i = 0; i < 2; i++){
    int id = tid * 2 + i;
    int m = id >> 3, kc = id & 7;
    *(bf16x8*)(wl + m * 64 + ((kc ^ (m & 7)) << 3)) = *(const bf16x8*)(omT + id * 8);
  }
  __syncthreads();
  {
    int r = tid & 127, half = tid >> 7;
    float s = 0.f;
#pragma unroll
    for (int j = 0; j < 4; j++){
      int kc = half * 4 + j;
      bf16x8 v = *(const bf16x8*)(qs + r * 64 + ((kc ^ (r & 7)) << 3));
#pragma unroll
      for (int e = 0; e < 8; e++){ float f = b2f((u16)v[e]); s += f * f; }
    }
    part[half][r] = s;
  }
  __syncthreads();
  if (tid < 128) nrm[tid] = 0.0625f * (part[0][tid] + part[1][tid]);
  __syncthreads();
  f32x4 acc[2][4] = {};
#pragma unroll
  for (int kt = 0; kt < 2; kt++){
    int kc = kt * 4 + (lane >> 4);
    bf16x8 fa[2], fb[4];
#pragma unroll
    for (int mt = 0; mt < 2; mt++){
      int r = w * 32 + mt * 16 + (lane & 15);
      fa[mt] = *(const bf16x8*)(qs + r * 64 + ((kc ^ (r & 7)) << 3));
    }
#pragma unroll
    for (int nt = 0; nt < 4; nt++){
      int m = nt * 16 + (lane & 15);
      fb[nt] = *(const bf16x8*)(wl + m * 64 + ((kc ^ (m & 7)) << 3));
    }
#pragma unroll
    for (int mt = 0; mt < 2; mt++)
#pragma unroll
      for (int nt = 0; nt < 4; nt++)
        acc[mt][nt] = __builtin_amdgcn_mfma_f32_16x16x32_bf16(fa[mt], fb[nt], acc[mt][nt], 0, 0, 0);
  }
  const float LNC = -2.4260151319598086f;   // ln(128^-0.5)
#pragma unroll
  for (int mt = 0; mt < 2; mt++)
#pragma unroll
    for (int nt = 0; nt < 4; nt++)
#pragma unroll
      for (int r4 = 0; r4 < 4; r4++){
        int r = w * 32 + mt * 16 + ((lane >> 4) << 2) + r4;
        int m = nt * 16 + (lane & 15);
        float u = acc[mt][nt][r4];
        float nr = nrm[r];
        ph[r * 128 + m]      = f2b(__expf(u - nr + LNC));
        ph[r * 128 + 64 + m] = f2b(__expf(-u - nr + LNC));
      }
  __syncthreads();
  u16* go = dst + (size_t)row0 * 128;
#pragma unroll
  for (int i = 0; i < 8; i++){
    int id = i * 256 + tid;
    *(bf16x8*)(go + id * 8) = *(const bf16x8*)(ph + id * 8);
  }
}

// ---------------- per-chunk kv^T[d][m] (bf16), ksum [128m] f32 ----------------
__global__ __launch_bounds__(256) void kvchunk(const u16* __restrict__ Kp, const u16* __restrict__ vt,
                                               u16* __restrict__ kv, float* __restrict__ ksum){
  __shared__ __align__(16) u16 Ks[128 * 128];
  __shared__ __align__(16) u16 Vst[64 * 128];
  int blk = blockIdx.x; int bh = blk >> 4, c = blk & 15;
  int tid = threadIdx.x;
  size_t base = (size_t)bh * 2048 + c * 128;
  const u16* Kc = Kp + base * 128;
  const u16* vtc = vt + (size_t)bh * 64 * 2048 + c * 128;
  {
    int j = tid >> 1, half = tid & 1;
#pragma unroll
    for (int i = 0; i < 8; i++)
      *(bf16x8*)(Ks + j * 128 + half * 64 + i * 8) = *(const bf16x8*)(Kc + j * 128 + half * 64 + i * 8);
#pragma unroll
    for (int i = 0; i < 4; i++){
      int id = tid * 4 + i;
      int d = id >> 4, mc = id & 15;
      *(bf16x8*)(Vst + d * 128 + mc * 8) = *(const bf16x8*)(vtc + (size_t)d * 2048 + mc * 8);
    }
  }
  __syncthreads();
  int tm = tid & 15, td = tid >> 4;
  int mbase = tm * 8, dbase = td * 4;
  float acc[8][4] = {};
  float ks[8] = {};
  for (int i = 0; i < 128; i++){
    bf16x8 kk = *(const bf16x8*)(Ks + i * 128 + mbase);
    float kf[8];
#pragma unroll
    for (int e = 0; e < 8; e++) kf[e] = b2f((u16)kk[e]);
    float vf[4];
#pragma unroll
    for (int e = 0; e < 4; e++) vf[e] = b2f(Vst[(dbase + e) * 128 + i]);
#pragma unroll
    for (int a = 0; a < 8; a++){
      ks[a] += kf[a];
#pragma unroll
      for (int bb = 0; bb < 4; bb++) acc[a][bb] += kf[a] * vf[bb];
    }
  }
  u16* kvout = kv + ((size_t)bh * 16 + c) * 8192;
#pragma unroll
  for (int a = 0; a < 8; a++)
#pragma unroll
    for (int bb = 0; bb < 4; bb++)
      kvout[(size_t)(dbase + bb) * 128 + mbase + a] = f2b(acc[a][bb]);
  if (td == 0){
    float* kso = ksum + ((size_t)bh * 16 + c) * 128;
#pragma unroll
    for (int a = 0; a < 8; a++) kso[mbase + a] = ks[a];
  }
}

// ---------------- exclusive prefix over chunks (in place; kv bf16, f32 carry) ----------------
__global__ __launch_bounds__(256) void kvscan(u16* __restrict__ kv, float* __restrict__ ksum){
  int bh = blockIdx.x;
  int p = blockIdx.y;
  int tid = threadIdx.x;
  if (p < 8){
    size_t base = (size_t)bh * 16 * 8192;
    int idx0 = p * 1024 + tid;
    for (int rep = 0; rep < 4; rep++){
      int idx = idx0 + rep * 256;
      float run = 0.f;
#pragma unroll
      for (int c = 0; c < 16; c++){
        size_t off = base + (size_t)c * 8192 + idx;
        float v = b2f(kv[off]); kv[off] = f2b(run); run += v;
      }
    }
  } else if (tid < 128){
    size_t base = (size_t)bh * 16 * 128;
    float run = 0.f;
#pragma unroll
    for (int c = 0; c < 16; c++){
      size_t off = base + c * 128 + tid;
      float v = ksum[off]; ksum[off] = run; run += v;
    }
  }
}

// ---------------- MFMA fused attention (kv_pre bf16) ----------------
__global__ __launch_bounds__(512) void attn_fused(const u16* __restrict__ Qp, const u16* __restrict__ Kp,
                                                  const u16* __restrict__ vt, const u16* __restrict__ kvp,
                                                  const float* __restrict__ ksum, u16* __restrict__ aout){
  __shared__ __align__(16) u16 sm[53248];
  int blk = blockIdx.x, bh = blk >> 4, c = blk & 15;
  int b = bh >> 4, h = bh & 15;
  int tid = threadIdx.x, w = tid >> 6, lane = tid & 63;
  size_t base = (size_t)bh * 2048 + c * 128;
  const u16* Qc = Qp + base * 128;
  const u16* Kc = Kp + base * 128;
  const u16* vtc = vt + (size_t)bh * 64 * 2048 + c * 128;
  const u16* kvc = kvp + ((size_t)bh * 16 + c) * 8192;
  const float* ksc = ksum + ((size_t)bh * 16 + c) * 128;
  u16* Qs = sm;
  u16* Ks = sm + 16384;
  u16* B2 = sm + 32768;

#pragma unroll
  for (int i = 0; i < 4; i++){
    int id = tid * 4 + i;
    int r = id >> 4, kc = id & 15;
    int swo = (kc ^ (r & 15)) << 3;
    *(bf16x8*)(Qs + r * 128 + swo) = *(const bf16x8*)(Qc + (size_t)r * 128 + kc * 8);
    *(bf16x8*)(Ks + r * 128 + swo) = *(const bf16x8*)(Kc + (size_t)r * 128 + kc * 8);
  }
#pragma unroll
  for (int i = 0; i < 2; i++){
    int id = tid * 2 + i;
    int d = id >> 4, kc = id & 15;
    *(bf16x8*)(B2 + d * 256 + ((kc ^ (d & 31)) << 3)) = *(const bf16x8*)(vtc + (size_t)d * 2048 + kc * 8);
  }
#pragma unroll
  for (int i = 0; i < 2; i++){
    int id = tid * 2 + i;
    int d = id >> 4, mc = id & 15;
    bf16x8 pk = *(const bf16x8*)(kvc + d * 128 + mc * 8);
    int kc = 16 + mc;
    *(bf16x8*)(B2 + d * 256 + ((kc ^ (d & 31)) << 3)) = pk;
  }
  {
    int row = 64 + (tid >> 5), kc = tid & 31;
    bf16x8 pk = {};
    if (row == 64){
      if (kc < 16){
#pragma unroll
        for (int e = 0; e < 8; e++) pk[e] = (short)0x3F80;
      } else {
        const float* s8 = ksc + (kc - 16) * 8;
        float4 f0 = *(const float4*)(s8);
        float4 f1 = *(const float4*)(s8 + 4);
        pk[0] = (short)f2b(f0.x); pk[1] = (short)f2b(f0.y); pk[2] = (short)f2b(f0.z); pk[3] = (short)f2b(f0.w);
        pk[4] = (short)f2b(f1.x); pk[5] = (short)f2b(f1.y); pk[6] = (short)f2b(f1.z); pk[7] = (short)f2b(f1.w);
      }
    }
    *(bf16x8*)(B2 + row * 256 + ((kc ^ (row & 31)) << 3)) = pk;
  }
  __syncthreads();

  int wm = w >> 2, wn = w & 3;
  f32x4 acc1[4][2] = {};
#pragma unroll
  for (int kk = 0; kk < 4; kk++){
    int kc = kk * 4 + (lane >> 4);
    bf16x8 fa[4], fb[2];
#pragma unroll
    for (int m = 0; m < 4; m++){
      int row = wm * 64 + m * 16 + (lane & 15);
      fa[m] = *(const bf16x8*)(Qs + row * 128 + ((kc ^ (row & 15)) << 3));
    }
#pragma unroll
    for (int n = 0; n < 2; n++){
      int row = wn * 32 + n * 16 + (lane & 15);
      fb[n] = *(const bf16x8*)(Ks + row * 128 + ((kc ^ (row & 15)) << 3));
    }
#pragma unroll
    for (int m = 0; m < 4; m++)
#pragma unroll
      for (int n = 0; n < 2; n++)
        acc1[m][n] = __builtin_amdgcn_mfma_f32_16x16x32_bf16(fa[m], fb[n], acc1[m][n], 0, 0, 0);
  }
  __syncthreads();

#pragma unroll
  for (int m = 0; m < 4; m++)
#pragma unroll
    for (int n = 0; n < 2; n++)
#pragma unroll
      for (int r = 0; r < 4; r++){
        int i = wm * 64 + m * 16 + ((lane >> 4) << 2) + r;
        int j = wn * 32 + n * 16 + (lane & 15);
        float v = (j <= i) ? acc1[m][n][r] : 0.f;
        Ks[i * 128 + (((j >> 3) ^ (i & 15)) << 3) + (j & 7)] = f2b(v);
      }
  __syncthreads();

  f32x4 acc2[5] = {};
#pragma unroll
  for (int kk = 0; kk < 8; kk++){
    int kc = kk * 4 + (lane >> 4);
    int rowA = w * 16 + (lane & 15);
    bf16x8 fa2;
    if (kk < 4) fa2 = *(const bf16x8*)(Ks + rowA * 128 + ((kc ^ (rowA & 15)) << 3));
    else        fa2 = *(const bf16x8*)(Qs + rowA * 128 + (((kc - 16) ^ (rowA & 15)) << 3));
#pragma unroll
    for (int n = 0; n < 5; n++){
      int d = n * 16 + (lane & 15);
      bf16x8 fb2 = *(const bf16x8*)(B2 + d * 256 + ((kc ^ (d & 31)) << 3));
      acc2[n] = __builtin_amdgcn_mfma_f32_16x16x32_bf16(fa2, fb2, acc2[n], 0, 0, 0);
    }
  }

  float dd[4];
#pragma unroll
  for (int r = 0; r < 4; r++) dd[r] = __shfl(acc2[4][r], lane & 48) + 1e-6f;
  size_t obase = ((size_t)b * 2048 + c * 128) * 1024 + (size_t)h * 64;
#pragma unroll
  for (int n = 0; n < 4; n++)
#pragma unroll
    for (int r = 0; r < 4; r++){
      int i = w * 16 + ((lane >> 4) << 2) + r;
      int d = n * 16 + (lane & 15);
      aout[obase + (size_t)i * 1024 + d] = f2b(acc2[n][r] / dd[r]);
    }
}

// ---------------- universal residual-add + LayerNorm ----------------
__global__ __launch_bounds__(256) void lnr(const float* X1f, const u16* X1b,
                                           const u16* P0, const u16* P1,
                                           const float* __restrict__ g, const float* __restrict__ bb,
                                           float* outf, u16* outb, u16* outb2){
  __shared__ float red[2][4];
  int row = blockIdx.x, tid = threadIdx.x, w = tid >> 6, lane = tid & 63;
  size_t ro = (size_t)row * 1024 + tid * 4;
  float x0, x1, x2, x3;
  if (X1f){
    float4 a = *(const float4*)(X1f + ro);
    x0 = a.x; x1 = a.y; x2 = a.z; x3 = a.w;
  } else {
    ushort4 a = *(const ushort4*)(X1b + ro);
    x0 = b2f(a.x); x1 = b2f(a.y); x2 = b2f(a.z); x3 = b2f(a.w);
  }
  {
    ushort4 p0 = *(const ushort4*)(P0 + ro);
    x0 += b2f(p0.x); x1 += b2f(p0.y); x2 += b2f(p0.z); x3 += b2f(p0.w);
  }
  if (P1){
    ushort4 p1 = *(const ushort4*)(P1 + ro);
    x0 += b2f(p1.x); x1 += b2f(p1.y); x2 += b2f(p1.z); x3 += b2f(p1.w);
  }
  float s1 = x0 + x1 + x2 + x3;
  float s2 = x0 * x0 + x1 * x1 + x2 * x2 + x3 * x3;
#pragma unroll
  for (int off = 32; off; off >>= 1){ s1 += __shfl_xor(s1, off); s2 += __shfl_xor(s2, off); }
  if (lane == 0){ red[0][w] = s1; red[1][w] = s2; }
  __syncthreads();
  float t1 = red[0][0] + red[0][1] + red[0][2] + red[0][3];
  float t2 = red[1][0] + red[1][1] + red[1][2] + red[1][3];
  float mu = t1 * (1.f / 1024.f);
  float var = t2 * (1.f / 1024.f) - mu * mu;
  float rs = rsqrtf(var + 1e-5f);
  float4 gv = *(const float4*)(g + tid * 4);
  float4 bv = *(const float4*)(bb + tid * 4);
  float o0 = (x0 - mu) * rs * gv.x + bv.x;
  float o1 = (x1 - mu) * rs * gv.y + bv.y;
  float o2 = (x2 - mu) * rs * gv.z + bv.z;
  float o3 = (x3 - mu) * rs * gv.w + bv.w;
  if (outf) *(float4*)(outf + ro) = make_float4(o0, o1, o2, o3);
  ushort4 ob = make_ushort4(f2b(o0), f2b(o1), f2b(o2), f2b(o3));
  if (outb)  *(ushort4*)(outb + ro)  = ob;
  if (outb2) *(ushort4*)(outb2 + ro) = ob;
}

// ---------------- host ----------------
extern "C" void kernel_launch(void* const* d_in, const int* in_sizes, int n_in,
                              void* d_out, int out_size, void* d_ws, size_t ws_size,
                              hipStream_t stream){
  (void)in_sizes; (void)n_in;
  const float* x   = (const float*)d_in[0];
  const float* Wq  = (const float*)d_in[1];
  const float* bq  = (const float*)d_in[2];
  const float* Wk  = (const float*)d_in[3];
  const float* bk  = (const float*)d_in[4];
  const float* Wv  = (const float*)d_in[5];
  const float* bv  = (const float*)d_in[6];
  const float* Wo  = (const float*)d_in[7];
  const float* bo  = (const float*)d_in[8];
  const float* om  = (const float*)d_in[9];
  const float* g1  = (const float*)d_in[10];
  const float* be1 = (const float*)d_in[11];
  const float* W1  = (const float*)d_in[12];
  const float* bf1 = (const float*)d_in[13];
  const float* W2  = (const float*)d_in[14];
  const float* bf2 = (const float*)d_in[15];
  const float* g2  = (const float*)d_in[16];
  const float* be2 = (const float*)d_in[17];

  char* ws = (char*)d_ws;
  size_t off = 0;
  auto alloc = [&](size_t bytes) -> void* {
    void* p = ws + off; off += (bytes + 255) & ~(size_t)255; return p;
  };
  u16* Wcat = (u16*)alloc(3072ull * 1024 * 2);
  u16* Wot  = (u16*)alloc(1024ull * 1024 * 2);
  u16* W1t  = (u16*)alloc(4096ull * 1024 * 2);
  u16* W2t  = (u16*)alloc(1024ull * 4096 * 2);
  u16* omT  = (u16*)alloc(64ull * 64 * 2);
  float* bcat = (float*)alloc(6ull * 3072 * 4);
  float* zbuf = (float*)alloc(1024 * 4);
  u16* Xb  = (u16*)alloc(8192ull * 1024 * 2);
  u16* qb  = (u16*)alloc(131072ull * 64 * 2);   // contiguous qb|kb|vt|Qp for ybuf alias
  u16* kb  = (u16*)alloc(131072ull * 64 * 2);
  u16* vt  = (u16*)alloc(131072ull * 64 * 2);
  u16* Qp  = (u16*)alloc(131072ull * 128 * 2);
  u16* Kp  = (u16*)alloc(131072ull * 128 * 2);
  float* ksum = (float*)alloc(64ull * 16 * 128 * 4);

  if (off > ws_size){
    fillv<<<(out_size + 255) / 256, 256, 0, stream>>>((float*)d_out, (float)(ws_size >> 20), out_size);
    return;
  }

  u16*  kvbuf  = qb;                    // kv^T bf16 16MB in qb (dead after phi2)
  u16*  ybuf   = qb;                    // FFN intermediate bf16 [8192][4096] over qb..Qp[0:16MB]
  u16*  wooutb = Qp;                    // Wo out bf16 16MB (Qp dead after attn)
  u16*  w2outb = Qp + 8388608;          // W2 partial kz=0, bf16 16MB
  u16*  w2p1   = Kp + 8388608;          // W2 partial kz=1, bf16 16MB (Kp[16:32], dead after attn)
  u16*  residb = (u16*)d_out;           // bf16 residual stream in d_out[0:16MB]; final layer writes f32

  cvt16<<<8192, 256, 0, stream>>>(x, Xb);
  catbias<<<72, 256, 0, stream>>>(bq, bk, bv, bcat);
  fillv<<<4, 256, 0, stream>>>(zbuf, 0.f, 1024);

  for (int l = 0; l < 6; l++){
    size_t o1k = (size_t)l * 1024 * 1024;
    size_t o4k = (size_t)l * 4096 * 1024;
    wtrans7<<<12292, 256, 0, stream>>>(Wq + o1k, Wk + o1k, Wv + o1k, Wo + o1k,
                                       W1 + o4k, W2 + o4k, om + (size_t)l * 4096,
                                       Wcat, Wot, W1t, W2t, omT);

    gemm_bt<5><<<dim3(24, 64), 256, 0, stream>>>(Xb, Wcat, bcat + l * 3072, qb, 8192, 3072, 1024, 1024, 1024);
    phi2<<<2048, 256, 0, stream>>>(qb, kb, omT, Qp, Kp);
    kvchunk<<<1024, 256, 0, stream>>>(Kp, vt, kvbuf, ksum);
    kvscan<<<dim3(64, 9), 256, 0, stream>>>(kvbuf, ksum);
    attn_fused<<<1024, 512, 0, stream>>>(Qp, Kp, vt, kvbuf, ksum, Xb);
    gemm_bt<6><<<dim3(8, 64), 256, 0, stream>>>(Xb, Wot, bo + l * 1024, wooutb, 8192, 1024, 1024, 1024, 1024);
    lnr<<<8192, 256, 0, stream>>>(l == 0 ? x : nullptr, l == 0 ? nullptr : residb,
                                  wooutb, nullptr, g1 + l * 1024, be1 + l * 1024,
                                  nullptr, Xb, nullptr);
    gemm8p<2><<<dim3(16, 32), 512, 0, stream>>>(Xb, W1t, bf1 + l * 4096, ybuf, 8192, 4096, 1024, 1024, 1024);
    gemm8pk<<<dim3(256), 512, 0, stream>>>(ybuf, W2t, bf2 + l * 1024, zbuf, w2outb, w2p1,
                                           8192, 1024, 2048, 4096, 4096);
    if (l == 5)
      lnr<<<8192, 256, 0, stream>>>(nullptr, Xb, w2outb, w2p1, g2 + l * 1024, be2 + l * 1024,
                                    (float*)d_out, nullptr, nullptr);
    else
      lnr<<<8192, 256, 0, stream>>>(nullptr, Xb, w2outb, w2p1, g2 + l * 1024, be2 + l * 1024,
                                    nullptr, Xb, residb);
  }
}

// Round 18
// 2378.699 us; speedup vs baseline: 1.0925x; 1.0137x over previous
//
#include <hip/hip_runtime.h>

typedef unsigned short u16;
typedef __attribute__((ext_vector_type(8))) short bf16x8;
typedef __attribute__((ext_vector_type(4))) float f32x4;

#define DEV __device__ __forceinline__

DEV float b2f(u16 h){ return __uint_as_float(((unsigned)h) << 16); }
DEV u16 f2b(float f){ unsigned u = __float_as_uint(f); u += 0x7FFFu + ((u >> 16) & 1u); return (u16)(u >> 16); }

DEV void gload16(const u16* g, u16* l){
  __builtin_amdgcn_global_load_lds((const __attribute__((address_space(1))) unsigned*)g,
                                   (__attribute__((address_space(3))) unsigned*)l, 16, 0, 0);
}

// ---------------- merged per-layer weight transpose: 7 tensors in one launch ----------------
__global__ __launch_bounds__(256) void wtrans7(const float* __restrict__ Wq, const float* __restrict__ Wk,
                                               const float* __restrict__ Wv, const float* __restrict__ Wo,
                                               const float* __restrict__ W1, const float* __restrict__ W2,
                                               const float* __restrict__ om,
                                               u16* __restrict__ Wcat, u16* __restrict__ Wot,
                                               u16* __restrict__ W1t, u16* __restrict__ W2t,
                                               u16* __restrict__ omT){
  __shared__ float tile[32][33];
  int id = blockIdx.x;
  const float* src; u16* dst; int K, N, kb, nb; float scale = 1.f;
  if (id < 4096){
    int wsel = id >> 10, loc = id & 1023;
    kb = loc >> 5; nb = loc & 31; K = 1024; N = 1024;
    src = (wsel == 0) ? Wq : (wsel == 1) ? Wk : (wsel == 2) ? Wv : Wo;
    dst = (wsel < 3) ? Wcat + (size_t)wsel * 1048576 : Wot;
  } else if (id < 8192){
    int loc = id - 4096;
    kb = loc & 31; nb = loc >> 5; K = 1024; N = 4096;
    src = W1; dst = W1t;
  } else if (id < 12288){
    int loc = id - 8192;
    kb = loc & 127; nb = loc >> 7; K = 4096; N = 1024;
    src = W2; dst = W2t;
  } else {
    int loc = id - 12288;
    kb = loc & 1; nb = loc >> 1; K = 64; N = 64;
    src = om; dst = omT; scale = 0.35355339059327373f;
  }
  int k0 = kb * 32, n0 = nb * 32;
  int tid = threadIdx.x;
#pragma unroll
  for (int i = 0; i < 4; i++){
    int idx = tid + i * 256;
    int r = idx >> 5, c = idx & 31;
    tile[r][c] = src[(size_t)(k0 + r) * N + n0 + c];
  }
  __syncthreads();
#pragma unroll
  for (int i = 0; i < 4; i++){
    int idx = tid + i * 256;
    int r = idx >> 5, c = idx & 31;
    dst[(size_t)(n0 + r) * K + k0 + c] = f2b(tile[c][r] * scale);
  }
}

// ---------------- f32 -> bf16 convert ----------------
__global__ __launch_bounds__(256) void cvt16(const float* __restrict__ src, u16* __restrict__ dst){
  size_t i = ((size_t)blockIdx.x * 256 + threadIdx.x) * 4;
  float4 f = *(const float4*)(src + i);
  ushort4 o = make_ushort4(f2b(f.x), f2b(f.y), f2b(f.z), f2b(f.w));
  *(ushort4*)(dst + i) = o;
}

// ---------------- bias concat (all layers): [6][3072] = bq|bk|bv ----------------
__global__ void catbias(const float* __restrict__ bq, const float* __restrict__ bk,
                        const float* __restrict__ bv, float* __restrict__ bcat){
  int i = blockIdx.x * 256 + threadIdx.x;
  if (i >= 6 * 3072) return;
  int l = i / 3072, j = i % 3072;
  float v = (j < 1024) ? bq[l * 1024 + j] : (j < 2048) ? bk[l * 1024 + j - 1024] : bv[l * 1024 + j - 2048];
  bcat[i] = v;
}

// ---------------- diagnostic / zero fill ----------------
__global__ void fillv(float* __restrict__ p, float v, int n){
  int i = blockIdx.x * 256 + threadIdx.x;
  if (i < n) p[i] = v;
}

// ---------------- 128^2 bf16 MFMA GEMM (gload_lds dbuf + counted vmcnt + XCD swizzle) ----------------
// EPI 2: relu bf16 [M,N] ; EPI 5: fused QKV ; EPI 6: bf16 [M,N]
DEV int swz(int r){ return (r & 3) ^ ((r >> 2) & 3); }

template<int EPI>
__global__ __launch_bounds__(256) void gemm_bt(const u16* __restrict__ A, const u16* __restrict__ Bt,
                                               const float* __restrict__ bias, void* __restrict__ outp,
                                               int M, int N, int K, int ldA, int ldB){
  __shared__ __align__(16) u16 As[2][4096];
  __shared__ __align__(16) u16 Bs[2][4096];
  const int tid = threadIdx.x;
  const int lane = tid & 63;
  const int w = tid >> 6;
  const int wm = w >> 1, wn = w & 1;
  int nx = gridDim.x;
  int nwg = nx * gridDim.y;
  int lin = blockIdx.y * nx + blockIdx.x;
  int cpx = nwg >> 3;
  int sw = (lin & 7) * cpx + (lin >> 3);
  const int m0 = (sw / nx) * 128;
  const int n0 = (sw % nx) * 128;

  int r0 = tid >> 2, c0 = tid & 3;
  int r1 = r0 + 64;
  int cs0 = c0 ^ swz(r0);
  int cs1 = c0 ^ swz(r1);
  const u16* ag0 = A + (size_t)(m0 + r0) * ldA + cs0 * 8;
  const u16* ag1 = A + (size_t)(m0 + r1) * ldA + cs1 * 8;
  const u16* bg0 = Bt + (size_t)(n0 + r0) * ldB + cs0 * 8;
  const u16* bg1 = Bt + (size_t)(n0 + r1) * ldB + cs1 * 8;

  f32x4 acc[4][4] = {};
  const int KT = K >> 5;

  gload16(ag0, &As[0][w * 512]);
  gload16(ag1, &As[0][2048 + w * 512]);
  gload16(bg0, &Bs[0][w * 512]);
  gload16(bg1, &Bs[0][2048 + w * 512]);

  for (int kt = 0; kt < KT; kt++){
    int cur = kt & 1;
    if (kt + 1 < KT){
      int ko = (kt + 1) << 5;
      gload16(ag0 + ko, &As[cur ^ 1][w * 512]);
      gload16(ag1 + ko, &As[cur ^ 1][2048 + w * 512]);
      gload16(bg0 + ko, &Bs[cur ^ 1][w * 512]);
      gload16(bg1 + ko, &Bs[cur ^ 1][2048 + w * 512]);
      asm volatile("s_waitcnt vmcnt(4)" ::: "memory");
    } else {
      asm volatile("s_waitcnt vmcnt(0)" ::: "memory");
    }
    __builtin_amdgcn_s_barrier();
    bf16x8 fa[4], fb[4];
#pragma unroll
    for (int m = 0; m < 4; m++){
      int row = wm * 64 + m * 16 + (lane & 15);
      int cc = (lane >> 4) ^ swz(row);
      fa[m] = *(const bf16x8*)(&As[cur][row * 32 + cc * 8]);
    }
#pragma unroll
    for (int n = 0; n < 4; n++){
      int row = wn * 64 + n * 16 + (lane & 15);
      int cc = (lane >> 4) ^ swz(row);
      fb[n] = *(const bf16x8*)(&Bs[cur][row * 32 + cc * 8]);
    }
#pragma unroll
    for (int m = 0; m < 4; m++)
#pragma unroll
      for (int n = 0; n < 4; n++)
        acc[m][n] = __builtin_amdgcn_mfma_f32_16x16x32_bf16(fa[m], fb[n], acc[m][n], 0, 0, 0);
    asm volatile("s_waitcnt lgkmcnt(0)" ::: "memory");
    __builtin_amdgcn_s_barrier();
  }

#pragma unroll
  for (int m = 0; m < 4; m++){
    int rowb = m0 + wm * 64 + m * 16 + ((lane >> 4) << 2);
#pragma unroll
    for (int n = 0; n < 4; n++){
      int col = n0 + wn * 64 + n * 16 + (lane & 15);
      float bv = bias[col];
      if (EPI == 5 && col >= 2048){
        int cv = col - 2048, hh = cv >> 6, dh = cv & 63;
        int bIdx = rowb >> 11, s4 = rowb & 2047;
        ushort4 pk = make_ushort4(f2b(acc[m][n][0] + bv), f2b(acc[m][n][1] + bv),
                                  f2b(acc[m][n][2] + bv), f2b(acc[m][n][3] + bv));
        *(ushort4*)&((u16*)outp + 16777216)[((size_t)(bIdx * 16 + hh) * 64 + dh) * 2048 + s4] = pk;
      } else {
#pragma unroll
        for (int r = 0; r < 4; r++){
          float v = acc[m][n][r] + bv;
          int rr = rowb + r;
          if (EPI == 5){
            u16* dst0 = (u16*)outp + (col < 1024 ? 0 : 8388608);
            int cv = col & 1023, hh = cv >> 6, dh = cv & 63;
            int bIdx = rr >> 11, s = rr & 2047;
            dst0[(((size_t)(bIdx * 16 + hh) * 2048 + s) << 6) + dh] = f2b(v);
          } else if (EPI == 2){
            ((u16*)outp)[(size_t)rr * N + col] = f2b(v > 0.f ? v : 0.f);
          } else {
            ((u16*)outp)[(size_t)rr * N + col] = f2b(v);
          }
        }
      }
    }
  }
}

// ---------------- 8-phase 256^2 GEMM (m201 template): BK=64, K-half subtiles, counted vmcnt ----------------
// EPI 2: relu bf16 ; EPI 6: bf16   (scalar epilogue)
template<int EPI>
__global__ __launch_bounds__(512, 1) void gemm8p(const u16* __restrict__ A, const u16* __restrict__ Bt,
                                                 const float* __restrict__ bias, void* __restrict__ outp,
                                                 int M, int N, int K, int ldA, int ldB){
  __shared__ __align__(16) u16 As[2][16384];
  __shared__ __align__(16) u16 Bs[2][16384];
  const int tid = threadIdx.x;
  const int lane = tid & 63;
  const int w = tid >> 6;
  const int wm = w >> 2, wn = w & 3;
  int nx = gridDim.x;
  int nwg = nx * gridDim.y;
  int lin = blockIdx.y * nx + blockIdx.x;
  int cpx = nwg >> 3;
  int sw = (lin & 7) * cpx + (lin >> 3);
  const int m0 = (sw / nx) * 256;
  const int n0 = (sw % nx) * 256;

  const int id1 = 512 + tid;
  const int r0 = tid >> 2, c20 = tid & 3;
  const int r1 = id1 >> 2, c21 = id1 & 3;
  const int cs0 = c20 ^ ((r0 >> 1) & 3);
  const int cs1 = c21 ^ ((r1 >> 1) & 3);
  const u16* Ag0 = A + (size_t)(m0 + r0) * ldA + cs0 * 8;
  const u16* Ag1 = A + (size_t)(m0 + r1) * ldA + cs1 * 8;
  const u16* Bg0 = Bt + (size_t)(n0 + r0) * ldB + cs0 * 8;
  const u16* Bg1 = Bt + (size_t)(n0 + r1) * ldB + cs1 * 8;

  f32x4 acc[8][4] = {};
  const int KT = K >> 6;

  auto stA = [&](int buf, int kt, int ks){
    int kc = kt * 64 + ks * 32;
    gload16(Ag0 + kc, &As[buf][ks * 8192 + w * 512]);
    gload16(Ag1 + kc, &As[buf][ks * 8192 + 4096 + w * 512]);
  };
  auto stB = [&](int buf, int kt, int ks){
    int kc = kt * 64 + ks * 32;
    gload16(Bg0 + kc, &Bs[buf][ks * 8192 + w * 512]);
    gload16(Bg1 + kc, &Bs[buf][ks * 8192 + 4096 + w * 512]);
  };

  stA(0, 0, 0); stB(0, 0, 0); stA(0, 0, 1); stB(0, 0, 1);

  for (int t = 0; t < KT; t++){
    int c = t & 1, nb = c ^ 1;
    bool pf = (t + 1 < KT);
    asm volatile("s_waitcnt vmcnt(4)" ::: "memory");
    __builtin_amdgcn_s_barrier();

#pragma unroll
    for (int ks = 0; ks < 2; ks++){
      if (ks == 1){
        if (pf) asm volatile("s_waitcnt vmcnt(4)" ::: "memory");
        else    asm volatile("s_waitcnt vmcnt(0)" ::: "memory");
        __builtin_amdgcn_s_barrier();
      }
      if (pf){ if (ks == 0) stA(nb, t + 1, 0); else stA(nb, t + 1, 1); }
      bf16x8 fa[8], fb[2];
#pragma unroll
      for (int m = 0; m < 8; m++){
        int row = wm * 128 + m * 16 + (lane & 15);
        int slot = (lane >> 4) ^ ((row >> 1) & 3);
        fa[m] = *(const bf16x8*)(&As[c][ks * 8192 + row * 32 + slot * 8]);
      }
#pragma unroll
      for (int nn = 0; nn < 2; nn++){
        int row = wn * 64 + nn * 16 + (lane & 15);
        int slot = (lane >> 4) ^ ((row >> 1) & 3);
        fb[nn] = *(const bf16x8*)(&Bs[c][ks * 8192 + row * 32 + slot * 8]);
      }
      __builtin_amdgcn_s_setprio(1);
#pragma unroll
      for (int m = 0; m < 8; m++)
#pragma unroll
        for (int nn = 0; nn < 2; nn++)
          acc[m][nn] = __builtin_amdgcn_mfma_f32_16x16x32_bf16(fa[m], fb[nn], acc[m][nn], 0, 0, 0);
      __builtin_amdgcn_s_setprio(0);
      if (pf){ if (ks == 0) stB(nb, t + 1, 0); else stB(nb, t + 1, 1); }
#pragma unroll
      for (int nn = 0; nn < 2; nn++){
        int row = wn * 64 + 32 + nn * 16 + (lane & 15);
        int slot = (lane >> 4) ^ ((row >> 1) & 3);
        fb[nn] = *(const bf16x8*)(&Bs[c][ks * 8192 + row * 32 + slot * 8]);
      }
      __builtin_amdgcn_s_setprio(1);
#pragma unroll
      for (int m = 0; m < 8; m++)
#pragma unroll
        for (int nn = 0; nn < 2; nn++)
          acc[m][2 + nn] = __builtin_amdgcn_mfma_f32_16x16x32_bf16(fa[m], fb[nn], acc[m][2 + nn], 0, 0, 0);
      __builtin_amdgcn_s_setprio(0);
    }
  }

#pragma unroll
  for (int m = 0; m < 8; m++){
    int rowb = m0 + wm * 128 + m * 16 + ((lane >> 4) << 2);
#pragma unroll
    for (int n = 0; n < 4; n++){
      int col = n0 + wn * 64 + n * 16 + (lane & 15);
      float bv = bias[col];
#pragma unroll
      for (int r = 0; r < 4; r++){
        float v = acc[m][n][r] + bv;
        int rr = rowb + r;
        if (EPI == 2) ((u16*)outp)[(size_t)rr * N + col] = f2b(v > 0.f ? v : 0.f);
        else          ((u16*)outp)[(size_t)rr * N + col] = f2b(v);
      }
    }
  }
}

// ---------------- 8-phase 256^2 split-K GEMM: 256 blocks = (4 n)x(32 m)x(2 kz), bf16 partials ----------------
__global__ __launch_bounds__(512, 1) void gemm8pk(const u16* __restrict__ A, const u16* __restrict__ Bt,
                                                  const float* __restrict__ bias0, const float* __restrict__ bias1,
                                                  u16* __restrict__ out0, u16* __restrict__ out1,
                                                  int M, int N, int Khalf, int ldA, int ldB){
  __shared__ __align__(16) u16 As[2][16384];
  __shared__ __align__(16) u16 Bs[2][16384];
  const int tid = threadIdx.x;
  const int lane = tid & 63;
  const int w = tid >> 6;
  const int wm = w >> 2, wn = w & 3;
  int lin = blockIdx.x;               // 256 blocks
  int cpx = gridDim.x >> 3;
  int sw = (lin & 7) * cpx + (lin >> 3);
  const int kz = sw & 1;
  const int t2 = sw >> 1;
  const int n0 = (t2 & 3) * 256;
  const int m0 = (t2 >> 2) * 256;
  const u16* Ab = A + kz * Khalf;
  const u16* Bb = Bt + kz * Khalf;
  u16* outp = kz ? out1 : out0;
  const float* bias = kz ? bias1 : bias0;

  const int id1 = 512 + tid;
  const int r0 = tid >> 2, c20 = tid & 3;
  const int r1 = id1 >> 2, c21 = id1 & 3;
  const int cs0 = c20 ^ ((r0 >> 1) & 3);
  const int cs1 = c21 ^ ((r1 >> 1) & 3);
  const u16* Ag0 = Ab + (size_t)(m0 + r0) * ldA + cs0 * 8;
  const u16* Ag1 = Ab + (size_t)(m0 + r1) * ldA + cs1 * 8;
  const u16* Bg0 = Bb + (size_t)(n0 + r0) * ldB + cs0 * 8;
  const u16* Bg1 = Bb + (size_t)(n0 + r1) * ldB + cs1 * 8;

  f32x4 acc[8][4] = {};
  const int KT = Khalf >> 6;

  auto stA = [&](int buf, int kt, int ks){
    int kc = kt * 64 + ks * 32;
    gload16(Ag0 + kc, &As[buf][ks * 8192 + w * 512]);
    gload16(Ag1 + kc, &As[buf][ks * 8192 + 4096 + w * 512]);
  };
  auto stB = [&](int buf, int kt, int ks){
    int kc = kt * 64 + ks * 32;
    gload16(Bg0 + kc, &Bs[buf][ks * 8192 + w * 512]);
    gload16(Bg1 + kc, &Bs[buf][ks * 8192 + 4096 + w * 512]);
  };

  stA(0, 0, 0); stB(0, 0, 0); stA(0, 0, 1); stB(0, 0, 1);

  for (int t = 0; t < KT; t++){
    int c = t & 1, nb = c ^ 1;
    bool pf = (t + 1 < KT);
    asm volatile("s_waitcnt vmcnt(4)" ::: "memory");
    __builtin_amdgcn_s_barrier();

#pragma unroll
    for (int ks = 0; ks < 2; ks++){
      if (ks == 1){
        if (pf) asm volatile("s_waitcnt vmcnt(4)" ::: "memory");
        else    asm volatile("s_waitcnt vmcnt(0)" ::: "memory");
        __builtin_amdgcn_s_barrier();
      }
      if (pf){ if (ks == 0) stA(nb, t + 1, 0); else stA(nb, t + 1, 1); }
      bf16x8 fa[8], fb[2];
#pragma unroll
      for (int m = 0; m < 8; m++){
        int row = wm * 128 + m * 16 + (lane & 15);
        int slot = (lane >> 4) ^ ((row >> 1) & 3);
        fa[m] = *(const bf16x8*)(&As[c][ks * 8192 + row * 32 + slot * 8]);
      }
#pragma unroll
      for (int nn = 0; nn < 2; nn++){
        int row = wn * 64 + nn * 16 + (lane & 15);
        int slot = (lane >> 4) ^ ((row >> 1) & 3);
        fb[nn] = *(const bf16x8*)(&Bs[c][ks * 8192 + row * 32 + slot * 8]);
      }
      __builtin_amdgcn_s_setprio(1);
#pragma unroll
      for (int m = 0; m < 8; m++)
#pragma unroll
        for (int nn = 0; nn < 2; nn++)
          acc[m][nn] = __builtin_amdgcn_mfma_f32_16x16x32_bf16(fa[m], fb[nn], acc[m][nn], 0, 0, 0);
      __builtin_amdgcn_s_setprio(0);
      if (pf){ if (ks == 0) stB(nb, t + 1, 0); else stB(nb, t + 1, 1); }
#pragma unroll
      for (int nn = 0; nn < 2; nn++){
        int row = wn * 64 + 32 + nn * 16 + (lane & 15);
        int slot = (lane >> 4) ^ ((row >> 1) & 3);
        fb[nn] = *(const bf16x8*)(&Bs[c][ks * 8192 + row * 32 + slot * 8]);
      }
      __builtin_amdgcn_s_setprio(1);
#pragma unroll
      for (int m = 0; m < 8; m++)
#pragma unroll
        for (int nn = 0; nn < 2; nn++)
          acc[m][2 + nn] = __builtin_amdgcn_mfma_f32_16x16x32_bf16(fa[m], fb[nn], acc[m][2 + nn], 0, 0, 0);
      __builtin_amdgcn_s_setprio(0);
    }
  }

#pragma unroll
  for (int m = 0; m < 8; m++){
    int rowb = m0 + wm * 128 + m * 16 + ((lane >> 4) << 2);
#pragma unroll
    for (int n = 0; n < 4; n++){
      int col = n0 + wn * 64 + n * 16 + (lane & 15);
      float bv = bias[col];
#pragma unroll
      for (int r = 0; r < 4; r++)
        outp[(size_t)(rowb + r) * N + col] = f2b(acc[m][n][r] + bv);
    }
  }
}

// ---------------- FAVOR phi v2 (MFMA) + optional fused kv/ksum in K-blocks ----------------
__global__ __launch_bounds__(256) void phi2(const u16* __restrict__ qb, const u16* __restrict__ kb,
                                            const u16* __restrict__ omT,
                                            u16* __restrict__ Qp, u16* __restrict__ Kp,
                                            const u16* __restrict__ vt,
                                            u16* __restrict__ kv, float* __restrict__ ksum, int fuse){
  __shared__ __align__(16) u16 qs[128 * 64];
  __shared__ __align__(16) u16 wl[64 * 64];
  __shared__ __align__(16) u16 ph[128 * 128];
  __shared__ __align__(16) u16 Vst[64 * 128];
  __shared__ float part[2][128];
  __shared__ float nrm[128];
  int tid = threadIdx.x, w = tid >> 6, lane = tid & 63;
  int blk = blockIdx.x;
  const u16* src; u16* dst; int row0;
  bool isK = (blk >= 1024);
  if (!isK){ src = qb; dst = Qp; row0 = blk * 128; }
  else     { src = kb; dst = Kp; row0 = (blk - 1024) * 128; }
  const u16* g = src + (size_t)row0 * 64;
#pragma unroll
  for (int i = 0; i < 4; i++){
    int id = tid * 4 + i;
    int r = id >> 3, kc = id & 7;
    *(bf16x8*)(qs + r * 64 + ((kc ^ (r & 7)) << 3)) = *(const bf16x8*)(g + r * 64 + kc * 8);
  }
#pragma unroll
  for (int i = 0; i < 2; i++){
    int id = tid * 2 + i;
    int m = id >> 3, kc = id & 7;
    *(bf16x8*)(wl + m * 64 + ((kc ^ (m & 7)) << 3)) = *(const bf16x8*)(omT + id * 8);
  }
  __syncthreads();
  {
    int r = tid & 127, half = tid >> 7;
    float s = 0.f;
#pragma unroll
    for (int j = 0; j < 4; j++){
      int kc = half * 4 + j;
      bf16x8 v = *(const bf16x8*)(qs + r * 64 + ((kc ^ (r & 7)) << 3));
#pragma unroll
      for (int e = 0; e < 8; e++){ float f = b2f((u16)v[e]); s += f * f; }
    }
    part[half][r] = s;
  }
  __syncthreads();
  if (tid < 128) nrm[tid] = 0.0625f * (part[0][tid] + part[1][tid]);
  __syncthreads();
  f32x4 acc[2][4] = {};
#pragma unroll
  for (int kt = 0; kt < 2; kt++){
    int kc = kt * 4 + (lane >> 4);
    bf16x8 fa[2], fb[4];
#pragma unroll
    for (int mt = 0; mt < 2; mt++){
      int r = w * 32 + mt * 16 + (lane & 15);
      fa[mt] = *(const bf16x8*)(qs + r * 64 + ((kc ^ (r & 7)) << 3));
    }
#pragma unroll
    for (int nt = 0; nt < 4; nt++){
      int m = nt * 16 + (lane & 15);
      fb[nt] = *(const bf16x8*)(wl + m * 64 + ((kc ^ (m & 7)) << 3));
    }
#pragma unroll
    for (int mt = 0; mt < 2; mt++)
#pragma unroll
      for (int nt = 0; nt < 4; nt++)
        acc[mt][nt] = __builtin_amdgcn_mfma_f32_16x16x32_bf16(fa[mt], fb[nt], acc[mt][nt], 0, 0, 0);
  }
  const float LNC = -2.4260151319598086f;   // ln(128^-0.5)
#pragma unroll
  for (int mt = 0; mt < 2; mt++)
#pragma unroll
    for (int nt = 0; nt < 4; nt++)
#pragma unroll
      for (int r4 = 0; r4 < 4; r4++){
        int r = w * 32 + mt * 16 + ((lane >> 4) << 2) + r4;
        int m = nt * 16 + (lane & 15);
        float u = acc[mt][nt][r4];
        float nr = nrm[r];
        ph[r * 128 + m]      = f2b(__expf(u - nr + LNC));
        ph[r * 128 + 64 + m] = f2b(__expf(-u - nr + LNC));
      }
  // stage V^T chunk for fused kv (disjoint LDS; visible after the same barrier)
  int bh = 0, cch = 0;
  if (isK && fuse){
    int rr0 = blk - 1024;
    bh = rr0 >> 4; cch = rr0 & 15;
    const u16* vtc = vt + (size_t)bh * 131072 + cch * 128;
#pragma unroll
    for (int i = 0; i < 4; i++){
      int id = tid * 4 + i;
      int d = id >> 4, mc = id & 15;
      *(bf16x8*)(Vst + d * 128 + mc * 8) = *(const bf16x8*)(vtc + (size_t)d * 2048 + mc * 8);
    }
  }
  __syncthreads();
  u16* go = dst + (size_t)row0 * 128;
#pragma unroll
  for (int i = 0; i < 8; i++){
    int id = i * 256 + tid;
    *(bf16x8*)(go + id * 8) = *(const bf16x8*)(ph + id * 8);
  }
  if (isK && fuse){
    int tm = tid & 15, td = tid >> 4;
    int mbase = tm * 8, dbase = td * 4;
    float acc2[8][4] = {};
    float ks[8] = {};
    for (int i = 0; i < 128; i++){
      bf16x8 kk = *(const bf16x8*)(ph + i * 128 + mbase);
      float kf[8];
#pragma unroll
      for (int e = 0; e < 8; e++) kf[e] = b2f((u16)kk[e]);
      float vf[4];
#pragma unroll
      for (int e = 0; e < 4; e++) vf[e] = b2f(Vst[(dbase + e) * 128 + i]);
#pragma unroll
      for (int a = 0; a < 8; a++){
        ks[a] += kf[a];
#pragma unroll
        for (int bb = 0; bb < 4; bb++) acc2[a][bb] += kf[a] * vf[bb];
      }
    }
    u16* kvout = kv + ((size_t)bh * 16 + cch) * 8192;
#pragma unroll
    for (int a = 0; a < 8; a++)
#pragma unroll
      for (int bb = 0; bb < 4; bb++)
        kvout[(size_t)(dbase + bb) * 128 + mbase + a] = f2b(acc2[a][bb]);
    if (td == 0){
      float* kso = ksum + ((size_t)bh * 16 + cch) * 128;
#pragma unroll
      for (int a = 0; a < 8; a++) kso[mbase + a] = ks[a];
    }
  }
}

// ---------------- per-chunk kv^T[d][m] (bf16), ksum f32 (fallback when not fused) ----------------
__global__ __launch_bounds__(256) void kvchunk(const u16* __restrict__ Kp, const u16* __restrict__ vt,
                                               u16* __restrict__ kv, float* __restrict__ ksum){
  __shared__ __align__(16) u16 Ks[128 * 128];
  __shared__ __align__(16) u16 Vst[64 * 128];
  int blk = blockIdx.x; int bh = blk >> 4, c = blk & 15;
  int tid = threadIdx.x;
  size_t base = (size_t)bh * 2048 + c * 128;
  const u16* Kc = Kp + base * 128;
  const u16* vtc = vt + (size_t)bh * 64 * 2048 + c * 128;
  {
    int j = tid >> 1, half = tid & 1;
#pragma unroll
    for (int i = 0; i < 8; i++)
      *(bf16x8*)(Ks + j * 128 + half * 64 + i * 8) = *(const bf16x8*)(Kc + j * 128 + half * 64 + i * 8);
#pragma unroll
    for (int i = 0; i < 4; i++){
      int id = tid * 4 + i;
      int d = id >> 4, mc = id & 15;
      *(bf16x8*)(Vst + d * 128 + mc * 8) = *(const bf16x8*)(vtc + (size_t)d * 2048 + mc * 8);
    }
  }
  __syncthreads();
  int tm = tid & 15, td = tid >> 4;
  int mbase = tm * 8, dbase = td * 4;
  float acc[8][4] = {};
  float ks[8] = {};
  for (int i = 0; i < 128; i++){
    bf16x8 kk = *(const bf16x8*)(Ks + i * 128 + mbase);
    float kf[8];
#pragma unroll
    for (int e = 0; e < 8; e++) kf[e] = b2f((u16)kk[e]);
    float vf[4];
#pragma unroll
    for (int e = 0; e < 4; e++) vf[e] = b2f(Vst[(dbase + e) * 128 + i]);
#pragma unroll
    for (int a = 0; a < 8; a++){
      ks[a] += kf[a];
#pragma unroll
      for (int bb = 0; bb < 4; bb++) acc[a][bb] += kf[a] * vf[bb];
    }
  }
  u16* kvout = kv + ((size_t)bh * 16 + c) * 8192;
#pragma unroll
  for (int a = 0; a < 8; a++)
#pragma unroll
    for (int bb = 0; bb < 4; bb++)
      kvout[(size_t)(dbase + bb) * 128 + mbase + a] = f2b(acc[a][bb]);
  if (td == 0){
    float* kso = ksum + ((size_t)bh * 16 + c) * 128;
#pragma unroll
    for (int a = 0; a < 8; a++) kso[mbase + a] = ks[a];
  }
}

// ---------------- exclusive prefix over chunks (in place; kv bf16, f32 carry) ----------------
__global__ __launch_bounds__(256) void kvscan(u16* __restrict__ kv, float* __restrict__ ksum){
  int bh = blockIdx.x;
  int p = blockIdx.y;
  int tid = threadIdx.x;
  if (p < 8){
    size_t base = (size_t)bh * 16 * 8192;
    int idx0 = p * 1024 + tid;
    for (int rep = 0; rep < 4; rep++){
      int idx = idx0 + rep * 256;
      float run = 0.f;
#pragma unroll
      for (int c = 0; c < 16; c++){
        size_t off = base + (size_t)c * 8192 + idx;
        float v = b2f(kv[off]); kv[off] = f2b(run); run += v;
      }
    }
  } else if (tid < 128){
    size_t base = (size_t)bh * 16 * 128;
    float run = 0.f;
#pragma unroll
    for (int c = 0; c < 16; c++){
      size_t off = base + c * 128 + tid;
      float v = ksum[off]; ksum[off] = run; run += v;
    }
  }
}

// ---------------- MFMA fused attention (kv_pre bf16) ----------------
__global__ __launch_bounds__(512) void attn_fused(const u16* __restrict__ Qp, const u16* __restrict__ Kp,
                                                  const u16* __restrict__ vt, const u16* __restrict__ kvp,
                                                  const float* __restrict__ ksum, u16* __restrict__ aout){
  __shared__ __align__(16) u16 sm[53248];
  int blk = blockIdx.x, bh = blk >> 4, c = blk & 15;
  int b = bh >> 4, h = bh & 15;
  int tid = threadIdx.x, w = tid >> 6, lane = tid & 63;
  size_t base = (size_t)bh * 2048 + c * 128;
  const u16* Qc = Qp + base * 128;
  const u16* Kc = Kp + base * 128;
  const u16* vtc = vt + (size_t)bh * 64 * 2048 + c * 128;
  const u16* kvc = kvp + ((size_t)bh * 16 + c) * 8192;
  const float* ksc = ksum + ((size_t)bh * 16 + c) * 128;
  u16* Qs = sm;
  u16* Ks = sm + 16384;
  u16* B2 = sm + 32768;

#pragma unroll
  for (int i = 0; i < 4; i++){
    int id = tid * 4 + i;
    int r = id >> 4, kc = id & 15;
    int swo = (kc ^ (r & 15)) << 3;
    *(bf16x8*)(Qs + r * 128 + swo) = *(const bf16x8*)(Qc + (size_t)r * 128 + kc * 8);
    *(bf16x8*)(Ks + r * 128 + swo) = *(const bf16x8*)(Kc + (size_t)r * 128 + kc * 8);
  }
#pragma unroll
  for (int i = 0; i < 2; i++){
    int id = tid * 2 + i;
    int d = id >> 4, kc = id & 15;
    *(bf16x8*)(B2 + d * 256 + ((kc ^ (d & 31)) << 3)) = *(const bf16x8*)(vtc + (size_t)d * 2048 + kc * 8);
  }
#pragma unroll
  for (int i = 0; i < 2; i++){
    int id = tid * 2 + i;
    int d = id >> 4, mc = id & 15;
    bf16x8 pk = *(const bf16x8*)(kvc + d * 128 + mc * 8);
    int kc = 16 + mc;
    *(bf16x8*)(B2 + d * 256 + ((kc ^ (d & 31)) << 3)) = pk;
  }
  {
    int row = 64 + (tid >> 5), kc = tid & 31;
    bf16x8 pk = {};
    if (row == 64){
      if (kc < 16){
#pragma unroll
        for (int e = 0; e < 8; e++) pk[e] = (short)0x3F80;
      } else {
        const float* s8 = ksc + (kc - 16) * 8;
        float4 f0 = *(const float4*)(s8);
        float4 f1 = *(const float4*)(s8 + 4);
        pk[0] = (short)f2b(f0.x); pk[1] = (short)f2b(f0.y); pk[2] = (short)f2b(f0.z); pk[3] = (short)f2b(f0.w);
        pk[4] = (short)f2b(f1.x); pk[5] = (short)f2b(f1.y); pk[6] = (short)f2b(f1.z); pk[7] = (short)f2b(f1.w);
      }
    }
    *(bf16x8*)(B2 + row * 256 + ((kc ^ (row & 31)) << 3)) = pk;
  }
  __syncthreads();

  int wm = w >> 2, wn = w & 3;
  f32x4 acc1[4][2] = {};
#pragma unroll
  for (int kk = 0; kk < 4; kk++){
    int kc = kk * 4 + (lane >> 4);
    bf16x8 fa[4], fb[2];
#pragma unroll
    for (int m = 0; m < 4; m++){
      int row = wm * 64 + m * 16 + (lane & 15);
      fa[m] = *(const bf16x8*)(Qs + row * 128 + ((kc ^ (row & 15)) << 3));
    }
#pragma unroll
    for (int n = 0; n < 2; n++){
      int row = wn * 32 + n * 16 + (lane & 15);
      fb[n] = *(const bf16x8*)(Ks + row * 128 + ((kc ^ (row & 15)) << 3));
    }
#pragma unroll
    for (int m = 0; m < 4; m++)
#pragma unroll
      for (int n = 0; n < 2; n++)
        acc1[m][n] = __builtin_amdgcn_mfma_f32_16x16x32_bf16(fa[m], fb[n], acc1[m][n], 0, 0, 0);
  }
  __syncthreads();

#pragma unroll
  for (int m = 0; m < 4; m++)
#pragma unroll
    for (int n = 0; n < 2; n++)
#pragma unroll
      for (int r = 0; r < 4; r++){
        int i = wm * 64 + m * 16 + ((lane >> 4) << 2) + r;
        int j = wn * 32 + n * 16 + (lane & 15);
        float v = (j <= i) ? acc1[m][n][r] : 0.f;
        Ks[i * 128 + (((j >> 3) ^ (i & 15)) << 3) + (j & 7)] = f2b(v);
      }
  __syncthreads();

  f32x4 acc2[5] = {};
#pragma unroll
  for (int kk = 0; kk < 8; kk++){
    int kc = kk * 4 + (lane >> 4);
    int rowA = w * 16 + (lane & 15);
    bf16x8 fa2;
    if (kk < 4) fa2 = *(const bf16x8*)(Ks + rowA * 128 + ((kc ^ (rowA & 15)) << 3));
    else        fa2 = *(const bf16x8*)(Qs + rowA * 128 + (((kc - 16) ^ (rowA & 15)) << 3));
#pragma unroll
    for (int n = 0; n < 5; n++){
      int d = n * 16 + (lane & 15);
      bf16x8 fb2 = *(const bf16x8*)(B2 + d * 256 + ((kc ^ (d & 31)) << 3));
      acc2[n] = __builtin_amdgcn_mfma_f32_16x16x32_bf16(fa2, fb2, acc2[n], 0, 0, 0);
    }
  }

  float dd[4];
#pragma unroll
  for (int r = 0; r < 4; r++) dd[r] = __shfl(acc2[4][r], lane & 48) + 1e-6f;
  size_t obase = ((size_t)b * 2048 + c * 128) * 1024 + (size_t)h * 64;
#pragma unroll
  for (int n = 0; n < 4; n++)
#pragma unroll
    for (int r = 0; r < 4; r++){
      int i = w * 16 + ((lane >> 4) << 2) + r;
      int d = n * 16 + (lane & 15);
      aout[obase + (size_t)i * 1024 + d] = f2b(acc2[n][r] / dd[r]);
    }
}

// ---------------- universal residual-add + LayerNorm ----------------
__global__ __launch_bounds__(256) void lnr(const float* X1f, const u16* X1b,
                                           const u16* P0, const u16* P1,
                                           const float* __restrict__ g, const float* __restrict__ bb,
                                           float* outf, u16* outb, u16* outb2){
  __shared__ float red[2][4];
  int row = blockIdx.x, tid = threadIdx.x, w = tid >> 6, lane = tid & 63;
  size_t ro = (size_t)row * 1024 + tid * 4;
  float x0, x1, x2, x3;
  if (X1f){
    float4 a = *(const float4*)(X1f + ro);
    x0 = a.x; x1 = a.y; x2 = a.z; x3 = a.w;
  } else {
    ushort4 a = *(const ushort4*)(X1b + ro);
    x0 = b2f(a.x); x1 = b2f(a.y); x2 = b2f(a.z); x3 = b2f(a.w);
  }
  {
    ushort4 p0 = *(const ushort4*)(P0 + ro);
    x0 += b2f(p0.x); x1 += b2f(p0.y); x2 += b2f(p0.z); x3 += b2f(p0.w);
  }
  if (P1){
    ushort4 p1 = *(const ushort4*)(P1 + ro);
    x0 += b2f(p1.x); x1 += b2f(p1.y); x2 += b2f(p1.z); x3 += b2f(p1.w);
  }
  float s1 = x0 + x1 + x2 + x3;
  float s2 = x0 * x0 + x1 * x1 + x2 * x2 + x3 * x3;
#pragma unroll
  for (int off = 32; off; off >>= 1){ s1 += __shfl_xor(s1, off); s2 += __shfl_xor(s2, off); }
  if (lane == 0){ red[0][w] = s1; red[1][w] = s2; }
  __syncthreads();
  float t1 = red[0][0] + red[0][1] + red[0][2] + red[0][3];
  float t2 = red[1][0] + red[1][1] + red[1][2] + red[1][3];
  float mu = t1 * (1.f / 1024.f);
  float var = t2 * (1.f / 1024.f) - mu * mu;
  float rs = rsqrtf(var + 1e-5f);
  float4 gv = *(const float4*)(g + tid * 4);
  float4 bv = *(const float4*)(bb + tid * 4);
  float o0 = (x0 - mu) * rs * gv.x + bv.x;
  float o1 = (x1 - mu) * rs * gv.y + bv.y;
  float o2 = (x2 - mu) * rs * gv.z + bv.z;
  float o3 = (x3 - mu) * rs * gv.w + bv.w;
  if (outf) *(float4*)(outf + ro) = make_float4(o0, o1, o2, o3);
  ushort4 ob = make_ushort4(f2b(o0), f2b(o1), f2b(o2), f2b(o3));
  if (outb)  *(ushort4*)(outb + ro)  = ob;
  if (outb2) *(ushort4*)(outb2 + ro) = ob;
}

// ---------------- host ----------------
extern "C" void kernel_launch(void* const* d_in, const int* in_sizes, int n_in,
                              void* d_out, int out_size, void* d_ws, size_t ws_size,
                              hipStream_t stream){
  (void)in_sizes; (void)n_in;
  const float* x   = (const float*)d_in[0];
  const float* Wq  = (const float*)d_in[1];
  const float* bq  = (const float*)d_in[2];
  const float* Wk  = (const float*)d_in[3];
  const float* bk  = (const float*)d_in[4];
  const float* Wv  = (const float*)d_in[5];
  const float* bv  = (const float*)d_in[6];
  const float* Wo  = (const float*)d_in[7];
  const float* bo  = (const float*)d_in[8];
  const float* om  = (const float*)d_in[9];
  const float* g1  = (const float*)d_in[10];
  const float* be1 = (const float*)d_in[11];
  const float* W1  = (const float*)d_in[12];
  const float* bf1 = (const float*)d_in[13];
  const float* W2  = (const float*)d_in[14];
  const float* bf2 = (const float*)d_in[15];
  const float* g2  = (const float*)d_in[16];
  const float* be2 = (const float*)d_in[17];

  char* ws = (char*)d_ws;
  size_t off = 0;
  auto alloc = [&](size_t bytes) -> void* {
    void* p = ws + off; off += (bytes + 255) & ~(size_t)255; return p;
  };
  u16* Wcat = (u16*)alloc(3072ull * 1024 * 2);
  u16* Wot  = (u16*)alloc(1024ull * 1024 * 2);
  u16* W1t  = (u16*)alloc(4096ull * 1024 * 2);
  u16* W2t  = (u16*)alloc(1024ull * 4096 * 2);
  u16* omT  = (u16*)alloc(64ull * 64 * 2);
  float* bcat = (float*)alloc(6ull * 3072 * 4);
  float* zbuf = (float*)alloc(1024 * 4);
  u16* Xb  = (u16*)alloc(8192ull * 1024 * 2);
  u16* qb  = (u16*)alloc(131072ull * 64 * 2);   // contiguous qb|kb|vt|Qp for ybuf alias
  u16* kb  = (u16*)alloc(131072ull * 64 * 2);
  u16* vt  = (u16*)alloc(131072ull * 64 * 2);
  u16* Qp  = (u16*)alloc(131072ull * 128 * 2);
  u16* Kp  = (u16*)alloc(131072ull * 128 * 2);
  float* ksum = (float*)alloc(64ull * 16 * 128 * 4);
  size_t base_end = off;

  // dedicated 16MB kv buffer enables phi2-fused kvchunk (gated on ws_size)
  u16* kvded = (u16*)alloc(64ull * 16 * 8192 * 2);
  bool fuse = (off <= ws_size);
  if (!fuse){ off = base_end; kvded = qb; }     // fallback: kv in qb + separate kvchunk

  if (off > ws_size){
    fillv<<<(out_size + 255) / 256, 256, 0, stream>>>((float*)d_out, (float)(ws_size >> 20), out_size);
    return;
  }

  u16*  ybuf   = qb;                    // FFN intermediate bf16 [8192][4096] over qb..Qp[0:16MB]
  u16*  wooutb = Qp;                    // Wo out bf16 16MB (Qp dead after attn)
  u16*  w2outb = Qp + 8388608;          // W2 partial kz=0, bf16 16MB
  u16*  w2p1   = Kp + 8388608;          // W2 partial kz=1, bf16 16MB (Kp[16:32], dead after attn)
  u16*  residb = (u16*)d_out;           // bf16 residual stream in d_out[0:16MB]; final layer writes f32

  cvt16<<<8192, 256, 0, stream>>>(x, Xb);
  catbias<<<72, 256, 0, stream>>>(bq, bk, bv, bcat);
  fillv<<<4, 256, 0, stream>>>(zbuf, 0.f, 1024);

  for (int l = 0; l < 6; l++){
    size_t o1k = (size_t)l * 1024 * 1024;
    size_t o4k = (size_t)l * 4096 * 1024;
    wtrans7<<<12292, 256, 0, stream>>>(Wq + o1k, Wk + o1k, Wv + o1k, Wo + o1k,
                                       W1 + o4k, W2 + o4k, om + (size_t)l * 4096,
                                       Wcat, Wot, W1t, W2t, omT);

    gemm_bt<5><<<dim3(24, 64), 256, 0, stream>>>(Xb, Wcat, bcat + l * 3072, qb, 8192, 3072, 1024, 1024, 1024);
    phi2<<<2048, 256, 0, stream>>>(qb, kb, omT, Qp, Kp, vt, kvded, ksum, fuse ? 1 : 0);
    if (!fuse) kvchunk<<<1024, 256, 0, stream>>>(Kp, vt, kvded, ksum);
    kvscan<<<dim3(64, 9), 256, 0, stream>>>(kvded, ksum);
    attn_fused<<<1024, 512, 0, stream>>>(Qp, Kp, vt, kvded, ksum, Xb);
    gemm_bt<6><<<dim3(8, 64), 256, 0, stream>>>(Xb, Wot, bo + l * 1024, wooutb, 8192, 1024, 1024, 1024, 1024);
    lnr<<<8192, 256, 0, stream>>>(l == 0 ? x : nullptr, l == 0 ? nullptr : residb,
                                  wooutb, nullptr, g1 + l * 1024, be1 + l * 1024,
                                  nullptr, Xb, nullptr);
    gemm8p<2><<<dim3(16, 32), 512, 0, stream>>>(Xb, W1t, bf1 + l * 4096, ybuf, 8192, 4096, 1024, 1024, 1024);
    gemm8pk<<<dim3(256), 512, 0, stream>>>(ybuf, W2t, bf2 + l * 1024, zbuf, w2outb, w2p1,
                                           8192, 1024, 2048, 4096, 4096);
    if (l == 5)
      lnr<<<8192, 256, 0, stream>>>(nullptr, Xb, w2outb, w2p1, g2 + l * 1024, be2 + l * 1024,
                                    (float*)d_out, nullptr, nullptr);
    else
      lnr<<<8192, 256, 0, stream>>>(nullptr, Xb, w2outb, w2p1, g2 + l * 1024, be2 + l * 1024,
                                    nullptr, Xb, residb);
  }
}

// Round 19
// 2365.268 us; speedup vs baseline: 1.0987x; 1.0057x over previous
//
#include <hip/hip_runtime.h>

typedef unsigned short u16;
typedef __attribute__((ext_vector_type(8))) short bf16x8;
typedef __attribute__((ext_vector_type(4))) float f32x4;

#define DEV __device__ __forceinline__

DEV float b2f(u16 h){ return __uint_as_float(((unsigned)h) << 16); }
DEV u16 f2b(float f){ unsigned u = __float_as_uint(f); u += 0x7FFFu + ((u >> 16) & 1u); return (u16)(u >> 16); }

DEV void gload16(const u16* g, u16* l){
  __builtin_amdgcn_global_load_lds((const __attribute__((address_space(1))) unsigned*)g,
                                   (__attribute__((address_space(3))) unsigned*)l, 16, 0, 0);
}

// ---------------- merged per-layer weight transpose: 7 tensors in one launch ----------------
__global__ __launch_bounds__(256) void wtrans7(const float* __restrict__ Wq, const float* __restrict__ Wk,
                                               const float* __restrict__ Wv, const float* __restrict__ Wo,
                                               const float* __restrict__ W1, const float* __restrict__ W2,
                                               const float* __restrict__ om,
                                               u16* __restrict__ Wcat, u16* __restrict__ Wot,
                                               u16* __restrict__ W1t, u16* __restrict__ W2t,
                                               u16* __restrict__ omT){
  __shared__ float tile[32][33];
  int id = blockIdx.x;
  const float* src; u16* dst; int K, N, kb, nb; float scale = 1.f;
  if (id < 4096){
    int wsel = id >> 10, loc = id & 1023;
    kb = loc >> 5; nb = loc & 31; K = 1024; N = 1024;
    src = (wsel == 0) ? Wq : (wsel == 1) ? Wk : (wsel == 2) ? Wv : Wo;
    dst = (wsel < 3) ? Wcat + (size_t)wsel * 1048576 : Wot;
  } else if (id < 8192){
    int loc = id - 4096;
    kb = loc & 31; nb = loc >> 5; K = 1024; N = 4096;
    src = W1; dst = W1t;
  } else if (id < 12288){
    int loc = id - 8192;
    kb = loc & 127; nb = loc >> 7; K = 4096; N = 1024;
    src = W2; dst = W2t;
  } else {
    int loc = id - 12288;
    kb = loc & 1; nb = loc >> 1; K = 64; N = 64;
    src = om; dst = omT; scale = 0.35355339059327373f;
  }
  int k0 = kb * 32, n0 = nb * 32;
  int tid = threadIdx.x;
#pragma unroll
  for (int i = 0; i < 4; i++){
    int idx = tid + i * 256;
    int r = idx >> 5, c = idx & 31;
    tile[r][c] = src[(size_t)(k0 + r) * N + n0 + c];
  }
  __syncthreads();
#pragma unroll
  for (int i = 0; i < 4; i++){
    int idx = tid + i * 256;
    int r = idx >> 5, c = idx & 31;
    dst[(size_t)(n0 + r) * K + k0 + c] = f2b(tile[c][r] * scale);
  }
}

// ---------------- f32 -> bf16 convert ----------------
__global__ __launch_bounds__(256) void cvt16(const float* __restrict__ src, u16* __restrict__ dst){
  size_t i = ((size_t)blockIdx.x * 256 + threadIdx.x) * 4;
  float4 f = *(const float4*)(src + i);
  ushort4 o = make_ushort4(f2b(f.x), f2b(f.y), f2b(f.z), f2b(f.w));
  *(ushort4*)(dst + i) = o;
}

// ---------------- bias concat (all layers): [6][3072] = bq|bk|bv ----------------
__global__ void catbias(const float* __restrict__ bq, const float* __restrict__ bk,
                        const float* __restrict__ bv, float* __restrict__ bcat){
  int i = blockIdx.x * 256 + threadIdx.x;
  if (i >= 6 * 3072) return;
  int l = i / 3072, j = i % 3072;
  float v = (j < 1024) ? bq[l * 1024 + j] : (j < 2048) ? bk[l * 1024 + j - 1024] : bv[l * 1024 + j - 2048];
  bcat[i] = v;
}

// ---------------- diagnostic / zero fill ----------------
__global__ void fillv(float* __restrict__ p, float v, int n){
  int i = blockIdx.x * 256 + threadIdx.x;
  if (i < n) p[i] = v;
}

// ---------------- 128^2 bf16 MFMA GEMM (gload_lds dbuf + counted vmcnt + XCD swizzle) ----------------
// EPI 2: relu bf16 [M,N] ; EPI 5: fused QKV ; EPI 6: bf16 [M,N]
DEV int swz(int r){ return (r & 3) ^ ((r >> 2) & 3); }

template<int EPI>
__global__ __launch_bounds__(256) void gemm_bt(const u16* __restrict__ A, const u16* __restrict__ Bt,
                                               const float* __restrict__ bias, void* __restrict__ outp,
                                               int M, int N, int K, int ldA, int ldB){
  __shared__ __align__(16) u16 As[2][4096];
  __shared__ __align__(16) u16 Bs[2][4096];
  const int tid = threadIdx.x;
  const int lane = tid & 63;
  const int w = tid >> 6;
  const int wm = w >> 1, wn = w & 1;
  int nx = gridDim.x;
  int nwg = nx * gridDim.y;
  int lin = blockIdx.y * nx + blockIdx.x;
  int cpx = nwg >> 3;
  int sw = (lin & 7) * cpx + (lin >> 3);
  const int m0 = (sw / nx) * 128;
  const int n0 = (sw % nx) * 128;

  int r0 = tid >> 2, c0 = tid & 3;
  int r1 = r0 + 64;
  int cs0 = c0 ^ swz(r0);
  int cs1 = c0 ^ swz(r1);
  const u16* ag0 = A + (size_t)(m0 + r0) * ldA + cs0 * 8;
  const u16* ag1 = A + (size_t)(m0 + r1) * ldA + cs1 * 8;
  const u16* bg0 = Bt + (size_t)(n0 + r0) * ldB + cs0 * 8;
  const u16* bg1 = Bt + (size_t)(n0 + r1) * ldB + cs1 * 8;

  f32x4 acc[4][4] = {};
  const int KT = K >> 5;

  gload16(ag0, &As[0][w * 512]);
  gload16(ag1, &As[0][2048 + w * 512]);
  gload16(bg0, &Bs[0][w * 512]);
  gload16(bg1, &Bs[0][2048 + w * 512]);

  for (int kt = 0; kt < KT; kt++){
    int cur = kt & 1;
    if (kt + 1 < KT){
      int ko = (kt + 1) << 5;
      gload16(ag0 + ko, &As[cur ^ 1][w * 512]);
      gload16(ag1 + ko, &As[cur ^ 1][2048 + w * 512]);
      gload16(bg0 + ko, &Bs[cur ^ 1][w * 512]);
      gload16(bg1 + ko, &Bs[cur ^ 1][2048 + w * 512]);
      asm volatile("s_waitcnt vmcnt(4)" ::: "memory");
    } else {
      asm volatile("s_waitcnt vmcnt(0)" ::: "memory");
    }
    __builtin_amdgcn_s_barrier();
    bf16x8 fa[4], fb[4];
#pragma unroll
    for (int m = 0; m < 4; m++){
      int row = wm * 64 + m * 16 + (lane & 15);
      int cc = (lane >> 4) ^ swz(row);
      fa[m] = *(const bf16x8*)(&As[cur][row * 32 + cc * 8]);
    }
#pragma unroll
    for (int n = 0; n < 4; n++){
      int row = wn * 64 + n * 16 + (lane & 15);
      int cc = (lane >> 4) ^ swz(row);
      fb[n] = *(const bf16x8*)(&Bs[cur][row * 32 + cc * 8]);
    }
#pragma unroll
    for (int m = 0; m < 4; m++)
#pragma unroll
      for (int n = 0; n < 4; n++)
        acc[m][n] = __builtin_amdgcn_mfma_f32_16x16x32_bf16(fa[m], fb[n], acc[m][n], 0, 0, 0);
    asm volatile("s_waitcnt lgkmcnt(0)" ::: "memory");
    __builtin_amdgcn_s_barrier();
  }

#pragma unroll
  for (int m = 0; m < 4; m++){
    int rowb = m0 + wm * 64 + m * 16 + ((lane >> 4) << 2);
#pragma unroll
    for (int n = 0; n < 4; n++){
      int col = n0 + wn * 64 + n * 16 + (lane & 15);
      float bv = bias[col];
      if (EPI == 5 && col >= 2048){
        int cv = col - 2048, hh = cv >> 6, dh = cv & 63;
        int bIdx = rowb >> 11, s4 = rowb & 2047;
        ushort4 pk = make_ushort4(f2b(acc[m][n][0] + bv), f2b(acc[m][n][1] + bv),
                                  f2b(acc[m][n][2] + bv), f2b(acc[m][n][3] + bv));
        *(ushort4*)&((u16*)outp + 16777216)[((size_t)(bIdx * 16 + hh) * 64 + dh) * 2048 + s4] = pk;
      } else {
#pragma unroll
        for (int r = 0; r < 4; r++){
          float v = acc[m][n][r] + bv;
          int rr = rowb + r;
          if (EPI == 5){
            u16* dst0 = (u16*)outp + (col < 1024 ? 0 : 8388608);
            int cv = col & 1023, hh = cv >> 6, dh = cv & 63;
            int bIdx = rr >> 11, s = rr & 2047;
            dst0[(((size_t)(bIdx * 16 + hh) * 2048 + s) << 6) + dh] = f2b(v);
          } else if (EPI == 2){
            ((u16*)outp)[(size_t)rr * N + col] = f2b(v > 0.f ? v : 0.f);
          } else {
            ((u16*)outp)[(size_t)rr * N + col] = f2b(v);
          }
        }
      }
    }
  }
}

// ---------------- 8-phase 256^2 GEMM (m201 template): BK=64, K-half subtiles, counted vmcnt ----------------
// EPI 2: relu bf16 ; EPI 6: bf16   (scalar epilogue)
// XCD mapping: squarer 8x8 tile chunk per XCD when grid==(16,32) (W1 case)
template<int EPI>
__global__ __launch_bounds__(512, 1) void gemm8p(const u16* __restrict__ A, const u16* __restrict__ Bt,
                                                 const float* __restrict__ bias, void* __restrict__ outp,
                                                 int M, int N, int K, int ldA, int ldB){
  __shared__ __align__(16) u16 As[2][16384];
  __shared__ __align__(16) u16 Bs[2][16384];
  const int tid = threadIdx.x;
  const int lane = tid & 63;
  const int w = tid >> 6;
  const int wm = w >> 2, wn = w & 3;
  int nx = gridDim.x;
  int nwg = nx * gridDim.y;
  int lin = blockIdx.y * nx + blockIdx.x;
  int m0, n0;
  if (nx == 16 && gridDim.y == 32){
    // squarer: each XCD owns an 8x8 tile block (A 4MB + B 4MB per XCD vs 2+8)
    int xcd = lin & 7, loc = lin >> 3;
    int mt = (xcd >> 1) * 8 + (loc >> 3);
    int nt = (xcd & 1) * 8 + (loc & 7);
    m0 = mt * 256; n0 = nt * 256;
  } else {
    int cpx = nwg >> 3;
    int sw = (lin & 7) * cpx + (lin >> 3);
    m0 = (sw / nx) * 256;
    n0 = (sw % nx) * 256;
  }

  const int id1 = 512 + tid;
  const int r0 = tid >> 2, c20 = tid & 3;
  const int r1 = id1 >> 2, c21 = id1 & 3;
  const int cs0 = c20 ^ ((r0 >> 1) & 3);
  const int cs1 = c21 ^ ((r1 >> 1) & 3);
  const u16* Ag0 = A + (size_t)(m0 + r0) * ldA + cs0 * 8;
  const u16* Ag1 = A + (size_t)(m0 + r1) * ldA + cs1 * 8;
  const u16* Bg0 = Bt + (size_t)(n0 + r0) * ldB + cs0 * 8;
  const u16* Bg1 = Bt + (size_t)(n0 + r1) * ldB + cs1 * 8;

  f32x4 acc[8][4] = {};
  const int KT = K >> 6;

  auto stA = [&](int buf, int kt, int ks){
    int kc = kt * 64 + ks * 32;
    gload16(Ag0 + kc, &As[buf][ks * 8192 + w * 512]);
    gload16(Ag1 + kc, &As[buf][ks * 8192 + 4096 + w * 512]);
  };
  auto stB = [&](int buf, int kt, int ks){
    int kc = kt * 64 + ks * 32;
    gload16(Bg0 + kc, &Bs[buf][ks * 8192 + w * 512]);
    gload16(Bg1 + kc, &Bs[buf][ks * 8192 + 4096 + w * 512]);
  };

  stA(0, 0, 0); stB(0, 0, 0); stA(0, 0, 1); stB(0, 0, 1);

  for (int t = 0; t < KT; t++){
    int c = t & 1, nb = c ^ 1;
    bool pf = (t + 1 < KT);
    asm volatile("s_waitcnt vmcnt(4)" ::: "memory");
    __builtin_amdgcn_s_barrier();

#pragma unroll
    for (int ks = 0; ks < 2; ks++){
      if (ks == 1){
        if (pf) asm volatile("s_waitcnt vmcnt(4)" ::: "memory");
        else    asm volatile("s_waitcnt vmcnt(0)" ::: "memory");
        __builtin_amdgcn_s_barrier();
      }
      if (pf){ if (ks == 0) stA(nb, t + 1, 0); else stA(nb, t + 1, 1); }
      bf16x8 fa[8], fb[2];
#pragma unroll
      for (int m = 0; m < 8; m++){
        int row = wm * 128 + m * 16 + (lane & 15);
        int slot = (lane >> 4) ^ ((row >> 1) & 3);
        fa[m] = *(const bf16x8*)(&As[c][ks * 8192 + row * 32 + slot * 8]);
      }
#pragma unroll
      for (int nn = 0; nn < 2; nn++){
        int row = wn * 64 + nn * 16 + (lane & 15);
        int slot = (lane >> 4) ^ ((row >> 1) & 3);
        fb[nn] = *(const bf16x8*)(&Bs[c][ks * 8192 + row * 32 + slot * 8]);
      }
      __builtin_amdgcn_s_setprio(1);
#pragma unroll
      for (int m = 0; m < 8; m++)
#pragma unroll
        for (int nn = 0; nn < 2; nn++)
          acc[m][nn] = __builtin_amdgcn_mfma_f32_16x16x32_bf16(fa[m], fb[nn], acc[m][nn], 0, 0, 0);
      __builtin_amdgcn_s_setprio(0);
      if (pf){ if (ks == 0) stB(nb, t + 1, 0); else stB(nb, t + 1, 1); }
#pragma unroll
      for (int nn = 0; nn < 2; nn++){
        int row = wn * 64 + 32 + nn * 16 + (lane & 15);
        int slot = (lane >> 4) ^ ((row >> 1) & 3);
        fb[nn] = *(const bf16x8*)(&Bs[c][ks * 8192 + row * 32 + slot * 8]);
      }
      __builtin_amdgcn_s_setprio(1);
#pragma unroll
      for (int m = 0; m < 8; m++)
#pragma unroll
        for (int nn = 0; nn < 2; nn++)
          acc[m][2 + nn] = __builtin_amdgcn_mfma_f32_16x16x32_bf16(fa[m], fb[nn], acc[m][2 + nn], 0, 0, 0);
      __builtin_amdgcn_s_setprio(0);
    }
  }

#pragma unroll
  for (int m = 0; m < 8; m++){
    int rowb = m0 + wm * 128 + m * 16 + ((lane >> 4) << 2);
#pragma unroll
    for (int n = 0; n < 4; n++){
      int col = n0 + wn * 64 + n * 16 + (lane & 15);
      float bv = bias[col];
#pragma unroll
      for (int r = 0; r < 4; r++){
        float v = acc[m][n][r] + bv;
        int rr = rowb + r;
        if (EPI == 2) ((u16*)outp)[(size_t)rr * N + col] = f2b(v > 0.f ? v : 0.f);
        else          ((u16*)outp)[(size_t)rr * N + col] = f2b(v);
      }
    }
  }
}

// ---------------- 8-phase 256^2 split-K GEMM: 256 blocks = (4 n)x(32 m)x(2 kz), bf16 partials ----------------
__global__ __launch_bounds__(512, 1) void gemm8pk(const u16* __restrict__ A, const u16* __restrict__ Bt,
                                                  const float* __restrict__ bias0, const float* __restrict__ bias1,
                                                  u16* __restrict__ out0, u16* __restrict__ out1,
                                                  int M, int N, int Khalf, int ldA, int ldB){
  __shared__ __align__(16) u16 As[2][16384];
  __shared__ __align__(16) u16 Bs[2][16384];
  const int tid = threadIdx.x;
  const int lane = tid & 63;
  const int w = tid >> 6;
  const int wm = w >> 2, wn = w & 3;
  int lin = blockIdx.x;               // 256 blocks
  int cpx = gridDim.x >> 3;
  int sw = (lin & 7) * cpx + (lin >> 3);
  const int kz = sw & 1;
  const int t2 = sw >> 1;
  const int n0 = (t2 & 3) * 256;
  const int m0 = (t2 >> 2) * 256;
  const u16* Ab = A + kz * Khalf;
  const u16* Bb = Bt + kz * Khalf;
  u16* outp = kz ? out1 : out0;
  const float* bias = kz ? bias1 : bias0;

  const int id1 = 512 + tid;
  const int r0 = tid >> 2, c20 = tid & 3;
  const int r1 = id1 >> 2, c21 = id1 & 3;
  const int cs0 = c20 ^ ((r0 >> 1) & 3);
  const int cs1 = c21 ^ ((r1 >> 1) & 3);
  const u16* Ag0 = Ab + (size_t)(m0 + r0) * ldA + cs0 * 8;
  const u16* Ag1 = Ab + (size_t)(m0 + r1) * ldA + cs1 * 8;
  const u16* Bg0 = Bb + (size_t)(n0 + r0) * ldB + cs0 * 8;
  const u16* Bg1 = Bb + (size_t)(n0 + r1) * ldB + cs1 * 8;

  f32x4 acc[8][4] = {};
  const int KT = Khalf >> 6;

  auto stA = [&](int buf, int kt, int ks){
    int kc = kt * 64 + ks * 32;
    gload16(Ag0 + kc, &As[buf][ks * 8192 + w * 512]);
    gload16(Ag1 + kc, &As[buf][ks * 8192 + 4096 + w * 512]);
  };
  auto stB = [&](int buf, int kt, int ks){
    int kc = kt * 64 + ks * 32;
    gload16(Bg0 + kc, &Bs[buf][ks * 8192 + w * 512]);
    gload16(Bg1 + kc, &Bs[buf][ks * 8192 + 4096 + w * 512]);
  };

  stA(0, 0, 0); stB(0, 0, 0); stA(0, 0, 1); stB(0, 0, 1);

  for (int t = 0; t < KT; t++){
    int c = t & 1, nb = c ^ 1;
    bool pf = (t + 1 < KT);
    asm volatile("s_waitcnt vmcnt(4)" ::: "memory");
    __builtin_amdgcn_s_barrier();

#pragma unroll
    for (int ks = 0; ks < 2; ks++){
      if (ks == 1){
        if (pf) asm volatile("s_waitcnt vmcnt(4)" ::: "memory");
        else    asm volatile("s_waitcnt vmcnt(0)" ::: "memory");
        __builtin_amdgcn_s_barrier();
      }
      if (pf){ if (ks == 0) stA(nb, t + 1, 0); else stA(nb, t + 1, 1); }
      bf16x8 fa[8], fb[2];
#pragma unroll
      for (int m = 0; m < 8; m++){
        int row = wm * 128 + m * 16 + (lane & 15);
        int slot = (lane >> 4) ^ ((row >> 1) & 3);
        fa[m] = *(const bf16x8*)(&As[c][ks * 8192 + row * 32 + slot * 8]);
      }
#pragma unroll
      for (int nn = 0; nn < 2; nn++){
        int row = wn * 64 + nn * 16 + (lane & 15);
        int slot = (lane >> 4) ^ ((row >> 1) & 3);
        fb[nn] = *(const bf16x8*)(&Bs[c][ks * 8192 + row * 32 + slot * 8]);
      }
      __builtin_amdgcn_s_setprio(1);
#pragma unroll
      for (int m = 0; m < 8; m++)
#pragma unroll
        for (int nn = 0; nn < 2; nn++)
          acc[m][nn] = __builtin_amdgcn_mfma_f32_16x16x32_bf16(fa[m], fb[nn], acc[m][nn], 0, 0, 0);
      __builtin_amdgcn_s_setprio(0);
      if (pf){ if (ks == 0) stB(nb, t + 1, 0); else stB(nb, t + 1, 1); }
#pragma unroll
      for (int nn = 0; nn < 2; nn++){
        int row = wn * 64 + 32 + nn * 16 + (lane & 15);
        int slot = (lane >> 4) ^ ((row >> 1) & 3);
        fb[nn] = *(const bf16x8*)(&Bs[c][ks * 8192 + row * 32 + slot * 8]);
      }
      __builtin_amdgcn_s_setprio(1);
#pragma unroll
      for (int m = 0; m < 8; m++)
#pragma unroll
        for (int nn = 0; nn < 2; nn++)
          acc[m][2 + nn] = __builtin_amdgcn_mfma_f32_16x16x32_bf16(fa[m], fb[nn], acc[m][2 + nn], 0, 0, 0);
      __builtin_amdgcn_s_setprio(0);
    }
  }

#pragma unroll
  for (int m = 0; m < 8; m++){
    int rowb = m0 + wm * 128 + m * 16 + ((lane >> 4) << 2);
#pragma unroll
    for (int n = 0; n < 4; n++){
      int col = n0 + wn * 64 + n * 16 + (lane & 15);
      float bv = bias[col];
#pragma unroll
      for (int r = 0; r < 4; r++)
        outp[(size_t)(rowb + r) * N + col] = f2b(acc[m][n][r] + bv);
    }
  }
}

// ---------------- FAVOR phi v2 (MFMA) + fused kv/ksum in K-blocks ----------------
__global__ __launch_bounds__(256) void phi2(const u16* __restrict__ qb, const u16* __restrict__ kb,
                                            const u16* __restrict__ omT,
                                            u16* __restrict__ Qp, u16* __restrict__ Kp,
                                            const u16* __restrict__ vt,
                                            u16* __restrict__ kv, float* __restrict__ ksum, int fuse){
  __shared__ __align__(16) u16 qs[128 * 64];
  __shared__ __align__(16) u16 wl[64 * 64];
  __shared__ __align__(16) u16 ph[128 * 128];
  __shared__ __align__(16) u16 Vst[64 * 128];
  __shared__ float part[2][128];
  __shared__ float nrm[128];
  int tid = threadIdx.x, w = tid >> 6, lane = tid & 63;
  int blk = blockIdx.x;
  const u16* src; u16* dst; int row0;
  bool isK = (blk >= 1024);
  if (!isK){ src = qb; dst = Qp; row0 = blk * 128; }
  else     { src = kb; dst = Kp; row0 = (blk - 1024) * 128; }
  const u16* g = src + (size_t)row0 * 64;
#pragma unroll
  for (int i = 0; i < 4; i++){
    int id = tid * 4 + i;
    int r = id >> 3, kc = id & 7;
    *(bf16x8*)(qs + r * 64 + ((kc ^ (r & 7)) << 3)) = *(const bf16x8*)(g + r * 64 + kc * 8);
  }
#pragma unroll
  for (int i = 0; i < 2; i++){
    int id = tid * 2 + i;
    int m = id >> 3, kc = id & 7;
    *(bf16x8*)(wl + m * 64 + ((kc ^ (m & 7)) << 3)) = *(const bf16x8*)(omT + id * 8);
  }
  __syncthreads();
  {
    int r = tid & 127, half = tid >> 7;
    float s = 0.f;
#pragma unroll
    for (int j = 0; j < 4; j++){
      int kc = half * 4 + j;
      bf16x8 v = *(const bf16x8*)(qs + r * 64 + ((kc ^ (r & 7)) << 3));
#pragma unroll
      for (int e = 0; e < 8; e++){ float f = b2f((u16)v[e]); s += f * f; }
    }
    part[half][r] = s;
  }
  __syncthreads();
  if (tid < 128) nrm[tid] = 0.0625f * (part[0][tid] + part[1][tid]);
  __syncthreads();
  f32x4 acc[2][4] = {};
#pragma unroll
  for (int kt = 0; kt < 2; kt++){
    int kc = kt * 4 + (lane >> 4);
    bf16x8 fa[2], fb[4];
#pragma unroll
    for (int mt = 0; mt < 2; mt++){
      int r = w * 32 + mt * 16 + (lane & 15);
      fa[mt] = *(const bf16x8*)(qs + r * 64 + ((kc ^ (r & 7)) << 3));
    }
#pragma unroll
    for (int nt = 0; nt < 4; nt++){
      int m = nt * 16 + (lane & 15);
      fb[nt] = *(const bf16x8*)(wl + m * 64 + ((kc ^ (m & 7)) << 3));
    }
#pragma unroll
    for (int mt = 0; mt < 2; mt++)
#pragma unroll
      for (int nt = 0; nt < 4; nt++)
        acc[mt][nt] = __builtin_amdgcn_mfma_f32_16x16x32_bf16(fa[mt], fb[nt], acc[mt][nt], 0, 0, 0);
  }
  const float LNC = -2.4260151319598086f;   // ln(128^-0.5)
#pragma unroll
  for (int mt = 0; mt < 2; mt++)
#pragma unroll
    for (int nt = 0; nt < 4; nt++)
#pragma unroll
      for (int r4 = 0; r4 < 4; r4++){
        int r = w * 32 + mt * 16 + ((lane >> 4) << 2) + r4;
        int m = nt * 16 + (lane & 15);
        float u = acc[mt][nt][r4];
        float nr = nrm[r];
        ph[r * 128 + m]      = f2b(__expf(u - nr + LNC));
        ph[r * 128 + 64 + m] = f2b(__expf(-u - nr + LNC));
      }
  // stage V^T chunk for fused kv (disjoint LDS; visible after the same barrier)
  int bh = 0, cch = 0;
  if (isK && fuse){
    int rr0 = blk - 1024;
    bh = rr0 >> 4; cch = rr0 & 15;
    const u16* vtc = vt + (size_t)bh * 131072 + cch * 128;
#pragma unroll
    for (int i = 0; i < 4; i++){
      int id = tid * 4 + i;
      int d = id >> 4, mc = id & 15;
      *(bf16x8*)(Vst + d * 128 + mc * 8) = *(const bf16x8*)(vtc + (size_t)d * 2048 + mc * 8);
    }
  }
  __syncthreads();
  u16* go = dst + (size_t)row0 * 128;
#pragma unroll
  for (int i = 0; i < 8; i++){
    int id = i * 256 + tid;
    *(bf16x8*)(go + id * 8) = *(const bf16x8*)(ph + id * 8);
  }
  if (isK && fuse){
    int tm = tid & 15, td = tid >> 4;
    int mbase = tm * 8, dbase = td * 4;
    float acc2[8][4] = {};
    float ks[8] = {};
    for (int i = 0; i < 128; i++){
      bf16x8 kk = *(const bf16x8*)(ph + i * 128 + mbase);
      float kf[8];
#pragma unroll
      for (int e = 0; e < 8; e++) kf[e] = b2f((u16)kk[e]);
      float vf[4];
#pragma unroll
      for (int e = 0; e < 4; e++) vf[e] = b2f(Vst[(dbase + e) * 128 + i]);
#pragma unroll
      for (int a = 0; a < 8; a++){
        ks[a] += kf[a];
#pragma unroll
        for (int bb = 0; bb < 4; bb++) acc2[a][bb] += kf[a] * vf[bb];
      }
    }
    u16* kvout = kv + ((size_t)bh * 16 + cch) * 8192;
#pragma unroll
    for (int a = 0; a < 8; a++)
#pragma unroll
      for (int bb = 0; bb < 4; bb++)
        kvout[(size_t)(dbase + bb) * 128 + mbase + a] = f2b(acc2[a][bb]);
    if (td == 0){
      float* kso = ksum + ((size_t)bh * 16 + cch) * 128;
#pragma unroll
      for (int a = 0; a < 8; a++) kso[mbase + a] = ks[a];
    }
  }
}

// ---------------- per-chunk kv^T[d][m] (bf16), ksum f32 (fallback when not fused) ----------------
__global__ __launch_bounds__(256) void kvchunk(const u16* __restrict__ Kp, const u16* __restrict__ vt,
                                               u16* __restrict__ kv, float* __restrict__ ksum){
  __shared__ __align__(16) u16 Ks[128 * 128];
  __shared__ __align__(16) u16 Vst[64 * 128];
  int blk = blockIdx.x; int bh = blk >> 4, c = blk & 15;
  int tid = threadIdx.x;
  size_t base = (size_t)bh * 2048 + c * 128;
  const u16* Kc = Kp + base * 128;
  const u16* vtc = vt + (size_t)bh * 64 * 2048 + c * 128;
  {
    int j = tid >> 1, half = tid & 1;
#pragma unroll
    for (int i = 0; i < 8; i++)
      *(bf16x8*)(Ks + j * 128 + half * 64 + i * 8) = *(const bf16x8*)(Kc + j * 128 + half * 64 + i * 8);
#pragma unroll
    for (int i = 0; i < 4; i++){
      int id = tid * 4 + i;
      int d = id >> 4, mc = id & 15;
      *(bf16x8*)(Vst + d * 128 + mc * 8) = *(const bf16x8*)(vtc + (size_t)d * 2048 + mc * 8);
    }
  }
  __syncthreads();
  int tm = tid & 15, td = tid >> 4;
  int mbase = tm * 8, dbase = td * 4;
  float acc[8][4] = {};
  float ks[8] = {};
  for (int i = 0; i < 128; i++){
    bf16x8 kk = *(const bf16x8*)(Ks + i * 128 + mbase);
    float kf[8];
#pragma unroll
    for (int e = 0; e < 8; e++) kf[e] = b2f((u16)kk[e]);
    float vf[4];
#pragma unroll
    for (int e = 0; e < 4; e++) vf[e] = b2f(Vst[(dbase + e) * 128 + i]);
#pragma unroll
    for (int a = 0; a < 8; a++){
      ks[a] += kf[a];
#pragma unroll
      for (int bb = 0; bb < 4; bb++) acc[a][bb] += kf[a] * vf[bb];
    }
  }
  u16* kvout = kv + ((size_t)bh * 16 + c) * 8192;
#pragma unroll
  for (int a = 0; a < 8; a++)
#pragma unroll
    for (int bb = 0; bb < 4; bb++)
      kvout[(size_t)(dbase + bb) * 128 + mbase + a] = f2b(acc[a][bb]);
  if (td == 0){
    float* kso = ksum + ((size_t)bh * 16 + c) * 128;
#pragma unroll
    for (int a = 0; a < 8; a++) kso[mbase + a] = ks[a];
  }
}

// ---------------- exclusive prefix over chunks (in place; kv bf16, f32 carry) ----------------
__global__ __launch_bounds__(256) void kvscan(u16* __restrict__ kv, float* __restrict__ ksum){
  int bh = blockIdx.x;
  int p = blockIdx.y;
  int tid = threadIdx.x;
  if (p < 8){
    size_t base = (size_t)bh * 16 * 8192;
    int idx0 = p * 1024 + tid;
    for (int rep = 0; rep < 4; rep++){
      int idx = idx0 + rep * 256;
      float run = 0.f;
#pragma unroll
      for (int c = 0; c < 16; c++){
        size_t off = base + (size_t)c * 8192 + idx;
        float v = b2f(kv[off]); kv[off] = f2b(run); run += v;
      }
    }
  } else if (tid < 128){
    size_t base = (size_t)bh * 16 * 128;
    float run = 0.f;
#pragma unroll
    for (int c = 0; c < 16; c++){
      size_t off = base + c * 128 + tid;
      float v = ksum[off]; ksum[off] = run; run += v;
    }
  }
}

// ---------------- MFMA fused attention (kv_pre bf16) ----------------
__global__ __launch_bounds__(512) void attn_fused(const u16* __restrict__ Qp, const u16* __restrict__ Kp,
                                                  const u16* __restrict__ vt, const u16* __restrict__ kvp,
                                                  const float* __restrict__ ksum, u16* __restrict__ aout){
  __shared__ __align__(16) u16 sm[53248];
  int blk = blockIdx.x, bh = blk >> 4, c = blk & 15;
  int b = bh >> 4, h = bh & 15;
  int tid = threadIdx.x, w = tid >> 6, lane = tid & 63;
  size_t base = (size_t)bh * 2048 + c * 128;
  const u16* Qc = Qp + base * 128;
  const u16* Kc = Kp + base * 128;
  const u16* vtc = vt + (size_t)bh * 64 * 2048 + c * 128;
  const u16* kvc = kvp + ((size_t)bh * 16 + c) * 8192;
  const float* ksc = ksum + ((size_t)bh * 16 + c) * 128;
  u16* Qs = sm;
  u16* Ks = sm + 16384;
  u16* B2 = sm + 32768;

#pragma unroll
  for (int i = 0; i < 4; i++){
    int id = tid * 4 + i;
    int r = id >> 4, kc = id & 15;
    int swo = (kc ^ (r & 15)) << 3;
    *(bf16x8*)(Qs + r * 128 + swo) = *(const bf16x8*)(Qc + (size_t)r * 128 + kc * 8);
    *(bf16x8*)(Ks + r * 128 + swo) = *(const bf16x8*)(Kc + (size_t)r * 128 + kc * 8);
  }
#pragma unroll
  for (int i = 0; i < 2; i++){
    int id = tid * 2 + i;
    int d = id >> 4, kc = id & 15;
    *(bf16x8*)(B2 + d * 256 + ((kc ^ (d & 31)) << 3)) = *(const bf16x8*)(vtc + (size_t)d * 2048 + kc * 8);
  }
#pragma unroll
  for (int i = 0; i < 2; i++){
    int id = tid * 2 + i;
    int d = id >> 4, mc = id & 15;
    bf16x8 pk = *(const bf16x8*)(kvc + d * 128 + mc * 8);
    int kc = 16 + mc;
    *(bf16x8*)(B2 + d * 256 + ((kc ^ (d & 31)) << 3)) = pk;
  }
  {
    int row = 64 + (tid >> 5), kc = tid & 31;
    bf16x8 pk = {};
    if (row == 64){
      if (kc < 16){
#pragma unroll
        for (int e = 0; e < 8; e++) pk[e] = (short)0x3F80;
      } else {
        const float* s8 = ksc + (kc - 16) * 8;
        float4 f0 = *(const float4*)(s8);
        float4 f1 = *(const float4*)(s8 + 4);
        pk[0] = (short)f2b(f0.x); pk[1] = (short)f2b(f0.y); pk[2] = (short)f2b(f0.z); pk[3] = (short)f2b(f0.w);
        pk[4] = (short)f2b(f1.x); pk[5] = (short)f2b(f1.y); pk[6] = (short)f2b(f1.z); pk[7] = (short)f2b(f1.w);
      }
    }
    *(bf16x8*)(B2 + row * 256 + ((kc ^ (row & 31)) << 3)) = pk;
  }
  __syncthreads();

  int wm = w >> 2, wn = w & 3;
  f32x4 acc1[4][2] = {};
#pragma unroll
  for (int kk = 0; kk < 4; kk++){
    int kc = kk * 4 + (lane >> 4);
    bf16x8 fa[4], fb[2];
#pragma unroll
    for (int m = 0; m < 4; m++){
      int row = wm * 64 + m * 16 + (lane & 15);
      fa[m] = *(const bf16x8*)(Qs + row * 128 + ((kc ^ (row & 15)) << 3));
    }
#pragma unroll
    for (int n = 0; n < 2; n++){
      int row = wn * 32 + n * 16 + (lane & 15);
      fb[n] = *(const bf16x8*)(Ks + row * 128 + ((kc ^ (row & 15)) << 3));
    }
#pragma unroll
    for (int m = 0; m < 4; m++)
#pragma unroll
      for (int n = 0; n < 2; n++)
        acc1[m][n] = __builtin_amdgcn_mfma_f32_16x16x32_bf16(fa[m], fb[n], acc1[m][n], 0, 0, 0);
  }
  __syncthreads();

#pragma unroll
  for (int m = 0; m < 4; m++)
#pragma unroll
    for (int n = 0; n < 2; n++)
#pragma unroll
      for (int r = 0; r < 4; r++){
        int i = wm * 64 + m * 16 + ((lane >> 4) << 2) + r;
        int j = wn * 32 + n * 16 + (lane & 15);
        float v = (j <= i) ? acc1[m][n][r] : 0.f;
        Ks[i * 128 + (((j >> 3) ^ (i & 15)) << 3) + (j & 7)] = f2b(v);
      }
  __syncthreads();

  f32x4 acc2[5] = {};
#pragma unroll
  for (int kk = 0; kk < 8; kk++){
    int kc = kk * 4 + (lane >> 4);
    int rowA = w * 16 + (lane & 15);
    bf16x8 fa2;
    if (kk < 4) fa2 = *(const bf16x8*)(Ks + rowA * 128 + ((kc ^ (rowA & 15)) << 3));
    else        fa2 = *(const bf16x8*)(Qs + rowA * 128 + (((kc - 16) ^ (rowA & 15)) << 3));
#pragma unroll
    for (int n = 0; n < 5; n++){
      int d = n * 16 + (lane & 15);
      bf16x8 fb2 = *(const bf16x8*)(B2 + d * 256 + ((kc ^ (d & 31)) << 3));
      acc2[n] = __builtin_amdgcn_mfma_f32_16x16x32_bf16(fa2, fb2, acc2[n], 0, 0, 0);
    }
  }

  float dd[4];
#pragma unroll
  for (int r = 0; r < 4; r++) dd[r] = __shfl(acc2[4][r], lane & 48) + 1e-6f;
  size_t obase = ((size_t)b * 2048 + c * 128) * 1024 + (size_t)h * 64;
#pragma unroll
  for (int n = 0; n < 4; n++)
#pragma unroll
    for (int r = 0; r < 4; r++){
      int i = w * 16 + ((lane >> 4) << 2) + r;
      int d = n * 16 + (lane & 15);
      aout[obase + (size_t)i * 1024 + d] = f2b(acc2[n][r] / dd[r]);
    }
}

// ---------------- universal residual-add + LayerNorm ----------------
__global__ __launch_bounds__(256) void lnr(const float* X1f, const u16* X1b,
                                           const u16* P0, const u16* P1,
                                           const float* __restrict__ g, const float* __restrict__ bb,
                                           float* outf, u16* outb, u16* outb2){
  __shared__ float red[2][4];
  int row = blockIdx.x, tid = threadIdx.x, w = tid >> 6, lane = tid & 63;
  size_t ro = (size_t)row * 1024 + tid * 4;
  float x0, x1, x2, x3;
  if (X1f){
    float4 a = *(const float4*)(X1f + ro);
    x0 = a.x; x1 = a.y; x2 = a.z; x3 = a.w;
  } else {
    ushort4 a = *(const ushort4*)(X1b + ro);
    x0 = b2f(a.x); x1 = b2f(a.y); x2 = b2f(a.z); x3 = b2f(a.w);
  }
  {
    ushort4 p0 = *(const ushort4*)(P0 + ro);
    x0 += b2f(p0.x); x1 += b2f(p0.y); x2 += b2f(p0.z); x3 += b2f(p0.w);
  }
  if (P1){
    ushort4 p1 = *(const ushort4*)(P1 + ro);
    x0 += b2f(p1.x); x1 += b2f(p1.y); x2 += b2f(p1.z); x3 += b2f(p1.w);
  }
  float s1 = x0 + x1 + x2 + x3;
  float s2 = x0 * x0 + x1 * x1 + x2 * x2 + x3 * x3;
#pragma unroll
  for (int off = 32; off; off >>= 1){ s1 += __shfl_xor(s1, off); s2 += __shfl_xor(s2, off); }
  if (lane == 0){ red[0][w] = s1; red[1][w] = s2; }
  __syncthreads();
  float t1 = red[0][0] + red[0][1] + red[0][2] + red[0][3];
  float t2 = red[1][0] + red[1][1] + red[1][2] + red[1][3];
  float mu = t1 * (1.f / 1024.f);
  float var = t2 * (1.f / 1024.f) - mu * mu;
  float rs = rsqrtf(var + 1e-5f);
  float4 gv = *(const float4*)(g + tid * 4);
  float4 bv = *(const float4*)(bb + tid * 4);
  float o0 = (x0 - mu) * rs * gv.x + bv.x;
  float o1 = (x1 - mu) * rs * gv.y + bv.y;
  float o2 = (x2 - mu) * rs * gv.z + bv.z;
  float o3 = (x3 - mu) * rs * gv.w + bv.w;
  if (outf) *(float4*)(outf + ro) = make_float4(o0, o1, o2, o3);
  ushort4 ob = make_ushort4(f2b(o0), f2b(o1), f2b(o2), f2b(o3));
  if (outb)  *(ushort4*)(outb + ro)  = ob;
  if (outb2) *(ushort4*)(outb2 + ro) = ob;
}

// ---------------- host ----------------
extern "C" void kernel_launch(void* const* d_in, const int* in_sizes, int n_in,
                              void* d_out, int out_size, void* d_ws, size_t ws_size,
                              hipStream_t stream){
  (void)in_sizes; (void)n_in;
  const float* x   = (const float*)d_in[0];
  const float* Wq  = (const float*)d_in[1];
  const float* bq  = (const float*)d_in[2];
  const float* Wk  = (const float*)d_in[3];
  const float* bk  = (const float*)d_in[4];
  const float* Wv  = (const float*)d_in[5];
  const float* bv  = (const float*)d_in[6];
  const float* Wo  = (const float*)d_in[7];
  const float* bo  = (const float*)d_in[8];
  const float* om  = (const float*)d_in[9];
  const float* g1  = (const float*)d_in[10];
  const float* be1 = (const float*)d_in[11];
  const float* W1  = (const float*)d_in[12];
  const float* bf1 = (const float*)d_in[13];
  const float* W2  = (const float*)d_in[14];
  const float* bf2 = (const float*)d_in[15];
  const float* g2  = (const float*)d_in[16];
  const float* be2 = (const float*)d_in[17];

  char* ws = (char*)d_ws;
  size_t off = 0;
  auto alloc = [&](size_t bytes) -> void* {
    void* p = ws + off; off += (bytes + 255) & ~(size_t)255; return p;
  };
  u16* Wcat = (u16*)alloc(3072ull * 1024 * 2);
  u16* Wot  = (u16*)alloc(1024ull * 1024 * 2);
  u16* W1t  = (u16*)alloc(4096ull * 1024 * 2);
  u16* W2t  = (u16*)alloc(1024ull * 4096 * 2);
  u16* omT  = (u16*)alloc(64ull * 64 * 2);
  float* bcat = (float*)alloc(6ull * 3072 * 4);
  float* zbuf = (float*)alloc(1024 * 4);
  u16* Xb  = (u16*)alloc(8192ull * 1024 * 2);
  u16* qb  = (u16*)alloc(131072ull * 64 * 2);   // contiguous qb|kb|vt|Qp for ybuf alias
  u16* kb  = (u16*)alloc(131072ull * 64 * 2);
  u16* vt  = (u16*)alloc(131072ull * 64 * 2);
  u16* Qp  = (u16*)alloc(131072ull * 128 * 2);
  u16* Kp  = (u16*)alloc(131072ull * 128 * 2);
  float* ksum = (float*)alloc(64ull * 16 * 128 * 4);
  size_t base_end = off;

  // dedicated 16MB kv buffer enables phi2-fused kvchunk (gated on ws_size)
  u16* kvded = (u16*)alloc(64ull * 16 * 8192 * 2);
  bool fuse = (off <= ws_size);
  if (!fuse){ off = base_end; kvded = qb; }     // fallback: kv in qb + separate kvchunk

  if (off > ws_size){
    fillv<<<(out_size + 255) / 256, 256, 0, stream>>>((float*)d_out, (float)(ws_size >> 20), out_size);
    return;
  }

  u16*  ybuf   = qb;                    // FFN intermediate bf16 [8192][4096] over qb..Qp[0:16MB]
  u16*  wooutb = Qp;                    // Wo out bf16 16MB (Qp dead after attn)
  u16*  w2outb = Qp + 8388608;          // W2 partial kz=0, bf16 16MB
  u16*  w2p1   = Kp + 8388608;          // W2 partial kz=1, bf16 16MB (Kp[16:32], dead after attn)
  u16*  residb = (u16*)d_out;           // bf16 residual stream in d_out[0:16MB]; final layer writes f32

  cvt16<<<8192, 256, 0, stream>>>(x, Xb);
  catbias<<<72, 256, 0, stream>>>(bq, bk, bv, bcat);
  fillv<<<4, 256, 0, stream>>>(zbuf, 0.f, 1024);

  for (int l = 0; l < 6; l++){
    size_t o1k = (size_t)l * 1024 * 1024;
    size_t o4k = (size_t)l * 4096 * 1024;
    wtrans7<<<12292, 256, 0, stream>>>(Wq + o1k, Wk + o1k, Wv + o1k, Wo + o1k,
                                       W1 + o4k, W2 + o4k, om + (size_t)l * 4096,
                                       Wcat, Wot, W1t, W2t, omT);

    gemm_bt<5><<<dim3(24, 64), 256, 0, stream>>>(Xb, Wcat, bcat + l * 3072, qb, 8192, 3072, 1024, 1024, 1024);
    phi2<<<2048, 256, 0, stream>>>(qb, kb, omT, Qp, Kp, vt, kvded, ksum, fuse ? 1 : 0);
    if (!fuse) kvchunk<<<1024, 256, 0, stream>>>(Kp, vt, kvded, ksum);
    kvscan<<<dim3(64, 9), 256, 0, stream>>>(kvded, ksum);
    attn_fused<<<1024, 512, 0, stream>>>(Qp, Kp, vt, kvded, ksum, Xb);
    gemm_bt<6><<<dim3(8, 64), 256, 0, stream>>>(Xb, Wot, bo + l * 1024, wooutb, 8192, 1024, 1024, 1024, 1024);
    lnr<<<8192, 256, 0, stream>>>(l == 0 ? x : nullptr, l == 0 ? nullptr : residb,
                                  wooutb, nullptr, g1 + l * 1024, be1 + l * 1024,
                                  nullptr, Xb, nullptr);
    gemm8p<2><<<dim3(16, 32), 512, 0, stream>>>(Xb, W1t, bf1 + l * 4096, ybuf, 8192, 4096, 1024, 1024, 1024);
    gemm8pk<<<dim3(256), 512, 0, stream>>>(ybuf, W2t, bf2 + l * 1024, zbuf, w2outb, w2p1,
                                           8192, 1024, 2048, 4096, 4096);
    if (l == 5)
      lnr<<<8192, 256, 0, stream>>>(nullptr, Xb, w2outb, w2p1, g2 + l * 1024, be2 + l * 1024,
                                    (float*)d_out, nullptr, nullptr);
    else
      lnr<<<8192, 256, 0, stream>>>(nullptr, Xb, w2outb, w2p1, g2 + l * 1024, be2 + l * 1024,
                                    nullptr, Xb, residb);
  }
}

// Round 20
// 2291.724 us; speedup vs baseline: 1.1339x; 1.0321x over previous
//
#include <hip/hip_runtime.h>

typedef unsigned short u16;
typedef __attribute__((ext_vector_type(8))) short bf16x8;
typedef __attribute__((ext_vector_type(4))) float f32x4;

#define DEV __device__ __forceinline__

DEV float b2f(u16 h){ return __uint_as_float(((unsigned)h) << 16); }
DEV u16 f2b(float f){ unsigned u = __float_as_uint(f); u += 0x7FFFu + ((u >> 16) & 1u); return (u16)(u >> 16); }

DEV void gload16(const u16* g, u16* l){
  __builtin_amdgcn_global_load_lds((const __attribute__((address_space(1))) unsigned*)g,
                                   (__attribute__((address_space(3))) unsigned*)l, 16, 0, 0);
}

// ---------------- merged per-layer weight transpose: 7 tensors in one launch ----------------
__global__ __launch_bounds__(256) void wtrans7(const float* __restrict__ Wq, const float* __restrict__ Wk,
                                               const float* __restrict__ Wv, const float* __restrict__ Wo,
                                               const float* __restrict__ W1, const float* __restrict__ W2,
                                               const float* __restrict__ om,
                                               u16* __restrict__ Wcat, u16* __restrict__ Wot,
                                               u16* __restrict__ W1t, u16* __restrict__ W2t,
                                               u16* __restrict__ omT){
  __shared__ float tile[32][33];
  int id = blockIdx.x;
  const float* src; u16* dst; int K, N, kb, nb; float scale = 1.f;
  if (id < 4096){
    int wsel = id >> 10, loc = id & 1023;
    kb = loc >> 5; nb = loc & 31; K = 1024; N = 1024;
    src = (wsel == 0) ? Wq : (wsel == 1) ? Wk : (wsel == 2) ? Wv : Wo;
    dst = (wsel < 3) ? Wcat + (size_t)wsel * 1048576 : Wot;
  } else if (id < 8192){
    int loc = id - 4096;
    kb = loc & 31; nb = loc >> 5; K = 1024; N = 4096;
    src = W1; dst = W1t;
  } else if (id < 12288){
    int loc = id - 8192;
    kb = loc & 127; nb = loc >> 7; K = 4096; N = 1024;
    src = W2; dst = W2t;
  } else {
    int loc = id - 12288;
    kb = loc & 1; nb = loc >> 1; K = 64; N = 64;
    src = om; dst = omT; scale = 0.35355339059327373f;
  }
  int k0 = kb * 32, n0 = nb * 32;
  int tid = threadIdx.x;
#pragma unroll
  for (int i = 0; i < 4; i++){
    int idx = tid + i * 256;
    int r = idx >> 5, c = idx & 31;
    tile[r][c] = src[(size_t)(k0 + r) * N + n0 + c];
  }
  __syncthreads();
#pragma unroll
  for (int i = 0; i < 4; i++){
    int idx = tid + i * 256;
    int r = idx >> 5, c = idx & 31;
    dst[(size_t)(n0 + r) * K + k0 + c] = f2b(tile[c][r] * scale);
  }
}

// ---------------- f32 -> bf16 convert ----------------
__global__ __launch_bounds__(256) void cvt16(const float* __restrict__ src, u16* __restrict__ dst){
  size_t i = ((size_t)blockIdx.x * 256 + threadIdx.x) * 4;
  float4 f = *(const float4*)(src + i);
  ushort4 o = make_ushort4(f2b(f.x), f2b(f.y), f2b(f.z), f2b(f.w));
  *(ushort4*)(dst + i) = o;
}

// ---------------- bias concat (all layers): [6][3072] = bq|bk|bv ----------------
__global__ void catbias(const float* __restrict__ bq, const float* __restrict__ bk,
                        const float* __restrict__ bv, float* __restrict__ bcat){
  int i = blockIdx.x * 256 + threadIdx.x;
  if (i >= 6 * 3072) return;
  int l = i / 3072, j = i % 3072;
  float v = (j < 1024) ? bq[l * 1024 + j] : (j < 2048) ? bk[l * 1024 + j - 1024] : bv[l * 1024 + j - 2048];
  bcat[i] = v;
}

// ---------------- diagnostic / zero fill ----------------
__global__ void fillv(float* __restrict__ p, float v, int n){
  int i = blockIdx.x * 256 + threadIdx.x;
  if (i < n) p[i] = v;
}

// ---------------- 128^2 bf16 MFMA GEMM (gload_lds dbuf + counted vmcnt + XCD swizzle) ----------------
// EPI 2: relu bf16 [M,N] ; EPI 5: fused QKV ; EPI 6: bf16 [M,N]
DEV int swz(int r){ return (r & 3) ^ ((r >> 2) & 3); }

template<int EPI>
__global__ __launch_bounds__(256) void gemm_bt(const u16* __restrict__ A, const u16* __restrict__ Bt,
                                               const float* __restrict__ bias, void* __restrict__ outp,
                                               int M, int N, int K, int ldA, int ldB){
  __shared__ __align__(16) u16 As[2][4096];
  __shared__ __align__(16) u16 Bs[2][4096];
  const int tid = threadIdx.x;
  const int lane = tid & 63;
  const int w = tid >> 6;
  const int wm = w >> 1, wn = w & 1;
  int nx = gridDim.x;
  int nwg = nx * gridDim.y;
  int lin = blockIdx.y * nx + blockIdx.x;
  int cpx = nwg >> 3;
  int sw = (lin & 7) * cpx + (lin >> 3);
  const int m0 = (sw / nx) * 128;
  const int n0 = (sw % nx) * 128;

  int r0 = tid >> 2, c0 = tid & 3;
  int r1 = r0 + 64;
  int cs0 = c0 ^ swz(r0);
  int cs1 = c0 ^ swz(r1);
  const u16* ag0 = A + (size_t)(m0 + r0) * ldA + cs0 * 8;
  const u16* ag1 = A + (size_t)(m0 + r1) * ldA + cs1 * 8;
  const u16* bg0 = Bt + (size_t)(n0 + r0) * ldB + cs0 * 8;
  const u16* bg1 = Bt + (size_t)(n0 + r1) * ldB + cs1 * 8;

  f32x4 acc[4][4] = {};
  const int KT = K >> 5;

  gload16(ag0, &As[0][w * 512]);
  gload16(ag1, &As[0][2048 + w * 512]);
  gload16(bg0, &Bs[0][w * 512]);
  gload16(bg1, &Bs[0][2048 + w * 512]);

  for (int kt = 0; kt < KT; kt++){
    int cur = kt & 1;
    if (kt + 1 < KT){
      int ko = (kt + 1) << 5;
      gload16(ag0 + ko, &As[cur ^ 1][w * 512]);
      gload16(ag1 + ko, &As[cur ^ 1][2048 + w * 512]);
      gload16(bg0 + ko, &Bs[cur ^ 1][w * 512]);
      gload16(bg1 + ko, &Bs[cur ^ 1][2048 + w * 512]);
      asm volatile("s_waitcnt vmcnt(4)" ::: "memory");
    } else {
      asm volatile("s_waitcnt vmcnt(0)" ::: "memory");
    }
    __builtin_amdgcn_s_barrier();
    bf16x8 fa[4], fb[4];
#pragma unroll
    for (int m = 0; m < 4; m++){
      int row = wm * 64 + m * 16 + (lane & 15);
      int cc = (lane >> 4) ^ swz(row);
      fa[m] = *(const bf16x8*)(&As[cur][row * 32 + cc * 8]);
    }
#pragma unroll
    for (int n = 0; n < 4; n++){
      int row = wn * 64 + n * 16 + (lane & 15);
      int cc = (lane >> 4) ^ swz(row);
      fb[n] = *(const bf16x8*)(&Bs[cur][row * 32 + cc * 8]);
    }
#pragma unroll
    for (int m = 0; m < 4; m++)
#pragma unroll
      for (int n = 0; n < 4; n++)
        acc[m][n] = __builtin_amdgcn_mfma_f32_16x16x32_bf16(fa[m], fb[n], acc[m][n], 0, 0, 0);
    asm volatile("s_waitcnt lgkmcnt(0)" ::: "memory");
    __builtin_amdgcn_s_barrier();
  }

#pragma unroll
  for (int m = 0; m < 4; m++){
    int rowb = m0 + wm * 64 + m * 16 + ((lane >> 4) << 2);
#pragma unroll
    for (int n = 0; n < 4; n++){
      int col = n0 + wn * 64 + n * 16 + (lane & 15);
      float bv = bias[col];
      if (EPI == 5 && col >= 2048){
        int cv = col - 2048, hh = cv >> 6, dh = cv & 63;
        int bIdx = rowb >> 11, s4 = rowb & 2047;
        ushort4 pk = make_ushort4(f2b(acc[m][n][0] + bv), f2b(acc[m][n][1] + bv),
                                  f2b(acc[m][n][2] + bv), f2b(acc[m][n][3] + bv));
        *(ushort4*)&((u16*)outp + 16777216)[((size_t)(bIdx * 16 + hh) * 64 + dh) * 2048 + s4] = pk;
      } else {
#pragma unroll
        for (int r = 0; r < 4; r++){
          float v = acc[m][n][r] + bv;
          int rr = rowb + r;
          if (EPI == 5){
            u16* dst0 = (u16*)outp + (col < 1024 ? 0 : 8388608);
            int cv = col & 1023, hh = cv >> 6, dh = cv & 63;
            int bIdx = rr >> 11, s = rr & 2047;
            dst0[(((size_t)(bIdx * 16 + hh) * 2048 + s) << 6) + dh] = f2b(v);
          } else if (EPI == 2){
            ((u16*)outp)[(size_t)rr * N + col] = f2b(v > 0.f ? v : 0.f);
          } else {
            ((u16*)outp)[(size_t)rr * N + col] = f2b(v);
          }
        }
      }
    }
  }
}

// ---------------- 8-phase 256^2 GEMM (m201 template): compile-time KT, counted vmcnt ----------------
// EPI 2: relu bf16 ; EPI 6: bf16   (scalar epilogue)
// XCD mapping: squarer 8x8 tile chunk per XCD when grid==(16,32) (W1 case)
template<int EPI, int KT>
__global__ __launch_bounds__(512, 1) void gemm8p(const u16* __restrict__ A, const u16* __restrict__ Bt,
                                                 const float* __restrict__ bias, void* __restrict__ outp,
                                                 int M, int N, int ldA, int ldB){
  __shared__ __align__(16) u16 As[2][16384];
  __shared__ __align__(16) u16 Bs[2][16384];
  const int tid = threadIdx.x;
  const int lane = tid & 63;
  const int w = tid >> 6;
  const int wm = w >> 2, wn = w & 3;
  int nx = gridDim.x;
  int nwg = nx * gridDim.y;
  int lin = blockIdx.y * nx + blockIdx.x;
  int m0, n0;
  if (nx == 16 && gridDim.y == 32){
    int xcd = lin & 7, loc = lin >> 3;
    int mt = (xcd >> 1) * 8 + (loc >> 3);
    int nt = (xcd & 1) * 8 + (loc & 7);
    m0 = mt * 256; n0 = nt * 256;
  } else {
    int cpx = nwg >> 3;
    int sw = (lin & 7) * cpx + (lin >> 3);
    m0 = (sw / nx) * 256;
    n0 = (sw % nx) * 256;
  }

  const int id1 = 512 + tid;
  const int r0 = tid >> 2, c20 = tid & 3;
  const int r1 = id1 >> 2, c21 = id1 & 3;
  const int cs0 = c20 ^ ((r0 >> 1) & 3);
  const int cs1 = c21 ^ ((r1 >> 1) & 3);
  const u16* Ag0 = A + (size_t)(m0 + r0) * ldA + cs0 * 8;
  const u16* Ag1 = A + (size_t)(m0 + r1) * ldA + cs1 * 8;
  const u16* Bg0 = Bt + (size_t)(n0 + r0) * ldB + cs0 * 8;
  const u16* Bg1 = Bt + (size_t)(n0 + r1) * ldB + cs1 * 8;

  f32x4 acc[8][4] = {};

  auto stA = [&](int buf, int kt, int ks){
    int kc = kt * 64 + ks * 32;
    gload16(Ag0 + kc, &As[buf][ks * 8192 + w * 512]);
    gload16(Ag1 + kc, &As[buf][ks * 8192 + 4096 + w * 512]);
  };
  auto stB = [&](int buf, int kt, int ks){
    int kc = kt * 64 + ks * 32;
    gload16(Bg0 + kc, &Bs[buf][ks * 8192 + w * 512]);
    gload16(Bg1 + kc, &Bs[buf][ks * 8192 + 4096 + w * 512]);
  };

  stA(0, 0, 0); stB(0, 0, 0); stA(0, 0, 1); stB(0, 0, 1);

  for (int t = 0; t < KT; t++){
    int c = t & 1, nb = c ^ 1;
    bool pf = (t + 1 < KT);
    asm volatile("s_waitcnt vmcnt(4)" ::: "memory");
    __builtin_amdgcn_s_barrier();

#pragma unroll
    for (int ks = 0; ks < 2; ks++){
      if (ks == 1){
        if (pf) asm volatile("s_waitcnt vmcnt(4)" ::: "memory");
        else    asm volatile("s_waitcnt vmcnt(0)" ::: "memory");
        __builtin_amdgcn_s_barrier();
      }
      if (pf){ if (ks == 0) stA(nb, t + 1, 0); else stA(nb, t + 1, 1); }
      bf16x8 fa[8], fb[2];
#pragma unroll
      for (int m = 0; m < 8; m++){
        int row = wm * 128 + m * 16 + (lane & 15);
        int slot = (lane >> 4) ^ ((row >> 1) & 3);
        fa[m] = *(const bf16x8*)(&As[c][ks * 8192 + row * 32 + slot * 8]);
      }
#pragma unroll
      for (int nn = 0; nn < 2; nn++){
        int row = wn * 64 + nn * 16 + (lane & 15);
        int slot = (lane >> 4) ^ ((row >> 1) & 3);
        fb[nn] = *(const bf16x8*)(&Bs[c][ks * 8192 + row * 32 + slot * 8]);
      }
      __builtin_amdgcn_s_setprio(1);
#pragma unroll
      for (int m = 0; m < 8; m++)
#pragma unroll
        for (int nn = 0; nn < 2; nn++)
          acc[m][nn] = __builtin_amdgcn_mfma_f32_16x16x32_bf16(fa[m], fb[nn], acc[m][nn], 0, 0, 0);
      __builtin_amdgcn_s_setprio(0);
      if (pf){ if (ks == 0) stB(nb, t + 1, 0); else stB(nb, t + 1, 1); }
#pragma unroll
      for (int nn = 0; nn < 2; nn++){
        int row = wn * 64 + 32 + nn * 16 + (lane & 15);
        int slot = (lane >> 4) ^ ((row >> 1) & 3);
        fb[nn] = *(const bf16x8*)(&Bs[c][ks * 8192 + row * 32 + slot * 8]);
      }
      __builtin_amdgcn_s_setprio(1);
#pragma unroll
      for (int m = 0; m < 8; m++)
#pragma unroll
        for (int nn = 0; nn < 2; nn++)
          acc[m][2 + nn] = __builtin_amdgcn_mfma_f32_16x16x32_bf16(fa[m], fb[nn], acc[m][2 + nn], 0, 0, 0);
      __builtin_amdgcn_s_setprio(0);
    }
  }

#pragma unroll
  for (int m = 0; m < 8; m++){
    int rowb = m0 + wm * 128 + m * 16 + ((lane >> 4) << 2);
#pragma unroll
    for (int n = 0; n < 4; n++){
      int col = n0 + wn * 64 + n * 16 + (lane & 15);
      float bv = bias[col];
#pragma unroll
      for (int r = 0; r < 4; r++){
        float v = acc[m][n][r] + bv;
        int rr = rowb + r;
        if (EPI == 2) ((u16*)outp)[(size_t)rr * N + col] = f2b(v > 0.f ? v : 0.f);
        else          ((u16*)outp)[(size_t)rr * N + col] = f2b(v);
      }
    }
  }
}

// ---------------- 8-phase 256^2 split-K GEMM: compile-time KT, 256 blocks, bf16 partials ----------------
template<int KT>
__global__ __launch_bounds__(512, 1) void gemm8pk(const u16* __restrict__ A, const u16* __restrict__ Bt,
                                                  const float* __restrict__ bias0, const float* __restrict__ bias1,
                                                  u16* __restrict__ out0, u16* __restrict__ out1,
                                                  int M, int N, int Khalf, int ldA, int ldB){
  __shared__ __align__(16) u16 As[2][16384];
  __shared__ __align__(16) u16 Bs[2][16384];
  const int tid = threadIdx.x;
  const int lane = tid & 63;
  const int w = tid >> 6;
  const int wm = w >> 2, wn = w & 3;
  int lin = blockIdx.x;               // 256 blocks
  int cpx = gridDim.x >> 3;
  int sw = (lin & 7) * cpx + (lin >> 3);
  const int kz = sw & 1;
  const int t2 = sw >> 1;
  const int n0 = (t2 & 3) * 256;
  const int m0 = (t2 >> 2) * 256;
  const u16* Ab = A + kz * Khalf;
  const u16* Bb = Bt + kz * Khalf;
  u16* outp = kz ? out1 : out0;
  const float* bias = kz ? bias1 : bias0;

  const int id1 = 512 + tid;
  const int r0 = tid >> 2, c20 = tid & 3;
  const int r1 = id1 >> 2, c21 = id1 & 3;
  const int cs0 = c20 ^ ((r0 >> 1) & 3);
  const int cs1 = c21 ^ ((r1 >> 1) & 3);
  const u16* Ag0 = Ab + (size_t)(m0 + r0) * ldA + cs0 * 8;
  const u16* Ag1 = Ab + (size_t)(m0 + r1) * ldA + cs1 * 8;
  const u16* Bg0 = Bb + (size_t)(n0 + r0) * ldB + cs0 * 8;
  const u16* Bg1 = Bb + (size_t)(n0 + r1) * ldB + cs1 * 8;

  f32x4 acc[8][4] = {};

  auto stA = [&](int buf, int kt, int ks){
    int kc = kt * 64 + ks * 32;
    gload16(Ag0 + kc, &As[buf][ks * 8192 + w * 512]);
    gload16(Ag1 + kc, &As[buf][ks * 8192 + 4096 + w * 512]);
  };
  auto stB = [&](int buf, int kt, int ks){
    int kc = kt * 64 + ks * 32;
    gload16(Bg0 + kc, &Bs[buf][ks * 8192 + w * 512]);
    gload16(Bg1 + kc, &Bs[buf][ks * 8192 + 4096 + w * 512]);
  };

  stA(0, 0, 0); stB(0, 0, 0); stA(0, 0, 1); stB(0, 0, 1);

  for (int t = 0; t < KT; t++){
    int c = t & 1, nb = c ^ 1;
    bool pf = (t + 1 < KT);
    asm volatile("s_waitcnt vmcnt(4)" ::: "memory");
    __builtin_amdgcn_s_barrier();

#pragma unroll
    for (int ks = 0; ks < 2; ks++){
      if (ks == 1){
        if (pf) asm volatile("s_waitcnt vmcnt(4)" ::: "memory");
        else    asm volatile("s_waitcnt vmcnt(0)" ::: "memory");
        __builtin_amdgcn_s_barrier();
      }
      if (pf){ if (ks == 0) stA(nb, t + 1, 0); else stA(nb, t + 1, 1); }
      bf16x8 fa[8], fb[2];
#pragma unroll
      for (int m = 0; m < 8; m++){
        int row = wm * 128 + m * 16 + (lane & 15);
        int slot = (lane >> 4) ^ ((row >> 1) & 3);
        fa[m] = *(const bf16x8*)(&As[c][ks * 8192 + row * 32 + slot * 8]);
      }
#pragma unroll
      for (int nn = 0; nn < 2; nn++){
        int row = wn * 64 + nn * 16 + (lane & 15);
        int slot = (lane >> 4) ^ ((row >> 1) & 3);
        fb[nn] = *(const bf16x8*)(&Bs[c][ks * 8192 + row * 32 + slot * 8]);
      }
      __builtin_amdgcn_s_setprio(1);
#pragma unroll
      for (int m = 0; m < 8; m++)
#pragma unroll
        for (int nn = 0; nn < 2; nn++)
          acc[m][nn] = __builtin_amdgcn_mfma_f32_16x16x32_bf16(fa[m], fb[nn], acc[m][nn], 0, 0, 0);
      __builtin_amdgcn_s_setprio(0);
      if (pf){ if (ks == 0) stB(nb, t + 1, 0); else stB(nb, t + 1, 1); }
#pragma unroll
      for (int nn = 0; nn < 2; nn++){
        int row = wn * 64 + 32 + nn * 16 + (lane & 15);
        int slot = (lane >> 4) ^ ((row >> 1) & 3);
        fb[nn] = *(const bf16x8*)(&Bs[c][ks * 8192 + row * 32 + slot * 8]);
      }
      __builtin_amdgcn_s_setprio(1);
#pragma unroll
      for (int m = 0; m < 8; m++)
#pragma unroll
        for (int nn = 0; nn < 2; nn++)
          acc[m][2 + nn] = __builtin_amdgcn_mfma_f32_16x16x32_bf16(fa[m], fb[nn], acc[m][2 + nn], 0, 0, 0);
      __builtin_amdgcn_s_setprio(0);
    }
  }

#pragma unroll
  for (int m = 0; m < 8; m++){
    int rowb = m0 + wm * 128 + m * 16 + ((lane >> 4) << 2);
#pragma unroll
    for (int n = 0; n < 4; n++){
      int col = n0 + wn * 64 + n * 16 + (lane & 15);
      float bv = bias[col];
#pragma unroll
      for (int r = 0; r < 4; r++)
        outp[(size_t)(rowb + r) * N + col] = f2b(acc[m][n][r] + bv);
    }
  }
}

// ---------------- FAVOR phi v2 (MFMA) + fused kv/ksum in K-blocks ----------------
__global__ __launch_bounds__(256) void phi2(const u16* __restrict__ qb, const u16* __restrict__ kb,
                                            const u16* __restrict__ omT,
                                            u16* __restrict__ Qp, u16* __restrict__ Kp,
                                            const u16* __restrict__ vt,
                                            u16* __restrict__ kv, float* __restrict__ ksum, int fuse){
  __shared__ __align__(16) u16 qs[128 * 64];
  __shared__ __align__(16) u16 wl[64 * 64];
  __shared__ __align__(16) u16 ph[128 * 128];
  __shared__ __align__(16) u16 Vst[64 * 128];
  __shared__ float part[2][128];
  __shared__ float nrm[128];
  int tid = threadIdx.x, w = tid >> 6, lane = tid & 63;
  int blk = blockIdx.x;
  const u16* src; u16* dst; int row0;
  bool isK = (blk >= 1024);
  if (!isK){ src = qb; dst = Qp; row0 = blk * 128; }
  else     { src = kb; dst = Kp; row0 = (blk - 1024) * 128; }
  const u16* g = src + (size_t)row0 * 64;
#pragma unroll
  for (int i = 0; i < 4; i++){
    int id = tid * 4 + i;
    int r = id >> 3, kc = id & 7;
    *(bf16x8*)(qs + r * 64 + ((kc ^ (r & 7)) << 3)) = *(const bf16x8*)(g + r * 64 + kc * 8);
  }
#pragma unroll
  for (int i = 0; i < 2; i++){
    int id = tid * 2 + i;
    int m = id >> 3, kc = id & 7;
    *(bf16x8*)(wl + m * 64 + ((kc ^ (m & 7)) << 3)) = *(const bf16x8*)(omT + id * 8);
  }
  __syncthreads();
  {
    int r = tid & 127, half = tid >> 7;
    float s = 0.f;
#pragma unroll
    for (int j = 0; j < 4; j++){
      int kc = half * 4 + j;
      bf16x8 v = *(const bf16x8*)(qs + r * 64 + ((kc ^ (r & 7)) << 3));
#pragma unroll
      for (int e = 0; e < 8; e++){ float f = b2f((u16)v[e]); s += f * f; }
    }
    part[half][r] = s;
  }
  __syncthreads();
  if (tid < 128) nrm[tid] = 0.0625f * (part[0][tid] + part[1][tid]);
  __syncthreads();
  f32x4 acc[2][4] = {};
#pragma unroll
  for (int kt = 0; kt < 2; kt++){
    int kc = kt * 4 + (lane >> 4);
    bf16x8 fa[2], fb[4];
#pragma unroll
    for (int mt = 0; mt < 2; mt++){
      int r = w * 32 + mt * 16 + (lane & 15);
      fa[mt] = *(const bf16x8*)(qs + r * 64 + ((kc ^ (r & 7)) << 3));
    }
#pragma unroll
    for (int nt = 0; nt < 4; nt++){
      int m = nt * 16 + (lane & 15);
      fb[nt] = *(const bf16x8*)(wl + m * 64 + ((kc ^ (m & 7)) << 3));
    }
#pragma unroll
    for (int mt = 0; mt < 2; mt++)
#pragma unroll
      for (int nt = 0; nt < 4; nt++)
        acc[mt][nt] = __builtin_amdgcn_mfma_f32_16x16x32_bf16(fa[mt], fb[nt], acc[mt][nt], 0, 0, 0);
  }
  const float LNC = -2.4260151319598086f;   // ln(128^-0.5)
#pragma unroll
  for (int mt = 0; mt < 2; mt++)
#pragma unroll
    for (int nt = 0; nt < 4; nt++)
#pragma unroll
      for (int r4 = 0; r4 < 4; r4++){
        int r = w * 32 + mt * 16 + ((lane >> 4) << 2) + r4;
        int m = nt * 16 + (lane & 15);
        float u = acc[mt][nt][r4];
        float nr = nrm[r];
        ph[r * 128 + m]      = f2b(__expf(u - nr + LNC));
        ph[r * 128 + 64 + m] = f2b(__expf(-u - nr + LNC));
      }
  int bh = 0, cch = 0;
  if (isK && fuse){
    int rr0 = blk - 1024;
    bh = rr0 >> 4; cch = rr0 & 15;
    const u16* vtc = vt + (size_t)bh * 131072 + cch * 128;
#pragma unroll
    for (int i = 0; i < 4; i++){
      int id = tid * 4 + i;
      int d = id >> 4, mc = id & 15;
      *(bf16x8*)(Vst + d * 128 + mc * 8) = *(const bf16x8*)(vtc + (size_t)d * 2048 + mc * 8);
    }
  }
  __syncthreads();
  u16* go = dst + (size_t)row0 * 128;
#pragma unroll
  for (int i = 0; i < 8; i++){
    int id = i * 256 + tid;
    *(bf16x8*)(go + id * 8) = *(const bf16x8*)(ph + id * 8);
  }
  if (isK && fuse){
    int tm = tid & 15, td = tid >> 4;
    int mbase = tm * 8, dbase = td * 4;
    float acc2[8][4] = {};
    float ks[8] = {};
    for (int i = 0; i < 128; i++){
      bf16x8 kk = *(const bf16x8*)(ph + i * 128 + mbase);
      float kf[8];
#pragma unroll
      for (int e = 0; e < 8; e++) kf[e] = b2f((u16)kk[e]);
      float vf[4];
#pragma unroll
      for (int e = 0; e < 4; e++) vf[e] = b2f(Vst[(dbase + e) * 128 + i]);
#pragma unroll
      for (int a = 0; a < 8; a++){
        ks[a] += kf[a];
#pragma unroll
        for (int bb = 0; bb < 4; bb++) acc2[a][bb] += kf[a] * vf[bb];
      }
    }
    u16* kvout = kv + ((size_t)bh * 16 + cch) * 8192;
#pragma unroll
    for (int a = 0; a < 8; a++)
#pragma unroll
      for (int bb = 0; bb < 4; bb++)
        kvout[(size_t)(dbase + bb) * 128 + mbase + a] = f2b(acc2[a][bb]);
    if (td == 0){
      float* kso = ksum + ((size_t)bh * 16 + cch) * 128;
#pragma unroll
      for (int a = 0; a < 8; a++) kso[mbase + a] = ks[a];
    }
  }
}

// ---------------- per-chunk kv^T[d][m] (bf16), ksum f32 (fallback when not fused) ----------------
__global__ __launch_bounds__(256) void kvchunk(const u16* __restrict__ Kp, const u16* __restrict__ vt,
                                               u16* __restrict__ kv, float* __restrict__ ksum){
  __shared__ __align__(16) u16 Ks[128 * 128];
  __shared__ __align__(16) u16 Vst[64 * 128];
  int blk = blockIdx.x; int bh = blk >> 4, c = blk & 15;
  int tid = threadIdx.x;
  size_t base = (size_t)bh * 2048 + c * 128;
  const u16* Kc = Kp + base * 128;
  const u16* vtc = vt + (size_t)bh * 64 * 2048 + c * 128;
  {
    int j = tid >> 1, half = tid & 1;
#pragma unroll
    for (int i = 0; i < 8; i++)
      *(bf16x8*)(Ks + j * 128 + half * 64 + i * 8) = *(const bf16x8*)(Kc + j * 128 + half * 64 + i * 8);
#pragma unroll
    for (int i = 0; i < 4; i++){
      int id = tid * 4 + i;
      int d = id >> 4, mc = id & 15;
      *(bf16x8*)(Vst + d * 128 + mc * 8) = *(const bf16x8*)(vtc + (size_t)d * 2048 + mc * 8);
    }
  }
  __syncthreads();
  int tm = tid & 15, td = tid >> 4;
  int mbase = tm * 8, dbase = td * 4;
  float acc[8][4] = {};
  float ks[8] = {};
  for (int i = 0; i < 128; i++){
    bf16x8 kk = *(const bf16x8*)(Ks + i * 128 + mbase);
    float kf[8];
#pragma unroll
    for (int e = 0; e < 8; e++) kf[e] = b2f((u16)kk[e]);
    float vf[4];
#pragma unroll
    for (int e = 0; e < 4; e++) vf[e] = b2f(Vst[(dbase + e) * 128 + i]);
#pragma unroll
    for (int a = 0; a < 8; a++){
      ks[a] += kf[a];
#pragma unroll
      for (int bb = 0; bb < 4; bb++) acc[a][bb] += kf[a] * vf[bb];
    }
  }
  u16* kvout = kv + ((size_t)bh * 16 + c) * 8192;
#pragma unroll
  for (int a = 0; a < 8; a++)
#pragma unroll
    for (int bb = 0; bb < 4; bb++)
      kvout[(size_t)(dbase + bb) * 128 + mbase + a] = f2b(acc[a][bb]);
  if (td == 0){
    float* kso = ksum + ((size_t)bh * 16 + c) * 128;
#pragma unroll
    for (int a = 0; a < 8; a++) kso[mbase + a] = ks[a];
  }
}

// ---------------- exclusive prefix over chunks (in place; kv bf16, f32 carry) ----------------
__global__ __launch_bounds__(256) void kvscan(u16* __restrict__ kv, float* __restrict__ ksum){
  int bh = blockIdx.x;
  int p = blockIdx.y;
  int tid = threadIdx.x;
  if (p < 8){
    size_t base = (size_t)bh * 16 * 8192;
    int idx0 = p * 1024 + tid;
    for (int rep = 0; rep < 4; rep++){
      int idx = idx0 + rep * 256;
      float run = 0.f;
#pragma unroll
      for (int c = 0; c < 16; c++){
        size_t off = base + (size_t)c * 8192 + idx;
        float v = b2f(kv[off]); kv[off] = f2b(run); run += v;
      }
    }
  } else if (tid < 128){
    size_t base = (size_t)bh * 16 * 128;
    float run = 0.f;
#pragma unroll
    for (int c = 0; c < 16; c++){
      size_t off = base + c * 128 + tid;
      float v = ksum[off]; ksum[off] = run; run += v;
    }
  }
}

// ---------------- MFMA fused attention (kv_pre bf16) ----------------
__global__ __launch_bounds__(512) void attn_fused(const u16* __restrict__ Qp, const u16* __restrict__ Kp,
                                                  const u16* __restrict__ vt, const u16* __restrict__ kvp,
                                                  const float* __restrict__ ksum, u16* __restrict__ aout){
  __shared__ __align__(16) u16 sm[53248];
  int blk = blockIdx.x, bh = blk >> 4, c = blk & 15;
  int b = bh >> 4, h = bh & 15;
  int tid = threadIdx.x, w = tid >> 6, lane = tid & 63;
  size_t base = (size_t)bh * 2048 + c * 128;
  const u16* Qc = Qp + base * 128;
  const u16* Kc = Kp + base * 128;
  const u16* vtc = vt + (size_t)bh * 64 * 2048 + c * 128;
  const u16* kvc = kvp + ((size_t)bh * 16 + c) * 8192;
  const float* ksc = ksum + ((size_t)bh * 16 + c) * 128;
  u16* Qs = sm;
  u16* Ks = sm + 16384;
  u16* B2 = sm + 32768;

#pragma unroll
  for (int i = 0; i < 4; i++){
    int id = tid * 4 + i;
    int r = id >> 4, kc = id & 15;
    int swo = (kc ^ (r & 15)) << 3;
    *(bf16x8*)(Qs + r * 128 + swo) = *(const bf16x8*)(Qc + (size_t)r * 128 + kc * 8);
    *(bf16x8*)(Ks + r * 128 + swo) = *(const bf16x8*)(Kc + (size_t)r * 128 + kc * 8);
  }
#pragma unroll
  for (int i = 0; i < 2; i++){
    int id = tid * 2 + i;
    int d = id >> 4, kc = id & 15;
    *(bf16x8*)(B2 + d * 256 + ((kc ^ (d & 31)) << 3)) = *(const bf16x8*)(vtc + (size_t)d * 2048 + kc * 8);
  }
#pragma unroll
  for (int i = 0; i < 2; i++){
    int id = tid * 2 + i;
    int d = id >> 4, mc = id & 15;
    bf16x8 pk = *(const bf16x8*)(kvc + d * 128 + mc * 8);
    int kc = 16 + mc;
    *(bf16x8*)(B2 + d * 256 + ((kc ^ (d & 31)) << 3)) = pk;
  }
  {
    int row = 64 + (tid >> 5), kc = tid & 31;
    bf16x8 pk = {};
    if (row == 64){
      if (kc < 16){
#pragma unroll
        for (int e = 0; e < 8; e++) pk[e] = (short)0x3F80;
      } else {
        const float* s8 = ksc + (kc - 16) * 8;
        float4 f0 = *(const float4*)(s8);
        float4 f1 = *(const float4*)(s8 + 4);
        pk[0] = (short)f2b(f0.x); pk[1] = (short)f2b(f0.y); pk[2] = (short)f2b(f0.z); pk[3] = (short)f2b(f0.w);
        pk[4] = (short)f2b(f1.x); pk[5] = (short)f2b(f1.y); pk[6] = (short)f2b(f1.z); pk[7] = (short)f2b(f1.w);
      }
    }
    *(bf16x8*)(B2 + row * 256 + ((kc ^ (row & 31)) << 3)) = pk;
  }
  __syncthreads();

  int wm = w >> 2, wn = w & 3;
  f32x4 acc1[4][2] = {};
#pragma unroll
  for (int kk = 0; kk < 4; kk++){
    int kc = kk * 4 + (lane >> 4);
    bf16x8 fa[4], fb[2];
#pragma unroll
    for (int m = 0; m < 4; m++){
      int row = wm * 64 + m * 16 + (lane & 15);
      fa[m] = *(const bf16x8*)(Qs + row * 128 + ((kc ^ (row & 15)) << 3));
    }
#pragma unroll
    for (int n = 0; n < 2; n++){
      int row = wn * 32 + n * 16 + (lane & 15);
      fb[n] = *(const bf16x8*)(Ks + row * 128 + ((kc ^ (row & 15)) << 3));
    }
#pragma unroll
    for (int m = 0; m < 4; m++)
#pragma unroll
      for (int n = 0; n < 2; n++)
        acc1[m][n] = __builtin_amdgcn_mfma_f32_16x16x32_bf16(fa[m], fb[n], acc1[m][n], 0, 0, 0);
  }
  __syncthreads();

#pragma unroll
  for (int m = 0; m < 4; m++)
#pragma unroll
    for (int n = 0; n < 2; n++)
#pragma unroll
      for (int r = 0; r < 4; r++){
        int i = wm * 64 + m * 16 + ((lane >> 4) << 2) + r;
        int j = wn * 32 + n * 16 + (lane & 15);
        float v = (j <= i) ? acc1[m][n][r] : 0.f;
        Ks[i * 128 + (((j >> 3) ^ (i & 15)) << 3) + (j & 7)] = f2b(v);
      }
  __syncthreads();

  f32x4 acc2[5] = {};
#pragma unroll
  for (int kk = 0; kk < 8; kk++){
    int kc = kk * 4 + (lane >> 4);
    int rowA = w * 16 + (lane & 15);
    bf16x8 fa2;
    if (kk < 4) fa2 = *(const bf16x8*)(Ks + rowA * 128 + ((kc ^ (rowA & 15)) << 3));
    else        fa2 = *(const bf16x8*)(Qs + rowA * 128 + (((kc - 16) ^ (rowA & 15)) << 3));
#pragma unroll
    for (int n = 0; n < 5; n++){
      int d = n * 16 + (lane & 15);
      bf16x8 fb2 = *(const bf16x8*)(B2 + d * 256 + ((kc ^ (d & 31)) << 3));
      acc2[n] = __builtin_amdgcn_mfma_f32_16x16x32_bf16(fa2, fb2, acc2[n], 0, 0, 0);
    }
  }

  float dd[4];
#pragma unroll
  for (int r = 0; r < 4; r++) dd[r] = __shfl(acc2[4][r], lane & 48) + 1e-6f;
  size_t obase = ((size_t)b * 2048 + c * 128) * 1024 + (size_t)h * 64;
#pragma unroll
  for (int n = 0; n < 4; n++)
#pragma unroll
    for (int r = 0; r < 4; r++){
      int i = w * 16 + ((lane >> 4) << 2) + r;
      int d = n * 16 + (lane & 15);
      aout[obase + (size_t)i * 1024 + d] = f2b(acc2[n][r] / dd[r]);
    }
}

// ---------------- universal residual-add + LayerNorm ----------------
__global__ __launch_bounds__(256) void lnr(const float* X1f, const u16* X1b,
                                           const u16* P0, const u16* P1,
                                           const float* __restrict__ g, const float* __restrict__ bb,
                                           float* outf, u16* outb, u16* outb2){
  __shared__ float red[2][4];
  int row = blockIdx.x, tid = threadIdx.x, w = tid >> 6, lane = tid & 63;
  size_t ro = (size_t)row * 1024 + tid * 4;
  float x0, x1, x2, x3;
  if (X1f){
    float4 a = *(const float4*)(X1f + ro);
    x0 = a.x; x1 = a.y; x2 = a.z; x3 = a.w;
  } else {
    ushort4 a = *(const ushort4*)(X1b + ro);
    x0 = b2f(a.x); x1 = b2f(a.y); x2 = b2f(a.z); x3 = b2f(a.w);
  }
  {
    ushort4 p0 = *(const ushort4*)(P0 + ro);
    x0 += b2f(p0.x); x1 += b2f(p0.y); x2 += b2f(p0.z); x3 += b2f(p0.w);
  }
  if (P1){
    ushort4 p1 = *(const ushort4*)(P1 + ro);
    x0 += b2f(p1.x); x1 += b2f(p1.y); x2 += b2f(p1.z); x3 += b2f(p1.w);
  }
  float s1 = x0 + x1 + x2 + x3;
  float s2 = x0 * x0 + x1 * x1 + x2 * x2 + x3 * x3;
#pragma unroll
  for (int off = 32; off; off >>= 1){ s1 += __shfl_xor(s1, off); s2 += __shfl_xor(s2, off); }
  if (lane == 0){ red[0][w] = s1; red[1][w] = s2; }
  __syncthreads();
  float t1 = red[0][0] + red[0][1] + red[0][2] + red[0][3];
  float t2 = red[1][0] + red[1][1] + red[1][2] + red[1][3];
  float mu = t1 * (1.f / 1024.f);
  float var = t2 * (1.f / 1024.f) - mu * mu;
  float rs = rsqrtf(var + 1e-5f);
  float4 gv = *(const float4*)(g + tid * 4);
  float4 bv = *(const float4*)(bb + tid * 4);
  float o0 = (x0 - mu) * rs * gv.x + bv.x;
  float o1 = (x1 - mu) * rs * gv.y + bv.y;
  float o2 = (x2 - mu) * rs * gv.z + bv.z;
  float o3 = (x3 - mu) * rs * gv.w + bv.w;
  if (outf) *(float4*)(outf + ro) = make_float4(o0, o1, o2, o3);
  ushort4 ob = make_ushort4(f2b(o0), f2b(o1), f2b(o2), f2b(o3));
  if (outb)  *(ushort4*)(outb + ro)  = ob;
  if (outb2) *(ushort4*)(outb2 + ro) = ob;
}

// ---------------- host ----------------
extern "C" void kernel_launch(void* const* d_in, const int* in_sizes, int n_in,
                              void* d_out, int out_size, void* d_ws, size_t ws_size,
                              hipStream_t stream){
  (void)in_sizes; (void)n_in;
  const float* x   = (const float*)d_in[0];
  const float* Wq  = (const float*)d_in[1];
  const float* bq  = (const float*)d_in[2];
  const float* Wk  = (const float*)d_in[3];
  const float* bk  = (const float*)d_in[4];
  const float* Wv  = (const float*)d_in[5];
  const float* bv  = (const float*)d_in[6];
  const float* Wo  = (const float*)d_in[7];
  const float* bo  = (const float*)d_in[8];
  const float* om  = (const float*)d_in[9];
  const float* g1  = (const float*)d_in[10];
  const float* be1 = (const float*)d_in[11];
  const float* W1  = (const float*)d_in[12];
  const float* bf1 = (const float*)d_in[13];
  const float* W2  = (const float*)d_in[14];
  const float* bf2 = (const float*)d_in[15];
  const float* g2  = (const float*)d_in[16];
  const float* be2 = (const float*)d_in[17];

  char* ws = (char*)d_ws;
  size_t off = 0;
  auto alloc = [&](size_t bytes) -> void* {
    void* p = ws + off; off += (bytes + 255) & ~(size_t)255; return p;
  };
  u16* Wcat = (u16*)alloc(3072ull * 1024 * 2);
  u16* Wot  = (u16*)alloc(1024ull * 1024 * 2);
  u16* W1t  = (u16*)alloc(4096ull * 1024 * 2);
  u16* W2t  = (u16*)alloc(1024ull * 4096 * 2);
  u16* omT  = (u16*)alloc(64ull * 64 * 2);
  float* bcat = (float*)alloc(6ull * 3072 * 4);
  float* zbuf = (float*)alloc(1024 * 4);
  u16* Xb  = (u16*)alloc(8192ull * 1024 * 2);
  u16* qb  = (u16*)alloc(131072ull * 64 * 2);   // contiguous qb|kb|vt|Qp for ybuf alias
  u16* kb  = (u16*)alloc(131072ull * 64 * 2);
  u16* vt  = (u16*)alloc(131072ull * 64 * 2);
  u16* Qp  = (u16*)alloc(131072ull * 128 * 2);
  u16* Kp  = (u16*)alloc(131072ull * 128 * 2);
  float* ksum = (float*)alloc(64ull * 16 * 128 * 4);
  size_t base_end = off;

  // dedicated 16MB kv buffer enables phi2-fused kvchunk (gated on ws_size)
  u16* kvded = (u16*)alloc(64ull * 16 * 8192 * 2);
  bool fuse = (off <= ws_size);
  if (!fuse){ off = base_end; kvded = qb; }     // fallback: kv in qb + separate kvchunk

  if (off > ws_size){
    fillv<<<(out_size + 255) / 256, 256, 0, stream>>>((float*)d_out, (float)(ws_size >> 20), out_size);
    return;
  }

  u16*  ybuf   = qb;                    // FFN intermediate bf16 [8192][4096] over qb..Qp[0:16MB]
  u16*  wooutb = Qp;                    // Wo out bf16 16MB (Qp dead after attn)
  u16*  w2outb = Qp + 8388608;          // W2 partial kz=0, bf16 16MB
  u16*  w2p1   = Kp + 8388608;          // W2 partial kz=1, bf16 16MB (Kp[16:32], dead after attn)
  u16*  residb = (u16*)d_out;           // bf16 residual stream in d_out[0:16MB]; final layer writes f32

  cvt16<<<8192, 256, 0, stream>>>(x, Xb);
  catbias<<<72, 256, 0, stream>>>(bq, bk, bv, bcat);
  fillv<<<4, 256, 0, stream>>>(zbuf, 0.f, 1024);

  for (int l = 0; l < 6; l++){
    size_t o1k = (size_t)l * 1024 * 1024;
    size_t o4k = (size_t)l * 4096 * 1024;
    wtrans7<<<12292, 256, 0, stream>>>(Wq + o1k, Wk + o1k, Wv + o1k, Wo + o1k,
                                       W1 + o4k, W2 + o4k, om + (size_t)l * 4096,
                                       Wcat, Wot, W1t, W2t, omT);

    gemm_bt<5><<<dim3(24, 64), 256, 0, stream>>>(Xb, Wcat, bcat + l * 3072, qb, 8192, 3072, 1024, 1024, 1024);
    phi2<<<2048, 256, 0, stream>>>(qb, kb, omT, Qp, Kp, vt, kvded, ksum, fuse ? 1 : 0);
    if (!fuse) kvchunk<<<1024, 256, 0, stream>>>(Kp, vt, kvded, ksum);
    kvscan<<<dim3(64, 9), 256, 0, stream>>>(kvded, ksum);
    attn_fused<<<1024, 512, 0, stream>>>(Qp, Kp, vt, kvded, ksum, Xb);
    gemm_bt<6><<<dim3(8, 64), 256, 0, stream>>>(Xb, Wot, bo + l * 1024, wooutb, 8192, 1024, 1024, 1024, 1024);
    lnr<<<8192, 256, 0, stream>>>(l == 0 ? x : nullptr, l == 0 ? nullptr : residb,
                                  wooutb, nullptr, g1 + l * 1024, be1 + l * 1024,
                                  nullptr, Xb, nullptr);
    gemm8p<2, 16><<<dim3(16, 32), 512, 0, stream>>>(Xb, W1t, bf1 + l * 4096, ybuf, 8192, 4096, 1024, 1024);
    gemm8pk<32><<<dim3(256), 512, 0, stream>>>(ybuf, W2t, bf2 + l * 1024, zbuf, w2outb, w2p1,
                                               8192, 1024, 2048, 4096, 4096);
    if (l == 5)
      lnr<<<8192, 256, 0, stream>>>(nullptr, Xb, w2outb, w2p1, g2 + l * 1024, be2 + l * 1024,
                                    (float*)d_out, nullptr, nullptr);
    else
      lnr<<<8192, 256, 0, stream>>>(nullptr, Xb, w2outb, w2p1, g2 + l * 1024, be2 + l * 1024,
                                    nullptr, Xb, residb);
  }
}